// Round 1
// baseline (2073.425 us; speedup 1.0000x reference)
//
#include <hip/hip_runtime.h>
#include <math.h>

#define NN 100000
#define HIDC 128
#define OUTC 40

// ---------------- graph prep ----------------

__global__ void zero_kernel(int* __restrict__ p, int n) {
  int i = blockIdx.x * blockDim.x + threadIdx.x;
  if (i < n) p[i] = 0;
}

__global__ void hist_kernel(const int* __restrict__ dst, int* __restrict__ cnt, int E) {
  int i = blockIdx.x * blockDim.x + threadIdx.x;
  if (i < E) atomicAdd(&cnt[dst[i]], 1);
}

#define SCAN_T 1024
__global__ __launch_bounds__(SCAN_T) void scan_kernel(
    const int* __restrict__ cnt, int* __restrict__ row_off, int* __restrict__ cursor,
    float* __restrict__ dinv, int N) {
  __shared__ int sums[SCAN_T];
  int t = threadIdx.x;
  int chunk = (N + SCAN_T - 1) / SCAN_T;
  int lo = t * chunk;
  int hi = lo + chunk; if (hi > N) hi = N; if (hi < lo) hi = lo;
  int s = 0;
  for (int i = lo; i < hi; i++) s += cnt[i];
  sums[t] = s;
  __syncthreads();
  // Hillis-Steele inclusive scan over per-thread sums
  for (int off = 1; off < SCAN_T; off <<= 1) {
    int v = (t >= off) ? sums[t - off] : 0;
    __syncthreads();
    sums[t] += v;
    __syncthreads();
  }
  int run = (t == 0) ? 0 : sums[t - 1];
  for (int i = lo; i < hi; i++) {
    int c = cnt[i];
    row_off[i] = run;
    cursor[i] = run;
    dinv[i] = rsqrtf((float)(c + 1));  // +1 self-loop; deg>0 always
    run += c;
  }
  if (t == SCAN_T - 1) row_off[N] = run;
}

__global__ void fill_kernel(const int* __restrict__ src, const int* __restrict__ dst,
                            int* __restrict__ cursor, int* __restrict__ csr, int E) {
  int i = blockIdx.x * blockDim.x + threadIdx.x;
  if (i < E) {
    int p = atomicAdd(&cursor[dst[i]], 1);
    csr[p] = src[i];
  }
}

// ---------------- GEMM (M x 128) @ (128 x 128), optional bias+relu ----------------
// tile: 64 rows x 128 cols per block, 256 threads, 8 rows x 4 cols per thread.
// W (64 KB) + X tile (32 KB) in LDS.

__global__ __launch_bounds__(256) void gemm_kernel(
    const float* __restrict__ X, const float* __restrict__ W,
    const float* __restrict__ bias, float* __restrict__ Y, int M, int relu) {
  __shared__ __align__(16) float Ws[128 * 128];
  __shared__ __align__(16) float Xs[64 * 128];
  int tx = threadIdx.x;
  int cg = tx & 31;   // col group: cols 4*cg .. 4*cg+3
  int rg = tx >> 5;   // row group: rows 8*rg .. 8*rg+7

  // stage W: 4096 float4
  for (int i = tx; i < 4096; i += 256)
    ((float4*)Ws)[i] = ((const float4*)W)[i];

  int row0 = blockIdx.x * 64;
  int rows_here = M - row0; if (rows_here > 64) rows_here = 64;
  const float4* Xg = (const float4*)(X + (size_t)row0 * 128);
  for (int i = tx; i < rows_here * 32; i += 256)
    ((float4*)Xs)[i] = Xg[i];
  __syncthreads();

  float acc[8][4];
#pragma unroll
  for (int r = 0; r < 8; r++)
#pragma unroll
    for (int c = 0; c < 4; c++) acc[r][c] = 0.f;

  for (int k = 0; k < 128; k += 4) {
    float4 w0 = *(const float4*)&Ws[(k + 0) * 128 + cg * 4];
    float4 w1 = *(const float4*)&Ws[(k + 1) * 128 + cg * 4];
    float4 w2 = *(const float4*)&Ws[(k + 2) * 128 + cg * 4];
    float4 w3 = *(const float4*)&Ws[(k + 3) * 128 + cg * 4];
#pragma unroll
    for (int r = 0; r < 8; r++) {
      float4 xv = *(const float4*)&Xs[(rg * 8 + r) * 128 + k];
      acc[r][0] = fmaf(xv.x, w0.x, fmaf(xv.y, w1.x, fmaf(xv.z, w2.x, fmaf(xv.w, w3.x, acc[r][0]))));
      acc[r][1] = fmaf(xv.x, w0.y, fmaf(xv.y, w1.y, fmaf(xv.z, w2.y, fmaf(xv.w, w3.y, acc[r][1]))));
      acc[r][2] = fmaf(xv.x, w0.z, fmaf(xv.y, w1.z, fmaf(xv.z, w2.z, fmaf(xv.w, w3.z, acc[r][2]))));
      acc[r][3] = fmaf(xv.x, w0.w, fmaf(xv.y, w1.w, fmaf(xv.z, w2.w, fmaf(xv.w, w3.w, acc[r][3]))));
    }
  }

  float4 bv = make_float4(0.f, 0.f, 0.f, 0.f);
  if (bias) bv = ((const float4*)bias)[cg];
#pragma unroll
  for (int r = 0; r < 8; r++) {
    int row = row0 + rg * 8 + r;
    if (row < M) {
      float4 o;
      o.x = acc[r][0] + bv.x; o.y = acc[r][1] + bv.y;
      o.z = acc[r][2] + bv.z; o.w = acc[r][3] + bv.w;
      if (relu) {
        o.x = fmaxf(o.x, 0.f); o.y = fmaxf(o.y, 0.f);
        o.z = fmaxf(o.z, 0.f); o.w = fmaxf(o.w, 0.f);
      }
      *(float4*)&Y[(size_t)row * 128 + cg * 4] = o;
    }
  }
}

// ---------------- aggregation (pull over dst-CSR, no float atomics) ----------------
// out[d] = relu( dinv[d] * ( sum_{s in csr[d]} dinv[s]*Ht[s] + dinv[d]*Ht[d] ) + b )
// one 64-lane wave per node, float2 per lane (128 cols).

__global__ __launch_bounds__(256) void aggregate_kernel(
    const float* __restrict__ Ht, const int* __restrict__ row_off,
    const int* __restrict__ csr, const float* __restrict__ dinv,
    const float* __restrict__ bias, float* __restrict__ Out, int N) {
  int wave = (blockIdx.x * blockDim.x + threadIdx.x) >> 6;
  int lane = threadIdx.x & 63;
  if (wave >= N) return;
  int d = wave;
  int beg = row_off[d], end = row_off[d + 1];
  const float2* Ht2 = (const float2*)Ht;
  float ax = 0.f, ay = 0.f;
  int e = beg;
  for (; e + 1 < end; e += 2) {
    int s0 = csr[e], s1 = csr[e + 1];
    float w0 = dinv[s0], w1 = dinv[s1];
    float2 v0 = Ht2[(size_t)s0 * 64 + lane];
    float2 v1 = Ht2[(size_t)s1 * 64 + lane];
    ax = fmaf(w0, v0.x, ax); ay = fmaf(w0, v0.y, ay);
    ax = fmaf(w1, v1.x, ax); ay = fmaf(w1, v1.y, ay);
  }
  if (e < end) {
    int s0 = csr[e];
    float w0 = dinv[s0];
    float2 v0 = Ht2[(size_t)s0 * 64 + lane];
    ax = fmaf(w0, v0.x, ax); ay = fmaf(w0, v0.y, ay);
  }
  float dd = dinv[d];
  float2 vs = Ht2[(size_t)d * 64 + lane];
  ax = fmaf(dd, vs.x, ax); ay = fmaf(dd, vs.y, ay);
  float2 b2 = ((const float2*)bias)[lane];
  float ox = fmaf(dd, ax, b2.x);
  float oy = fmaf(dd, ay, b2.y);
  ox = fmaxf(ox, 0.f); oy = fmaxf(oy, 0.f);
  float2 o; o.x = ox; o.y = oy;
  ((float2*)Out)[(size_t)d * 64 + lane] = o;
}

// ---------------- head: logits = H @ W2 + b2, then log_softmax per row ----------------
// one wave per row; lanes 0..39 hold one class each.

__device__ __forceinline__ float wave_max(float v) {
#pragma unroll
  for (int off = 32; off > 0; off >>= 1) v = fmaxf(v, __shfl_xor(v, off, 64));
  return v;
}
__device__ __forceinline__ float wave_sum(float v) {
#pragma unroll
  for (int off = 32; off > 0; off >>= 1) v += __shfl_xor(v, off, 64);
  return v;
}

__global__ __launch_bounds__(256) void head_kernel(
    const float* __restrict__ H, const float* __restrict__ W2,
    const float* __restrict__ b2, float* __restrict__ Out, int N) {
  __shared__ __align__(16) float Ws[128 * OUTC];
  __shared__ float bs[OUTC];
  int t = threadIdx.x;
  for (int i = t; i < 128 * OUTC; i += 256) Ws[i] = W2[i];
  if (t < OUTC) bs[t] = b2[t];
  __syncthreads();
  int row = blockIdx.x * 4 + (t >> 6);
  if (row >= N) return;
  int lane = t & 63;
  int c = (lane < OUTC) ? lane : (OUTC - 1);  // clamp so all lanes run the loop uniformly
  const float4* h4 = (const float4*)(H + (size_t)row * 128);
  float logit = bs[c];
  for (int k4 = 0; k4 < 32; k4++) {
    float4 hv = h4[k4];
    int k = k4 * 4;
    logit = fmaf(hv.x, Ws[(k + 0) * OUTC + c],
            fmaf(hv.y, Ws[(k + 1) * OUTC + c],
            fmaf(hv.z, Ws[(k + 2) * OUTC + c],
            fmaf(hv.w, Ws[(k + 3) * OUTC + c], logit))));
  }
  float v = (lane < OUTC) ? logit : -3.4e38f;
  float m = wave_max(v);
  float ex = (lane < OUTC) ? expf(logit - m) : 0.f;
  float s = wave_sum(ex);
  if (lane < OUTC) Out[(size_t)row * OUTC + lane] = logit - m - logf(s);
}

// ---------------- launch ----------------

extern "C" void kernel_launch(void* const* d_in, const int* in_sizes, int n_in,
                              void* d_out, int out_size, void* d_ws, size_t ws_size,
                              hipStream_t stream) {
  const float* x      = (const float*)d_in[0];
  const int*   edge   = (const int*)d_in[1];   // int32 per harness convention
  const float* lin1_w = (const float*)d_in[2];
  const float* lin1_b = (const float*)d_in[3];
  const float* gcn_w  = (const float*)d_in[4];
  const float* gcn_b  = (const float*)d_in[5];
  const float* lin2_w = (const float*)d_in[6];
  const float* lin2_b = (const float*)d_in[7];
  float* out = (float*)d_out;

  const int N = NN;
  const int E = in_sizes[1] / 2;  // 3,200,000
  const int* src = edge;
  const int* dst = edge + E;

  char* p = (char*)d_ws;
  auto alloc = [&](size_t bytes) { char* q = p; p += (bytes + 255) & ~(size_t)255; return q; };
  float* hA      = (float*)alloc((size_t)N * 128 * 4);
  float* hB      = (float*)alloc((size_t)N * 128 * 4);
  int*   cnt     = (int*)alloc((size_t)N * 4);
  int*   row_off = (int*)alloc((size_t)(N + 1) * 4);
  int*   cursor  = (int*)alloc((size_t)N * 4);
  float* dinv    = (float*)alloc((size_t)N * 4);
  int*   csr     = (int*)alloc((size_t)E * 4);

  // graph prep
  zero_kernel<<<(N + 255) / 256, 256, 0, stream>>>(cnt, N);
  hist_kernel<<<(E + 255) / 256, 256, 0, stream>>>(dst, cnt, E);
  scan_kernel<<<1, SCAN_T, 0, stream>>>(cnt, row_off, cursor, dinv, N);
  fill_kernel<<<(E + 255) / 256, 256, 0, stream>>>(src, dst, cursor, csr, E);

  int gemm_blocks = (N + 63) / 64;
  // h = relu(x @ W1 + b1)
  gemm_kernel<<<gemm_blocks, 256, 0, stream>>>(x, lin1_w, lin1_b, hA, N, 1);
  // 3 GCN layers
  for (int k = 0; k < 3; k++) {
    gemm_kernel<<<gemm_blocks, 256, 0, stream>>>(hA, gcn_w + (size_t)k * 128 * 128, nullptr, hB, N, 0);
    aggregate_kernel<<<(N + 3) / 4, 256, 0, stream>>>(hB, row_off, csr, dinv,
                                                      gcn_b + (size_t)k * 128, hA, N);
  }
  // head
  head_kernel<<<(N + 3) / 4, 256, 0, stream>>>(hA, lin2_w, lin2_b, out, N);
}

// Round 2
// 1808.518 us; speedup vs baseline: 1.1465x; 1.1465x over previous
//
#include <hip/hip_runtime.h>
#include <math.h>

#define NN 100000
#define HIDC 128
#define OUTC 40

// ---------------- graph prep ----------------

__global__ void zero_kernel(int* __restrict__ p, int n) {
  int i = blockIdx.x * blockDim.x + threadIdx.x;
  if (i < n) p[i] = 0;
}

__global__ void hist_kernel(const int* __restrict__ dst, int* __restrict__ cnt, int E) {
  int i = blockIdx.x * blockDim.x + threadIdx.x;
  if (i < E) atomicAdd(&cnt[dst[i]], 1);
}

// ---- parallel exclusive scan over cnt[0..N): 3 dispatches ----
// scan1: per-block (1024-elem chunk) sums -> partial[b]
// scan2: single small block scans partials (exclusive, in place)
// scan3: in-block scan + partial offset -> row_off/cursor/dinv

__global__ __launch_bounds__(256) void scan1_kernel(
    const int* __restrict__ cnt, int* __restrict__ partial, int N) {
  int b = blockIdx.x, t = threadIdx.x;
  int base = b * 1024 + t * 4;
  int s = 0;
#pragma unroll
  for (int j = 0; j < 4; j++) { int i = base + j; if (i < N) s += cnt[i]; }
  __shared__ int sums[256];
  sums[t] = s;
  __syncthreads();
  for (int off = 128; off > 0; off >>= 1) {
    if (t < off) sums[t] += sums[t + off];
    __syncthreads();
  }
  if (t == 0) partial[b] = sums[0];
}

__global__ __launch_bounds__(128) void scan2_kernel(int* __restrict__ partial, int nb) {
  __shared__ int sh[128];
  int t = threadIdx.x;
  int v = (t < nb) ? partial[t] : 0;
  sh[t] = v;
  __syncthreads();
  for (int off = 1; off < 128; off <<= 1) {
    int u = (t >= off) ? sh[t - off] : 0;
    __syncthreads();
    sh[t] += u;
    __syncthreads();
  }
  if (t < nb) partial[t] = sh[t] - v;  // exclusive
}

__global__ __launch_bounds__(256) void scan3_kernel(
    const int* __restrict__ cnt, const int* __restrict__ partial,
    int* __restrict__ row_off, int* __restrict__ cursor,
    float* __restrict__ dinv, int N) {
  int b = blockIdx.x, t = threadIdx.x;
  int base = b * 1024 + t * 4;
  int c[4]; int s = 0;
#pragma unroll
  for (int j = 0; j < 4; j++) { int i = base + j; c[j] = (i < N) ? cnt[i] : 0; s += c[j]; }
  __shared__ int sums[256];
  sums[t] = s;
  __syncthreads();
  for (int off = 1; off < 256; off <<= 1) {
    int u = (t >= off) ? sums[t - off] : 0;
    __syncthreads();
    sums[t] += u;
    __syncthreads();
  }
  int run = partial[b] + sums[t] - s;  // exclusive prefix for this thread's 4 elems
#pragma unroll
  for (int j = 0; j < 4; j++) {
    int i = base + j;
    if (i < N) {
      row_off[i] = run;
      cursor[i] = run;
      dinv[i] = rsqrtf((float)(c[j] + 1));  // +1 self-loop
      run += c[j];
    }
  }
  // last thread of last block: run == grand total (pads contribute 0)
  if (b == gridDim.x - 1 && t == 255) row_off[N] = run;
}

__global__ void fill_kernel(const int* __restrict__ src, const int* __restrict__ dst,
                            int* __restrict__ cursor, int* __restrict__ csr, int E) {
  int i = blockIdx.x * blockDim.x + threadIdx.x;
  if (i < E) {
    int p = atomicAdd(&cursor[dst[i]], 1);
    csr[p] = src[i];
  }
}

// ---------------- GEMM (M x 128) @ (128 x 128), optional bias+relu ----------------
// tile: 64 rows x 128 cols per block, 256 threads, 8 rows x 4 cols per thread.

__global__ __launch_bounds__(256) void gemm_kernel(
    const float* __restrict__ X, const float* __restrict__ W,
    const float* __restrict__ bias, float* __restrict__ Y, int M, int relu) {
  __shared__ __align__(16) float Ws[128 * 128];
  __shared__ __align__(16) float Xs[64 * 128];
  int tx = threadIdx.x;
  int cg = tx & 31;   // col group: cols 4*cg .. 4*cg+3
  int rg = tx >> 5;   // row group: rows 8*rg .. 8*rg+7

  for (int i = tx; i < 4096; i += 256)
    ((float4*)Ws)[i] = ((const float4*)W)[i];

  int row0 = blockIdx.x * 64;
  int rows_here = M - row0; if (rows_here > 64) rows_here = 64;
  const float4* Xg = (const float4*)(X + (size_t)row0 * 128);
  for (int i = tx; i < rows_here * 32; i += 256)
    ((float4*)Xs)[i] = Xg[i];
  __syncthreads();

  float acc[8][4];
#pragma unroll
  for (int r = 0; r < 8; r++)
#pragma unroll
    for (int c = 0; c < 4; c++) acc[r][c] = 0.f;

  for (int k = 0; k < 128; k += 4) {
    float4 w0 = *(const float4*)&Ws[(k + 0) * 128 + cg * 4];
    float4 w1 = *(const float4*)&Ws[(k + 1) * 128 + cg * 4];
    float4 w2 = *(const float4*)&Ws[(k + 2) * 128 + cg * 4];
    float4 w3 = *(const float4*)&Ws[(k + 3) * 128 + cg * 4];
#pragma unroll
    for (int r = 0; r < 8; r++) {
      float4 xv = *(const float4*)&Xs[(rg * 8 + r) * 128 + k];
      acc[r][0] = fmaf(xv.x, w0.x, fmaf(xv.y, w1.x, fmaf(xv.z, w2.x, fmaf(xv.w, w3.x, acc[r][0]))));
      acc[r][1] = fmaf(xv.x, w0.y, fmaf(xv.y, w1.y, fmaf(xv.z, w2.y, fmaf(xv.w, w3.y, acc[r][1]))));
      acc[r][2] = fmaf(xv.x, w0.z, fmaf(xv.y, w1.z, fmaf(xv.z, w2.z, fmaf(xv.w, w3.z, acc[r][2]))));
      acc[r][3] = fmaf(xv.x, w0.w, fmaf(xv.y, w1.w, fmaf(xv.z, w2.w, fmaf(xv.w, w3.w, acc[r][3]))));
    }
  }

  float4 bv = make_float4(0.f, 0.f, 0.f, 0.f);
  if (bias) bv = ((const float4*)bias)[cg];
#pragma unroll
  for (int r = 0; r < 8; r++) {
    int row = row0 + rg * 8 + r;
    if (row < M) {
      float4 o;
      o.x = acc[r][0] + bv.x; o.y = acc[r][1] + bv.y;
      o.z = acc[r][2] + bv.z; o.w = acc[r][3] + bv.w;
      if (relu) {
        o.x = fmaxf(o.x, 0.f); o.y = fmaxf(o.y, 0.f);
        o.z = fmaxf(o.z, 0.f); o.w = fmaxf(o.w, 0.f);
      }
      *(float4*)&Y[(size_t)row * 128 + cg * 4] = o;
    }
  }
}

// ---------------- aggregation (pull over dst-CSR, no float atomics) ----------------

__global__ __launch_bounds__(256) void aggregate_kernel(
    const float* __restrict__ Ht, const int* __restrict__ row_off,
    const int* __restrict__ csr, const float* __restrict__ dinv,
    const float* __restrict__ bias, float* __restrict__ Out, int N) {
  int wave = (blockIdx.x * blockDim.x + threadIdx.x) >> 6;
  int lane = threadIdx.x & 63;
  if (wave >= N) return;
  int d = wave;
  int beg = row_off[d], end = row_off[d + 1];
  const float2* Ht2 = (const float2*)Ht;
  float ax = 0.f, ay = 0.f;
  int e = beg;
  for (; e + 1 < end; e += 2) {
    int s0 = csr[e], s1 = csr[e + 1];
    float w0 = dinv[s0], w1 = dinv[s1];
    float2 v0 = Ht2[(size_t)s0 * 64 + lane];
    float2 v1 = Ht2[(size_t)s1 * 64 + lane];
    ax = fmaf(w0, v0.x, ax); ay = fmaf(w0, v0.y, ay);
    ax = fmaf(w1, v1.x, ax); ay = fmaf(w1, v1.y, ay);
  }
  if (e < end) {
    int s0 = csr[e];
    float w0 = dinv[s0];
    float2 v0 = Ht2[(size_t)s0 * 64 + lane];
    ax = fmaf(w0, v0.x, ax); ay = fmaf(w0, v0.y, ay);
  }
  float dd = dinv[d];
  float2 vs = Ht2[(size_t)d * 64 + lane];
  ax = fmaf(dd, vs.x, ax); ay = fmaf(dd, vs.y, ay);
  float2 b2 = ((const float2*)bias)[lane];
  float ox = fmaf(dd, ax, b2.x);
  float oy = fmaf(dd, ay, b2.y);
  ox = fmaxf(ox, 0.f); oy = fmaxf(oy, 0.f);
  float2 o; o.x = ox; o.y = oy;
  ((float2*)Out)[(size_t)d * 64 + lane] = o;
}

// ---------------- head: logits = H @ W2 + b2, then log_softmax per row ----------------

__device__ __forceinline__ float wave_max(float v) {
#pragma unroll
  for (int off = 32; off > 0; off >>= 1) v = fmaxf(v, __shfl_xor(v, off, 64));
  return v;
}
__device__ __forceinline__ float wave_sum(float v) {
#pragma unroll
  for (int off = 32; off > 0; off >>= 1) v += __shfl_xor(v, off, 64);
  return v;
}

__global__ __launch_bounds__(256) void head_kernel(
    const float* __restrict__ H, const float* __restrict__ W2,
    const float* __restrict__ b2, float* __restrict__ Out, int N) {
  __shared__ __align__(16) float Ws[128 * OUTC];
  __shared__ float bs[OUTC];
  int t = threadIdx.x;
  for (int i = t; i < 128 * OUTC; i += 256) Ws[i] = W2[i];
  if (t < OUTC) bs[t] = b2[t];
  __syncthreads();
  int row = blockIdx.x * 4 + (t >> 6);
  if (row >= N) return;
  int lane = t & 63;
  int c = (lane < OUTC) ? lane : (OUTC - 1);
  const float4* h4 = (const float4*)(H + (size_t)row * 128);
  float logit = bs[c];
  for (int k4 = 0; k4 < 32; k4++) {
    float4 hv = h4[k4];
    int k = k4 * 4;
    logit = fmaf(hv.x, Ws[(k + 0) * OUTC + c],
            fmaf(hv.y, Ws[(k + 1) * OUTC + c],
            fmaf(hv.z, Ws[(k + 2) * OUTC + c],
            fmaf(hv.w, Ws[(k + 3) * OUTC + c], logit))));
  }
  float v = (lane < OUTC) ? logit : -3.4e38f;
  float m = wave_max(v);
  float ex = (lane < OUTC) ? expf(logit - m) : 0.f;
  float s = wave_sum(ex);
  if (lane < OUTC) Out[(size_t)row * OUTC + lane] = logit - m - logf(s);
}

// ---------------- launch ----------------

extern "C" void kernel_launch(void* const* d_in, const int* in_sizes, int n_in,
                              void* d_out, int out_size, void* d_ws, size_t ws_size,
                              hipStream_t stream) {
  const float* x      = (const float*)d_in[0];
  const int*   edge   = (const int*)d_in[1];
  const float* lin1_w = (const float*)d_in[2];
  const float* lin1_b = (const float*)d_in[3];
  const float* gcn_w  = (const float*)d_in[4];
  const float* gcn_b  = (const float*)d_in[5];
  const float* lin2_w = (const float*)d_in[6];
  const float* lin2_b = (const float*)d_in[7];
  float* out = (float*)d_out;

  const int N = NN;
  const int E = in_sizes[1] / 2;  // 3,200,000
  const int* src = edge;
  const int* dst = edge + E;

  char* p = (char*)d_ws;
  auto alloc = [&](size_t bytes) { char* q = p; p += (bytes + 255) & ~(size_t)255; return q; };
  float* hA      = (float*)alloc((size_t)N * 128 * 4);
  float* hB      = (float*)alloc((size_t)N * 128 * 4);
  int*   cnt     = (int*)alloc((size_t)N * 4);
  int*   row_off = (int*)alloc((size_t)(N + 1) * 4);
  int*   cursor  = (int*)alloc((size_t)N * 4);
  float* dinv    = (float*)alloc((size_t)N * 4);
  int*   csr     = (int*)alloc((size_t)E * 4);
  int*   partial = (int*)alloc(((size_t)(N + 1023) / 1024) * 4);

  int nb = (N + 1023) / 1024;  // 98 scan blocks

  // graph prep
  zero_kernel<<<(N + 255) / 256, 256, 0, stream>>>(cnt, N);
  hist_kernel<<<(E + 255) / 256, 256, 0, stream>>>(dst, cnt, E);
  scan1_kernel<<<nb, 256, 0, stream>>>(cnt, partial, N);
  scan2_kernel<<<1, 128, 0, stream>>>(partial, nb);
  scan3_kernel<<<nb, 256, 0, stream>>>(cnt, partial, row_off, cursor, dinv, N);
  fill_kernel<<<(E + 255) / 256, 256, 0, stream>>>(src, dst, cursor, csr, E);

  int gemm_blocks = (N + 63) / 64;
  gemm_kernel<<<gemm_blocks, 256, 0, stream>>>(x, lin1_w, lin1_b, hA, N, 1);
  for (int k = 0; k < 3; k++) {
    gemm_kernel<<<gemm_blocks, 256, 0, stream>>>(hA, gcn_w + (size_t)k * 128 * 128, nullptr, hB, N, 0);
    aggregate_kernel<<<(N + 3) / 4, 256, 0, stream>>>(hB, row_off, csr, dinv,
                                                      gcn_b + (size_t)k * 128, hA, N);
  }
  head_kernel<<<(N + 3) / 4, 256, 0, stream>>>(hA, lin2_w, lin2_b, out, N);
}

// Round 3
// 1404.593 us; speedup vs baseline: 1.4762x; 1.2876x over previous
//
#include <hip/hip_runtime.h>
#include <math.h>

#define NN 100000
#define HIDC 128
#define OUTC 40

// bf16 pack/unpack (manual, RN) -------------------------------------------
__device__ __forceinline__ unsigned pack_bf16x2(float a, float b) {
  unsigned ua = __float_as_uint(a), ub = __float_as_uint(b);
  ua = ua + 0x7fff + ((ua >> 16) & 1);
  ub = ub + 0x7fff + ((ub >> 16) & 1);
  return (ua >> 16) | (ub & 0xffff0000u);
}
__device__ __forceinline__ float bf_lo(unsigned u) { return __uint_as_float(u << 16); }
__device__ __forceinline__ float bf_hi(unsigned u) { return __uint_as_float(u & 0xffff0000u); }

// ---------------- graph prep ----------------

__global__ void zero_kernel(int* __restrict__ p, int n) {
  int i = blockIdx.x * blockDim.x + threadIdx.x;
  if (i < n) p[i] = 0;
}

__global__ void hist_kernel(const int* __restrict__ dst, int* __restrict__ cnt, int E) {
  int i = blockIdx.x * blockDim.x + threadIdx.x;
  if (i < E) atomicAdd(&cnt[dst[i]], 1);
}

// ---- parallel exclusive scan over cnt[0..N): 3 dispatches ----

__global__ __launch_bounds__(256) void scan1_kernel(
    const int* __restrict__ cnt, int* __restrict__ partial, int N) {
  int b = blockIdx.x, t = threadIdx.x;
  int base = b * 1024 + t * 4;
  int s = 0;
#pragma unroll
  for (int j = 0; j < 4; j++) { int i = base + j; if (i < N) s += cnt[i]; }
  __shared__ int sums[256];
  sums[t] = s;
  __syncthreads();
  for (int off = 128; off > 0; off >>= 1) {
    if (t < off) sums[t] += sums[t + off];
    __syncthreads();
  }
  if (t == 0) partial[b] = sums[0];
}

__global__ __launch_bounds__(128) void scan2_kernel(int* __restrict__ partial, int nb) {
  __shared__ int sh[128];
  int t = threadIdx.x;
  int v = (t < nb) ? partial[t] : 0;
  sh[t] = v;
  __syncthreads();
  for (int off = 1; off < 128; off <<= 1) {
    int u = (t >= off) ? sh[t - off] : 0;
    __syncthreads();
    sh[t] += u;
    __syncthreads();
  }
  if (t < nb) partial[t] = sh[t] - v;  // exclusive
}

__global__ __launch_bounds__(256) void scan3_kernel(
    const int* __restrict__ cnt, const int* __restrict__ partial,
    int* __restrict__ row_off, int* __restrict__ cursor,
    float* __restrict__ dinv, int N) {
  int b = blockIdx.x, t = threadIdx.x;
  int base = b * 1024 + t * 4;
  int c[4]; int s = 0;
#pragma unroll
  for (int j = 0; j < 4; j++) { int i = base + j; c[j] = (i < N) ? cnt[i] : 0; s += c[j]; }
  __shared__ int sums[256];
  sums[t] = s;
  __syncthreads();
  for (int off = 1; off < 256; off <<= 1) {
    int u = (t >= off) ? sums[t - off] : 0;
    __syncthreads();
    sums[t] += u;
    __syncthreads();
  }
  int run = partial[b] + sums[t] - s;
#pragma unroll
  for (int j = 0; j < 4; j++) {
    int i = base + j;
    if (i < N) {
      row_off[i] = run;
      cursor[i] = run;
      dinv[i] = rsqrtf((float)(c[j] + 1));  // +1 self-loop
      run += c[j];
    }
  }
  if (b == gridDim.x - 1 && t == 255) row_off[N] = run;
}

__global__ void fill_kernel(const int* __restrict__ src, const int* __restrict__ dst,
                            int* __restrict__ cursor, int* __restrict__ csr, int E) {
  int i = blockIdx.x * blockDim.x + threadIdx.x;
  if (i < E) {
    int p = atomicAdd(&cursor[dst[i]], 1);
    csr[p] = src[i];
  }
}

// ---------------- GEMM (M x 128) @ (128 x 128) fp32 out, bias+relu ----------------

__global__ __launch_bounds__(256) void gemm_kernel(
    const float* __restrict__ X, const float* __restrict__ W,
    const float* __restrict__ bias, float* __restrict__ Y, int M, int relu) {
  __shared__ __align__(16) float Ws[128 * 128];
  __shared__ __align__(16) float Xs[64 * 128];
  int tx = threadIdx.x;
  int cg = tx & 31;
  int rg = tx >> 5;

  for (int i = tx; i < 4096; i += 256)
    ((float4*)Ws)[i] = ((const float4*)W)[i];

  int row0 = blockIdx.x * 64;
  int rows_here = M - row0; if (rows_here > 64) rows_here = 64;
  const float4* Xg = (const float4*)(X + (size_t)row0 * 128);
  for (int i = tx; i < rows_here * 32; i += 256)
    ((float4*)Xs)[i] = Xg[i];
  __syncthreads();

  float acc[8][4];
#pragma unroll
  for (int r = 0; r < 8; r++)
#pragma unroll
    for (int c = 0; c < 4; c++) acc[r][c] = 0.f;

  for (int k = 0; k < 128; k += 4) {
    float4 w0 = *(const float4*)&Ws[(k + 0) * 128 + cg * 4];
    float4 w1 = *(const float4*)&Ws[(k + 1) * 128 + cg * 4];
    float4 w2 = *(const float4*)&Ws[(k + 2) * 128 + cg * 4];
    float4 w3 = *(const float4*)&Ws[(k + 3) * 128 + cg * 4];
#pragma unroll
    for (int r = 0; r < 8; r++) {
      float4 xv = *(const float4*)&Xs[(rg * 8 + r) * 128 + k];
      acc[r][0] = fmaf(xv.x, w0.x, fmaf(xv.y, w1.x, fmaf(xv.z, w2.x, fmaf(xv.w, w3.x, acc[r][0]))));
      acc[r][1] = fmaf(xv.x, w0.y, fmaf(xv.y, w1.y, fmaf(xv.z, w2.y, fmaf(xv.w, w3.y, acc[r][1]))));
      acc[r][2] = fmaf(xv.x, w0.z, fmaf(xv.y, w1.z, fmaf(xv.z, w2.z, fmaf(xv.w, w3.z, acc[r][2]))));
      acc[r][3] = fmaf(xv.x, w0.w, fmaf(xv.y, w1.w, fmaf(xv.z, w2.w, fmaf(xv.w, w3.w, acc[r][3]))));
    }
  }

  float4 bv = make_float4(0.f, 0.f, 0.f, 0.f);
  if (bias) bv = ((const float4*)bias)[cg];
#pragma unroll
  for (int r = 0; r < 8; r++) {
    int row = row0 + rg * 8 + r;
    if (row < M) {
      float4 o;
      o.x = acc[r][0] + bv.x; o.y = acc[r][1] + bv.y;
      o.z = acc[r][2] + bv.z; o.w = acc[r][3] + bv.w;
      if (relu) {
        o.x = fmaxf(o.x, 0.f); o.y = fmaxf(o.y, 0.f);
        o.z = fmaxf(o.z, 0.f); o.w = fmaxf(o.w, 0.f);
      }
      *(float4*)&Y[(size_t)row * 128 + cg * 4] = o;
    }
  }
}

// ---- GEMM variant for GCN layers: Y16[row] = bf16( dinv[row] * (X@W)[row] ) ----
// output row = 64 uints (2 bf16 per uint); thread writes 2 uints (8 B).

__global__ __launch_bounds__(256) void gemm_scaled_bf16_kernel(
    const float* __restrict__ X, const float* __restrict__ W,
    const float* __restrict__ dinv, unsigned* __restrict__ Y16, int M) {
  __shared__ __align__(16) float Ws[128 * 128];
  __shared__ __align__(16) float Xs[64 * 128];
  int tx = threadIdx.x;
  int cg = tx & 31;
  int rg = tx >> 5;

  for (int i = tx; i < 4096; i += 256)
    ((float4*)Ws)[i] = ((const float4*)W)[i];

  int row0 = blockIdx.x * 64;
  int rows_here = M - row0; if (rows_here > 64) rows_here = 64;
  const float4* Xg = (const float4*)(X + (size_t)row0 * 128);
  for (int i = tx; i < rows_here * 32; i += 256)
    ((float4*)Xs)[i] = Xg[i];
  __syncthreads();

  float acc[8][4];
#pragma unroll
  for (int r = 0; r < 8; r++)
#pragma unroll
    for (int c = 0; c < 4; c++) acc[r][c] = 0.f;

  for (int k = 0; k < 128; k += 4) {
    float4 w0 = *(const float4*)&Ws[(k + 0) * 128 + cg * 4];
    float4 w1 = *(const float4*)&Ws[(k + 1) * 128 + cg * 4];
    float4 w2 = *(const float4*)&Ws[(k + 2) * 128 + cg * 4];
    float4 w3 = *(const float4*)&Ws[(k + 3) * 128 + cg * 4];
#pragma unroll
    for (int r = 0; r < 8; r++) {
      float4 xv = *(const float4*)&Xs[(rg * 8 + r) * 128 + k];
      acc[r][0] = fmaf(xv.x, w0.x, fmaf(xv.y, w1.x, fmaf(xv.z, w2.x, fmaf(xv.w, w3.x, acc[r][0]))));
      acc[r][1] = fmaf(xv.x, w0.y, fmaf(xv.y, w1.y, fmaf(xv.z, w2.y, fmaf(xv.w, w3.y, acc[r][1]))));
      acc[r][2] = fmaf(xv.x, w0.z, fmaf(xv.y, w1.z, fmaf(xv.z, w2.z, fmaf(xv.w, w3.z, acc[r][2]))));
      acc[r][3] = fmaf(xv.x, w0.w, fmaf(xv.y, w1.w, fmaf(xv.z, w2.w, fmaf(xv.w, w3.w, acc[r][3]))));
    }
  }

#pragma unroll
  for (int r = 0; r < 8; r++) {
    int row = row0 + rg * 8 + r;
    if (row < M) {
      float s = dinv[row];
      unsigned u0 = pack_bf16x2(acc[r][0] * s, acc[r][1] * s);
      unsigned u1 = pack_bf16x2(acc[r][2] * s, acc[r][3] * s);
      unsigned* yp = Y16 + (size_t)row * 64 + cg * 2;
      yp[0] = u0; yp[1] = u1;
    }
  }
}

// ---------------- aggregation: pull over dst-CSR, bf16 gathers, fp32 accum ----------------
// out[d] = relu( dinv[d] * ( sum_{s in csr[d]} scaledH[s] + scaledH[d] ) + b )
// one 64-lane wave per node; lane holds 2 cols (one uint = 2 bf16). Row = 256 B.

__global__ __launch_bounds__(256) void aggregate_bf16_kernel(
    const unsigned* __restrict__ Ht16, const int* __restrict__ row_off,
    const int* __restrict__ csr, const float* __restrict__ dinv,
    const float* __restrict__ bias, float* __restrict__ Out, int N) {
  int wave = (blockIdx.x * blockDim.x + threadIdx.x) >> 6;
  int lane = threadIdx.x & 63;
  if (wave >= N) return;
  int d = wave;
  int beg = row_off[d], end = row_off[d + 1];
  float ax = 0.f, ay = 0.f;
  int e = beg;
  for (; e + 3 < end; e += 4) {
    int s0 = csr[e], s1 = csr[e + 1], s2 = csr[e + 2], s3 = csr[e + 3];
    unsigned u0 = Ht16[(size_t)s0 * 64 + lane];
    unsigned u1 = Ht16[(size_t)s1 * 64 + lane];
    unsigned u2 = Ht16[(size_t)s2 * 64 + lane];
    unsigned u3 = Ht16[(size_t)s3 * 64 + lane];
    ax += bf_lo(u0); ay += bf_hi(u0);
    ax += bf_lo(u1); ay += bf_hi(u1);
    ax += bf_lo(u2); ay += bf_hi(u2);
    ax += bf_lo(u3); ay += bf_hi(u3);
  }
  for (; e < end; e++) {
    unsigned u0 = Ht16[(size_t)csr[e] * 64 + lane];
    ax += bf_lo(u0); ay += bf_hi(u0);
  }
  // self loop: scaledH[d] already carries dinv[d]
  unsigned us = Ht16[(size_t)d * 64 + lane];
  ax += bf_lo(us); ay += bf_hi(us);

  float dd = dinv[d];
  float2 b2 = ((const float2*)bias)[lane];
  float ox = fmaf(dd, ax, b2.x);
  float oy = fmaf(dd, ay, b2.y);
  ox = fmaxf(ox, 0.f); oy = fmaxf(oy, 0.f);
  float2 o; o.x = ox; o.y = oy;
  ((float2*)Out)[(size_t)d * 64 + lane] = o;
}

// ---------------- head: logits = H @ W2 + b2, then log_softmax per row ----------------

__device__ __forceinline__ float wave_max(float v) {
#pragma unroll
  for (int off = 32; off > 0; off >>= 1) v = fmaxf(v, __shfl_xor(v, off, 64));
  return v;
}
__device__ __forceinline__ float wave_sum(float v) {
#pragma unroll
  for (int off = 32; off > 0; off >>= 1) v += __shfl_xor(v, off, 64);
  return v;
}

__global__ __launch_bounds__(256) void head_kernel(
    const float* __restrict__ H, const float* __restrict__ W2,
    const float* __restrict__ b2, float* __restrict__ Out, int N) {
  __shared__ __align__(16) float Ws[128 * OUTC];
  __shared__ float bs[OUTC];
  int t = threadIdx.x;
  for (int i = t; i < 128 * OUTC; i += 256) Ws[i] = W2[i];
  if (t < OUTC) bs[t] = b2[t];
  __syncthreads();
  int row = blockIdx.x * 4 + (t >> 6);
  if (row >= N) return;
  int lane = t & 63;
  int c = (lane < OUTC) ? lane : (OUTC - 1);
  const float4* h4 = (const float4*)(H + (size_t)row * 128);
  float logit = bs[c];
  for (int k4 = 0; k4 < 32; k4++) {
    float4 hv = h4[k4];
    int k = k4 * 4;
    logit = fmaf(hv.x, Ws[(k + 0) * OUTC + c],
            fmaf(hv.y, Ws[(k + 1) * OUTC + c],
            fmaf(hv.z, Ws[(k + 2) * OUTC + c],
            fmaf(hv.w, Ws[(k + 3) * OUTC + c], logit))));
  }
  float v = (lane < OUTC) ? logit : -3.4e38f;
  float m = wave_max(v);
  float ex = (lane < OUTC) ? expf(logit - m) : 0.f;
  float s = wave_sum(ex);
  if (lane < OUTC) Out[(size_t)row * OUTC + lane] = logit - m - logf(s);
}

// ---------------- launch ----------------

extern "C" void kernel_launch(void* const* d_in, const int* in_sizes, int n_in,
                              void* d_out, int out_size, void* d_ws, size_t ws_size,
                              hipStream_t stream) {
  const float* x      = (const float*)d_in[0];
  const int*   edge   = (const int*)d_in[1];
  const float* lin1_w = (const float*)d_in[2];
  const float* lin1_b = (const float*)d_in[3];
  const float* gcn_w  = (const float*)d_in[4];
  const float* gcn_b  = (const float*)d_in[5];
  const float* lin2_w = (const float*)d_in[6];
  const float* lin2_b = (const float*)d_in[7];
  float* out = (float*)d_out;

  const int N = NN;
  const int E = in_sizes[1] / 2;  // 3,200,000
  const int* src = edge;
  const int* dst = edge + E;

  char* p = (char*)d_ws;
  auto alloc = [&](size_t bytes) { char* q = p; p += (bytes + 255) & ~(size_t)255; return q; };
  float*    hA      = (float*)alloc((size_t)N * 128 * 4);
  unsigned* hB16    = (unsigned*)alloc((size_t)N * 64 * 4);
  int*      cnt     = (int*)alloc((size_t)N * 4);
  int*      row_off = (int*)alloc((size_t)(N + 1) * 4);
  int*      cursor  = (int*)alloc((size_t)N * 4);
  float*    dinv    = (float*)alloc((size_t)N * 4);
  int*      csr     = (int*)alloc((size_t)E * 4);
  int*      partial = (int*)alloc(((size_t)(N + 1023) / 1024) * 4);

  int nb = (N + 1023) / 1024;

  // graph prep
  zero_kernel<<<(N + 255) / 256, 256, 0, stream>>>(cnt, N);
  hist_kernel<<<(E + 255) / 256, 256, 0, stream>>>(dst, cnt, E);
  scan1_kernel<<<nb, 256, 0, stream>>>(cnt, partial, N);
  scan2_kernel<<<1, 128, 0, stream>>>(partial, nb);
  scan3_kernel<<<nb, 256, 0, stream>>>(cnt, partial, row_off, cursor, dinv, N);
  fill_kernel<<<(E + 255) / 256, 256, 0, stream>>>(src, dst, cursor, csr, E);

  int gemm_blocks = (N + 63) / 64;
  gemm_kernel<<<gemm_blocks, 256, 0, stream>>>(x, lin1_w, lin1_b, hA, N, 1);
  for (int k = 0; k < 3; k++) {
    gemm_scaled_bf16_kernel<<<gemm_blocks, 256, 0, stream>>>(
        hA, gcn_w + (size_t)k * 128 * 128, dinv, hB16, N);
    aggregate_bf16_kernel<<<(N + 3) / 4, 256, 0, stream>>>(
        hB16, row_off, csr, dinv, gcn_b + (size_t)k * 128, hA, N);
  }
  head_kernel<<<(N + 3) / 4, 256, 0, stream>>>(hA, lin2_w, lin2_b, out, N);
}

// Round 4
// 1206.123 us; speedup vs baseline: 1.7191x; 1.1646x over previous
//
#include <hip/hip_runtime.h>
#include <math.h>

#define NN 100000
#define HIDC 128
#define OUTC 40
#define NBUCK ((NN + 511) >> 9)   // 196 buckets of 512 dst nodes
#define PT_TILE 8192

// bf16 pack/unpack (manual, RN) -------------------------------------------
__device__ __forceinline__ unsigned pack_bf16x2(float a, float b) {
  unsigned ua = __float_as_uint(a), ub = __float_as_uint(b);
  ua = ua + 0x7fff + ((ua >> 16) & 1);
  ub = ub + 0x7fff + ((ub >> 16) & 1);
  return (ua >> 16) | (ub & 0xffff0000u);
}
__device__ __forceinline__ float bf_lo(unsigned u) { return __uint_as_float(u << 16); }
__device__ __forceinline__ float bf_hi(unsigned u) { return __uint_as_float(u & 0xffff0000u); }

// ---------------- graph prep ----------------

__global__ void zero_kernel(int* __restrict__ p, int n) {
  int i = blockIdx.x * blockDim.x + threadIdx.x;
  if (i < n) p[i] = 0;
}

__global__ void hist_kernel(const int* __restrict__ dst, int* __restrict__ cnt, int E) {
  int i = blockIdx.x * blockDim.x + threadIdx.x;
  if (i < E) atomicAdd(&cnt[dst[i]], 1);
}

// ---- parallel exclusive scan over cnt[0..N): 3 dispatches ----

__global__ __launch_bounds__(256) void scan1_kernel(
    const int* __restrict__ cnt, int* __restrict__ partial, int N) {
  int b = blockIdx.x, t = threadIdx.x;
  int base = b * 1024 + t * 4;
  int s = 0;
#pragma unroll
  for (int j = 0; j < 4; j++) { int i = base + j; if (i < N) s += cnt[i]; }
  __shared__ int sums[256];
  sums[t] = s;
  __syncthreads();
  for (int off = 128; off > 0; off >>= 1) {
    if (t < off) sums[t] += sums[t + off];
    __syncthreads();
  }
  if (t == 0) partial[b] = sums[0];
}

__global__ __launch_bounds__(128) void scan2_kernel(int* __restrict__ partial, int nb) {
  __shared__ int sh[128];
  int t = threadIdx.x;
  int v = (t < nb) ? partial[t] : 0;
  sh[t] = v;
  __syncthreads();
  for (int off = 1; off < 128; off <<= 1) {
    int u = (t >= off) ? sh[t - off] : 0;
    __syncthreads();
    sh[t] += u;
    __syncthreads();
  }
  if (t < nb) partial[t] = sh[t] - v;  // exclusive
}

__global__ __launch_bounds__(256) void scan3_kernel(
    const int* __restrict__ cnt, const int* __restrict__ partial,
    int* __restrict__ row_off, float* __restrict__ dinv, int N) {
  int b = blockIdx.x, t = threadIdx.x;
  int base = b * 1024 + t * 4;
  int c[4]; int s = 0;
#pragma unroll
  for (int j = 0; j < 4; j++) { int i = base + j; c[j] = (i < N) ? cnt[i] : 0; s += c[j]; }
  __shared__ int sums[256];
  sums[t] = s;
  __syncthreads();
  for (int off = 1; off < 256; off <<= 1) {
    int u = (t >= off) ? sums[t - off] : 0;
    __syncthreads();
    sums[t] += u;
    __syncthreads();
  }
  int run = partial[b] + sums[t] - s;
#pragma unroll
  for (int j = 0; j < 4; j++) {
    int i = base + j;
    if (i < N) {
      row_off[i] = run;
      dinv[i] = rsqrtf((float)(c[j] + 1));  // +1 self-loop
      run += c[j];
    }
  }
  if (b == gridDim.x - 1 && t == 255) row_off[N] = run;
}

__global__ void init_bcur_kernel(const int* __restrict__ row_off, int* __restrict__ bcur) {
  int t = blockIdx.x * blockDim.x + threadIdx.x;
  if (t < NBUCK) bcur[t] = row_off[t << 9];
}

// ---- phase 1: partition edges into 196 dst-buckets (packed uint32) ----
// pack = (dst & 511) << 17 | src   (src < 2^17)
// Each tile reserves one run per bucket via a single global atomic, then
// writes into the run: ~170 B regions filled by one block -> full-line WBs.

__global__ __launch_bounds__(256) void partition_kernel(
    const int* __restrict__ src, const int* __restrict__ dst,
    int* __restrict__ bcur, unsigned* __restrict__ pairs, int E) {
  __shared__ int hist[256];
  __shared__ int base[256];
  __shared__ int lcur[256];
  int t = threadIdx.x;
  hist[t] = 0; lcur[t] = 0;
  __syncthreads();
  int e0 = blockIdx.x * PT_TILE;
  int ec = E - e0; if (ec > PT_TILE) ec = PT_TILE;
  for (int i = t; i < ec; i += 256)
    atomicAdd(&hist[dst[e0 + i] >> 9], 1);
  __syncthreads();
  if (hist[t] > 0) base[t] = atomicAdd(&bcur[t], hist[t]);
  __syncthreads();
  for (int i = t; i < ec; i += 256) {
    int d = dst[e0 + i], s = src[e0 + i];
    int b = d >> 9;
    int pos = atomicAdd(&lcur[b], 1);
    pairs[base[b] + pos] = ((unsigned)(d & 511) << 17) | (unsigned)s;
  }
}

// ---- phase 2: within-bucket counting sort -> csr, LDS cursors ----
// One block per bucket; scatter confined to the bucket's ~65 KB csr window.

__global__ __launch_bounds__(256) void bucket_fill_kernel(
    const unsigned* __restrict__ pairs, const int* __restrict__ row_off,
    int* __restrict__ csr, int N) {
  int b = blockIdx.x;
  int d0 = b << 9;
  int nd = N - d0; if (nd > 512) nd = 512;
  __shared__ int cur[512];
  int t = threadIdx.x;
  for (int j = t; j < nd; j += 256) cur[j] = row_off[d0 + j];
  __syncthreads();
  int hi = d0 + 512; if (hi > N) hi = N;
  int beg = row_off[d0];
  int end = row_off[hi];
  for (int i = beg + t; i < end; i += 256) {
    unsigned pk = pairs[i];
    int s = pk & 0x1FFFF;
    int ld = pk >> 17;
    int q = atomicAdd(&cur[ld], 1);
    csr[q] = s;
  }
}

// ---------------- GEMM (M x 128) @ (128 x 128) fp32 out, bias+relu ----------------

__global__ __launch_bounds__(256) void gemm_kernel(
    const float* __restrict__ X, const float* __restrict__ W,
    const float* __restrict__ bias, float* __restrict__ Y, int M, int relu) {
  __shared__ __align__(16) float Ws[128 * 128];
  __shared__ __align__(16) float Xs[64 * 128];
  int tx = threadIdx.x;
  int cg = tx & 31;
  int rg = tx >> 5;

  for (int i = tx; i < 4096; i += 256)
    ((float4*)Ws)[i] = ((const float4*)W)[i];

  int row0 = blockIdx.x * 64;
  int rows_here = M - row0; if (rows_here > 64) rows_here = 64;
  const float4* Xg = (const float4*)(X + (size_t)row0 * 128);
  for (int i = tx; i < rows_here * 32; i += 256)
    ((float4*)Xs)[i] = Xg[i];
  __syncthreads();

  float acc[8][4];
#pragma unroll
  for (int r = 0; r < 8; r++)
#pragma unroll
    for (int c = 0; c < 4; c++) acc[r][c] = 0.f;

  for (int k = 0; k < 128; k += 4) {
    float4 w0 = *(const float4*)&Ws[(k + 0) * 128 + cg * 4];
    float4 w1 = *(const float4*)&Ws[(k + 1) * 128 + cg * 4];
    float4 w2 = *(const float4*)&Ws[(k + 2) * 128 + cg * 4];
    float4 w3 = *(const float4*)&Ws[(k + 3) * 128 + cg * 4];
#pragma unroll
    for (int r = 0; r < 8; r++) {
      float4 xv = *(const float4*)&Xs[(rg * 8 + r) * 128 + k];
      acc[r][0] = fmaf(xv.x, w0.x, fmaf(xv.y, w1.x, fmaf(xv.z, w2.x, fmaf(xv.w, w3.x, acc[r][0]))));
      acc[r][1] = fmaf(xv.x, w0.y, fmaf(xv.y, w1.y, fmaf(xv.z, w2.y, fmaf(xv.w, w3.y, acc[r][1]))));
      acc[r][2] = fmaf(xv.x, w0.z, fmaf(xv.y, w1.z, fmaf(xv.z, w2.z, fmaf(xv.w, w3.z, acc[r][2]))));
      acc[r][3] = fmaf(xv.x, w0.w, fmaf(xv.y, w1.w, fmaf(xv.z, w2.w, fmaf(xv.w, w3.w, acc[r][3]))));
    }
  }

  float4 bv = make_float4(0.f, 0.f, 0.f, 0.f);
  if (bias) bv = ((const float4*)bias)[cg];
#pragma unroll
  for (int r = 0; r < 8; r++) {
    int row = row0 + rg * 8 + r;
    if (row < M) {
      float4 o;
      o.x = acc[r][0] + bv.x; o.y = acc[r][1] + bv.y;
      o.z = acc[r][2] + bv.z; o.w = acc[r][3] + bv.w;
      if (relu) {
        o.x = fmaxf(o.x, 0.f); o.y = fmaxf(o.y, 0.f);
        o.z = fmaxf(o.z, 0.f); o.w = fmaxf(o.w, 0.f);
      }
      *(float4*)&Y[(size_t)row * 128 + cg * 4] = o;
    }
  }
}

// ---- GEMM variant for GCN layers: Y16[row] = bf16( dinv[row] * (X@W)[row] ) ----

__global__ __launch_bounds__(256) void gemm_scaled_bf16_kernel(
    const float* __restrict__ X, const float* __restrict__ W,
    const float* __restrict__ dinv, unsigned* __restrict__ Y16, int M) {
  __shared__ __align__(16) float Ws[128 * 128];
  __shared__ __align__(16) float Xs[64 * 128];
  int tx = threadIdx.x;
  int cg = tx & 31;
  int rg = tx >> 5;

  for (int i = tx; i < 4096; i += 256)
    ((float4*)Ws)[i] = ((const float4*)W)[i];

  int row0 = blockIdx.x * 64;
  int rows_here = M - row0; if (rows_here > 64) rows_here = 64;
  const float4* Xg = (const float4*)(X + (size_t)row0 * 128);
  for (int i = tx; i < rows_here * 32; i += 256)
    ((float4*)Xs)[i] = Xg[i];
  __syncthreads();

  float acc[8][4];
#pragma unroll
  for (int r = 0; r < 8; r++)
#pragma unroll
    for (int c = 0; c < 4; c++) acc[r][c] = 0.f;

  for (int k = 0; k < 128; k += 4) {
    float4 w0 = *(const float4*)&Ws[(k + 0) * 128 + cg * 4];
    float4 w1 = *(const float4*)&Ws[(k + 1) * 128 + cg * 4];
    float4 w2 = *(const float4*)&Ws[(k + 2) * 128 + cg * 4];
    float4 w3 = *(const float4*)&Ws[(k + 3) * 128 + cg * 4];
#pragma unroll
    for (int r = 0; r < 8; r++) {
      float4 xv = *(const float4*)&Xs[(rg * 8 + r) * 128 + k];
      acc[r][0] = fmaf(xv.x, w0.x, fmaf(xv.y, w1.x, fmaf(xv.z, w2.x, fmaf(xv.w, w3.x, acc[r][0]))));
      acc[r][1] = fmaf(xv.x, w0.y, fmaf(xv.y, w1.y, fmaf(xv.z, w2.y, fmaf(xv.w, w3.y, acc[r][1]))));
      acc[r][2] = fmaf(xv.x, w0.z, fmaf(xv.y, w1.z, fmaf(xv.z, w2.z, fmaf(xv.w, w3.z, acc[r][2]))));
      acc[r][3] = fmaf(xv.x, w0.w, fmaf(xv.y, w1.w, fmaf(xv.z, w2.w, fmaf(xv.w, w3.w, acc[r][3]))));
    }
  }

#pragma unroll
  for (int r = 0; r < 8; r++) {
    int row = row0 + rg * 8 + r;
    if (row < M) {
      float s = dinv[row];
      unsigned u0 = pack_bf16x2(acc[r][0] * s, acc[r][1] * s);
      unsigned u1 = pack_bf16x2(acc[r][2] * s, acc[r][3] * s);
      unsigned* yp = Y16 + (size_t)row * 64 + cg * 2;
      yp[0] = u0; yp[1] = u1;
    }
  }
}

// ---------------- aggregation: pull over dst-CSR, bf16 gathers, fp32 accum ----------------

__global__ __launch_bounds__(256) void aggregate_bf16_kernel(
    const unsigned* __restrict__ Ht16, const int* __restrict__ row_off,
    const int* __restrict__ csr, const float* __restrict__ dinv,
    const float* __restrict__ bias, float* __restrict__ Out, int N) {
  int wave = (blockIdx.x * blockDim.x + threadIdx.x) >> 6;
  int lane = threadIdx.x & 63;
  if (wave >= N) return;
  int d = wave;
  int beg = row_off[d], end = row_off[d + 1];
  float ax = 0.f, ay = 0.f;
  int e = beg;
  for (; e + 3 < end; e += 4) {
    int s0 = csr[e], s1 = csr[e + 1], s2 = csr[e + 2], s3 = csr[e + 3];
    unsigned u0 = Ht16[(size_t)s0 * 64 + lane];
    unsigned u1 = Ht16[(size_t)s1 * 64 + lane];
    unsigned u2 = Ht16[(size_t)s2 * 64 + lane];
    unsigned u3 = Ht16[(size_t)s3 * 64 + lane];
    ax += bf_lo(u0); ay += bf_hi(u0);
    ax += bf_lo(u1); ay += bf_hi(u1);
    ax += bf_lo(u2); ay += bf_hi(u2);
    ax += bf_lo(u3); ay += bf_hi(u3);
  }
  for (; e < end; e++) {
    unsigned u0 = Ht16[(size_t)csr[e] * 64 + lane];
    ax += bf_lo(u0); ay += bf_hi(u0);
  }
  unsigned us = Ht16[(size_t)d * 64 + lane];
  ax += bf_lo(us); ay += bf_hi(us);

  float dd = dinv[d];
  float2 b2 = ((const float2*)bias)[lane];
  float ox = fmaf(dd, ax, b2.x);
  float oy = fmaf(dd, ay, b2.y);
  ox = fmaxf(ox, 0.f); oy = fmaxf(oy, 0.f);
  float2 o; o.x = ox; o.y = oy;
  ((float2*)Out)[(size_t)d * 64 + lane] = o;
}

// ---------------- head: logits = H @ W2 + b2, then log_softmax per row ----------------

__device__ __forceinline__ float wave_max(float v) {
#pragma unroll
  for (int off = 32; off > 0; off >>= 1) v = fmaxf(v, __shfl_xor(v, off, 64));
  return v;
}
__device__ __forceinline__ float wave_sum(float v) {
#pragma unroll
  for (int off = 32; off > 0; off >>= 1) v += __shfl_xor(v, off, 64);
  return v;
}

__global__ __launch_bounds__(256) void head_kernel(
    const float* __restrict__ H, const float* __restrict__ W2,
    const float* __restrict__ b2, float* __restrict__ Out, int N) {
  __shared__ __align__(16) float Ws[128 * OUTC];
  __shared__ float bs[OUTC];
  int t = threadIdx.x;
  for (int i = t; i < 128 * OUTC; i += 256) Ws[i] = W2[i];
  if (t < OUTC) bs[t] = b2[t];
  __syncthreads();
  int row = blockIdx.x * 4 + (t >> 6);
  if (row >= N) return;
  int lane = t & 63;
  int c = (lane < OUTC) ? lane : (OUTC - 1);
  const float4* h4 = (const float4*)(H + (size_t)row * 128);
  float logit = bs[c];
  for (int k4 = 0; k4 < 32; k4++) {
    float4 hv = h4[k4];
    int k = k4 * 4;
    logit = fmaf(hv.x, Ws[(k + 0) * OUTC + c],
            fmaf(hv.y, Ws[(k + 1) * OUTC + c],
            fmaf(hv.z, Ws[(k + 2) * OUTC + c],
            fmaf(hv.w, Ws[(k + 3) * OUTC + c], logit))));
  }
  float v = (lane < OUTC) ? logit : -3.4e38f;
  float m = wave_max(v);
  float ex = (lane < OUTC) ? expf(logit - m) : 0.f;
  float s = wave_sum(ex);
  if (lane < OUTC) Out[(size_t)row * OUTC + lane] = logit - m - logf(s);
}

// ---------------- launch ----------------

extern "C" void kernel_launch(void* const* d_in, const int* in_sizes, int n_in,
                              void* d_out, int out_size, void* d_ws, size_t ws_size,
                              hipStream_t stream) {
  const float* x      = (const float*)d_in[0];
  const int*   edge   = (const int*)d_in[1];
  const float* lin1_w = (const float*)d_in[2];
  const float* lin1_b = (const float*)d_in[3];
  const float* gcn_w  = (const float*)d_in[4];
  const float* gcn_b  = (const float*)d_in[5];
  const float* lin2_w = (const float*)d_in[6];
  const float* lin2_b = (const float*)d_in[7];
  float* out = (float*)d_out;

  const int N = NN;
  const int E = in_sizes[1] / 2;  // 3,200,000
  const int* src = edge;
  const int* dst = edge + E;

  char* p = (char*)d_ws;
  auto alloc = [&](size_t bytes) { char* q = p; p += (bytes + 255) & ~(size_t)255; return q; };
  float*    hA      = (float*)alloc((size_t)N * 128 * 4);
  unsigned* hB16    = (unsigned*)alloc((size_t)N * 64 * 4);
  int*      cnt     = (int*)alloc((size_t)N * 4);
  int*      row_off = (int*)alloc((size_t)(N + 1) * 4);
  float*    dinv    = (float*)alloc((size_t)N * 4);
  int*      csr     = (int*)alloc((size_t)E * 4);
  int*      partial = (int*)alloc(((size_t)(N + 1023) / 1024) * 4);
  int*      bcur    = (int*)alloc(256 * 4);
  // pairs aliases hB16: graph prep finishes before the first gemm writes hB16.
  unsigned* pairs   = hB16;

  int nb = (N + 1023) / 1024;

  // graph prep
  zero_kernel<<<(N + 255) / 256, 256, 0, stream>>>(cnt, N);
  hist_kernel<<<(E + 255) / 256, 256, 0, stream>>>(dst, cnt, E);
  scan1_kernel<<<nb, 256, 0, stream>>>(cnt, partial, N);
  scan2_kernel<<<1, 128, 0, stream>>>(partial, nb);
  scan3_kernel<<<nb, 256, 0, stream>>>(cnt, partial, row_off, dinv, N);
  init_bcur_kernel<<<1, 256, 0, stream>>>(row_off, bcur);
  partition_kernel<<<(E + PT_TILE - 1) / PT_TILE, 256, 0, stream>>>(src, dst, bcur, pairs, E);
  bucket_fill_kernel<<<NBUCK, 256, 0, stream>>>(pairs, row_off, csr, N);

  int gemm_blocks = (N + 63) / 64;
  gemm_kernel<<<gemm_blocks, 256, 0, stream>>>(x, lin1_w, lin1_b, hA, N, 1);
  for (int k = 0; k < 3; k++) {
    gemm_scaled_bf16_kernel<<<gemm_blocks, 256, 0, stream>>>(
        hA, gcn_w + (size_t)k * 128 * 128, dinv, hB16, N);
    aggregate_bf16_kernel<<<(N + 3) / 4, 256, 0, stream>>>(
        hB16, row_off, csr, dinv, gcn_b + (size_t)k * 128, hA, N);
  }
  head_kernel<<<(N + 3) / 4, 256, 0, stream>>>(hA, lin2_w, lin2_b, out, N);
}

// Round 5
// 1104.944 us; speedup vs baseline: 1.8765x; 1.0916x over previous
//
#include <hip/hip_runtime.h>
#include <math.h>

#define NN 100000
#define HIDC 128
#define OUTC 40
#define NBUCK ((NN + 511) >> 9)   // 196 buckets of 512 dst nodes
#define PT_TILE 8192

// bf16 pack/unpack (manual, RN) -------------------------------------------
__device__ __forceinline__ unsigned pack_bf16x2(float a, float b) {
  unsigned ua = __float_as_uint(a), ub = __float_as_uint(b);
  ua = ua + 0x7fff + ((ua >> 16) & 1);
  ub = ub + 0x7fff + ((ub >> 16) & 1);
  return (ua >> 16) | (ub & 0xffff0000u);
}
__device__ __forceinline__ float bf_lo(unsigned u) { return __uint_as_float(u << 16); }
__device__ __forceinline__ float bf_hi(unsigned u) { return __uint_as_float(u & 0xffff0000u); }

// ---------------- graph prep (bucket-based, no per-node global atomics) ----------------

__global__ void zero_small_kernel(int* __restrict__ p, int n) {
  int i = threadIdx.x;
  if (i < n) p[i] = 0;
}

// per-tile LDS histogram over 196 buckets -> global bucket counts
__global__ __launch_bounds__(256) void tilehist_kernel(
    const int* __restrict__ dst, int* __restrict__ bc, int E) {
  __shared__ int hist[256];
  int t = threadIdx.x;
  hist[t] = 0;
  __syncthreads();
  int e0 = blockIdx.x * PT_TILE;
  int ec = E - e0; if (ec > PT_TILE) ec = PT_TILE;
  for (int i = t; i < ec; i += 256)
    atomicAdd(&hist[dst[e0 + i] >> 9], 1);
  __syncthreads();
  if (t < NBUCK && hist[t] > 0) atomicAdd(&bc[t], hist[t]);
}

// single block: exclusive scan of bc[NBUCK] -> bbase, bcur; row_off[N] = E
__global__ __launch_bounds__(256) void bucket_scan_kernel(
    const int* __restrict__ bc, int* __restrict__ bbase, int* __restrict__ bcur,
    int* __restrict__ row_off, int N, int E) {
  __shared__ int sh[256];
  int t = threadIdx.x;
  int v = (t < NBUCK) ? bc[t] : 0;
  sh[t] = v;
  __syncthreads();
  for (int off = 1; off < 256; off <<= 1) {
    int u = (t >= off) ? sh[t - off] : 0;
    __syncthreads();
    sh[t] += u;
    __syncthreads();
  }
  if (t < NBUCK) { int ex = sh[t] - v; bbase[t] = ex; bcur[t] = ex; }
  if (t == 0) { bbase[NBUCK] = E; row_off[N] = E; }
}

// ---- phase 1: partition edges into 196 dst-buckets (packed uint32) ----
// pack = (dst & 511) << 17 | src   (src < 2^17; N=100000 < 131072)

__global__ __launch_bounds__(256) void partition_kernel(
    const int* __restrict__ src, const int* __restrict__ dst,
    int* __restrict__ bcur, unsigned* __restrict__ pairs, int E) {
  __shared__ int hist[256];
  __shared__ int base[256];
  __shared__ int lcur[256];
  int t = threadIdx.x;
  hist[t] = 0; lcur[t] = 0;
  __syncthreads();
  int e0 = blockIdx.x * PT_TILE;
  int ec = E - e0; if (ec > PT_TILE) ec = PT_TILE;
  for (int i = t; i < ec; i += 256)
    atomicAdd(&hist[dst[e0 + i] >> 9], 1);
  __syncthreads();
  if (hist[t] > 0) base[t] = atomicAdd(&bcur[t], hist[t]);
  __syncthreads();
  for (int i = t; i < ec; i += 256) {
    int d = dst[e0 + i], s = src[e0 + i];
    int b = d >> 9;
    int pos = atomicAdd(&lcur[b], 1);
    pairs[base[b] + pos] = ((unsigned)(d & 511) << 17) | (unsigned)s;
  }
}

// ---- phase 2: per-bucket LDS hist(512) + scan -> row_off/dinv, then csr scatter ----
// One block per bucket; pairs run is L2-resident across the two passes.

__global__ __launch_bounds__(256) void bucket_fill_kernel(
    const unsigned* __restrict__ pairs, const int* __restrict__ bbase,
    int* __restrict__ row_off, float* __restrict__ dinv,
    int* __restrict__ csr, int N) {
  int b = blockIdx.x;
  int d0 = b << 9;
  int nd = N - d0; if (nd > 512) nd = 512;
  __shared__ int hist[512];
  __shared__ int cur[512];
  __shared__ int sums[256];
  int t = threadIdx.x;
  hist[t] = 0; hist[t + 256] = 0;
  __syncthreads();
  int rbeg = bbase[b], rend = bbase[b + 1];
  for (int i = rbeg + t; i < rend; i += 256)
    atomicAdd(&hist[pairs[i] >> 17], 1);
  __syncthreads();
  // 512-elem exclusive scan: thread t handles elems 2t, 2t+1
  int h0 = hist[2 * t], h1 = hist[2 * t + 1];
  int s = h0 + h1;
  sums[t] = s;
  __syncthreads();
  for (int off = 1; off < 256; off <<= 1) {
    int u = (t >= off) ? sums[t - off] : 0;
    __syncthreads();
    sums[t] += u;
    __syncthreads();
  }
  int base0 = rbeg + sums[t] - s;
  int base1 = base0 + h0;
  int j0 = 2 * t, j1 = 2 * t + 1;
  if (j0 < nd) {
    row_off[d0 + j0] = base0;
    dinv[d0 + j0] = rsqrtf((float)(h0 + 1));
    cur[j0] = base0;
  }
  if (j1 < nd) {
    row_off[d0 + j1] = base1;
    dinv[d0 + j1] = rsqrtf((float)(h1 + 1));
    cur[j1] = base1;
  }
  __syncthreads();
  for (int i = rbeg + t; i < rend; i += 256) {
    unsigned pk = pairs[i];
    int q = atomicAdd(&cur[pk >> 17], 1);
    csr[q] = pk & 0x1FFFF;
  }
}

// ---------------- GEMM (M x 128) @ (128 x 128) fp32 out, bias+relu ----------------

__global__ __launch_bounds__(256) void gemm_kernel(
    const float* __restrict__ X, const float* __restrict__ W,
    const float* __restrict__ bias, float* __restrict__ Y, int M, int relu) {
  __shared__ __align__(16) float Ws[128 * 128];
  __shared__ __align__(16) float Xs[64 * 128];
  int tx = threadIdx.x;
  int cg = tx & 31;
  int rg = tx >> 5;

  for (int i = tx; i < 4096; i += 256)
    ((float4*)Ws)[i] = ((const float4*)W)[i];

  int row0 = blockIdx.x * 64;
  int rows_here = M - row0; if (rows_here > 64) rows_here = 64;
  const float4* Xg = (const float4*)(X + (size_t)row0 * 128);
  for (int i = tx; i < rows_here * 32; i += 256)
    ((float4*)Xs)[i] = Xg[i];
  __syncthreads();

  float acc[8][4];
#pragma unroll
  for (int r = 0; r < 8; r++)
#pragma unroll
    for (int c = 0; c < 4; c++) acc[r][c] = 0.f;

  for (int k = 0; k < 128; k += 4) {
    float4 w0 = *(const float4*)&Ws[(k + 0) * 128 + cg * 4];
    float4 w1 = *(const float4*)&Ws[(k + 1) * 128 + cg * 4];
    float4 w2 = *(const float4*)&Ws[(k + 2) * 128 + cg * 4];
    float4 w3 = *(const float4*)&Ws[(k + 3) * 128 + cg * 4];
#pragma unroll
    for (int r = 0; r < 8; r++) {
      float4 xv = *(const float4*)&Xs[(rg * 8 + r) * 128 + k];
      acc[r][0] = fmaf(xv.x, w0.x, fmaf(xv.y, w1.x, fmaf(xv.z, w2.x, fmaf(xv.w, w3.x, acc[r][0]))));
      acc[r][1] = fmaf(xv.x, w0.y, fmaf(xv.y, w1.y, fmaf(xv.z, w2.y, fmaf(xv.w, w3.y, acc[r][1]))));
      acc[r][2] = fmaf(xv.x, w0.z, fmaf(xv.y, w1.z, fmaf(xv.z, w2.z, fmaf(xv.w, w3.z, acc[r][2]))));
      acc[r][3] = fmaf(xv.x, w0.w, fmaf(xv.y, w1.w, fmaf(xv.z, w2.w, fmaf(xv.w, w3.w, acc[r][3]))));
    }
  }

  float4 bv = make_float4(0.f, 0.f, 0.f, 0.f);
  if (bias) bv = ((const float4*)bias)[cg];
#pragma unroll
  for (int r = 0; r < 8; r++) {
    int row = row0 + rg * 8 + r;
    if (row < M) {
      float4 o;
      o.x = acc[r][0] + bv.x; o.y = acc[r][1] + bv.y;
      o.z = acc[r][2] + bv.z; o.w = acc[r][3] + bv.w;
      if (relu) {
        o.x = fmaxf(o.x, 0.f); o.y = fmaxf(o.y, 0.f);
        o.z = fmaxf(o.z, 0.f); o.w = fmaxf(o.w, 0.f);
      }
      *(float4*)&Y[(size_t)row * 128 + cg * 4] = o;
    }
  }
}

// ---- GEMM variant for GCN layers: Y16[row] = bf16( dinv[row] * (X@W)[row] ) ----

__global__ __launch_bounds__(256) void gemm_scaled_bf16_kernel(
    const float* __restrict__ X, const float* __restrict__ W,
    const float* __restrict__ dinv, unsigned* __restrict__ Y16, int M) {
  __shared__ __align__(16) float Ws[128 * 128];
  __shared__ __align__(16) float Xs[64 * 128];
  int tx = threadIdx.x;
  int cg = tx & 31;
  int rg = tx >> 5;

  for (int i = tx; i < 4096; i += 256)
    ((float4*)Ws)[i] = ((const float4*)W)[i];

  int row0 = blockIdx.x * 64;
  int rows_here = M - row0; if (rows_here > 64) rows_here = 64;
  const float4* Xg = (const float4*)(X + (size_t)row0 * 128);
  for (int i = tx; i < rows_here * 32; i += 256)
    ((float4*)Xs)[i] = Xg[i];
  __syncthreads();

  float acc[8][4];
#pragma unroll
  for (int r = 0; r < 8; r++)
#pragma unroll
    for (int c = 0; c < 4; c++) acc[r][c] = 0.f;

  for (int k = 0; k < 128; k += 4) {
    float4 w0 = *(const float4*)&Ws[(k + 0) * 128 + cg * 4];
    float4 w1 = *(const float4*)&Ws[(k + 1) * 128 + cg * 4];
    float4 w2 = *(const float4*)&Ws[(k + 2) * 128 + cg * 4];
    float4 w3 = *(const float4*)&Ws[(k + 3) * 128 + cg * 4];
#pragma unroll
    for (int r = 0; r < 8; r++) {
      float4 xv = *(const float4*)&Xs[(rg * 8 + r) * 128 + k];
      acc[r][0] = fmaf(xv.x, w0.x, fmaf(xv.y, w1.x, fmaf(xv.z, w2.x, fmaf(xv.w, w3.x, acc[r][0]))));
      acc[r][1] = fmaf(xv.x, w0.y, fmaf(xv.y, w1.y, fmaf(xv.z, w2.y, fmaf(xv.w, w3.y, acc[r][1]))));
      acc[r][2] = fmaf(xv.x, w0.z, fmaf(xv.y, w1.z, fmaf(xv.z, w2.z, fmaf(xv.w, w3.z, acc[r][2]))));
      acc[r][3] = fmaf(xv.x, w0.w, fmaf(xv.y, w1.w, fmaf(xv.z, w2.w, fmaf(xv.w, w3.w, acc[r][3]))));
    }
  }

#pragma unroll
  for (int r = 0; r < 8; r++) {
    int row = row0 + rg * 8 + r;
    if (row < M) {
      float s = dinv[row];
      unsigned u0 = pack_bf16x2(acc[r][0] * s, acc[r][1] * s);
      unsigned u1 = pack_bf16x2(acc[r][2] * s, acc[r][3] * s);
      unsigned* yp = Y16 + (size_t)row * 64 + cg * 2;
      yp[0] = u0; yp[1] = u1;
    }
  }
}

// ---------------- aggregation: pull over dst-CSR, bf16 gathers, fp32 accum ----------------

__global__ __launch_bounds__(256) void aggregate_bf16_kernel(
    const unsigned* __restrict__ Ht16, const int* __restrict__ row_off,
    const int* __restrict__ csr, const float* __restrict__ dinv,
    const float* __restrict__ bias, float* __restrict__ Out, int N) {
  int wave = (blockIdx.x * blockDim.x + threadIdx.x) >> 6;
  int lane = threadIdx.x & 63;
  if (wave >= N) return;
  int d = wave;
  int beg = row_off[d], end = row_off[d + 1];
  float ax = 0.f, ay = 0.f;
  int e = beg;
  for (; e + 3 < end; e += 4) {
    int s0 = csr[e], s1 = csr[e + 1], s2 = csr[e + 2], s3 = csr[e + 3];
    unsigned u0 = Ht16[(size_t)s0 * 64 + lane];
    unsigned u1 = Ht16[(size_t)s1 * 64 + lane];
    unsigned u2 = Ht16[(size_t)s2 * 64 + lane];
    unsigned u3 = Ht16[(size_t)s3 * 64 + lane];
    ax += bf_lo(u0); ay += bf_hi(u0);
    ax += bf_lo(u1); ay += bf_hi(u1);
    ax += bf_lo(u2); ay += bf_hi(u2);
    ax += bf_lo(u3); ay += bf_hi(u3);
  }
  for (; e < end; e++) {
    unsigned u0 = Ht16[(size_t)csr[e] * 64 + lane];
    ax += bf_lo(u0); ay += bf_hi(u0);
  }
  unsigned us = Ht16[(size_t)d * 64 + lane];
  ax += bf_lo(us); ay += bf_hi(us);

  float dd = dinv[d];
  float2 b2 = ((const float2*)bias)[lane];
  float ox = fmaf(dd, ax, b2.x);
  float oy = fmaf(dd, ay, b2.y);
  ox = fmaxf(ox, 0.f); oy = fmaxf(oy, 0.f);
  float2 o; o.x = ox; o.y = oy;
  ((float2*)Out)[(size_t)d * 64 + lane] = o;
}

// ---------------- head: logits = H @ W2 + b2, then log_softmax per row ----------------

__device__ __forceinline__ float wave_max(float v) {
#pragma unroll
  for (int off = 32; off > 0; off >>= 1) v = fmaxf(v, __shfl_xor(v, off, 64));
  return v;
}
__device__ __forceinline__ float wave_sum(float v) {
#pragma unroll
  for (int off = 32; off > 0; off >>= 1) v += __shfl_xor(v, off, 64);
  return v;
}

__global__ __launch_bounds__(256) void head_kernel(
    const float* __restrict__ H, const float* __restrict__ W2,
    const float* __restrict__ b2, float* __restrict__ Out, int N) {
  __shared__ __align__(16) float Ws[128 * OUTC];
  __shared__ float bs[OUTC];
  int t = threadIdx.x;
  for (int i = t; i < 128 * OUTC; i += 256) Ws[i] = W2[i];
  if (t < OUTC) bs[t] = b2[t];
  __syncthreads();
  int row = blockIdx.x * 4 + (t >> 6);
  if (row >= N) return;
  int lane = t & 63;
  int c = (lane < OUTC) ? lane : (OUTC - 1);
  const float4* h4 = (const float4*)(H + (size_t)row * 128);
  float logit = bs[c];
  for (int k4 = 0; k4 < 32; k4++) {
    float4 hv = h4[k4];
    int k = k4 * 4;
    logit = fmaf(hv.x, Ws[(k + 0) * OUTC + c],
            fmaf(hv.y, Ws[(k + 1) * OUTC + c],
            fmaf(hv.z, Ws[(k + 2) * OUTC + c],
            fmaf(hv.w, Ws[(k + 3) * OUTC + c], logit))));
  }
  float v = (lane < OUTC) ? logit : -3.4e38f;
  float m = wave_max(v);
  float ex = (lane < OUTC) ? expf(logit - m) : 0.f;
  float s = wave_sum(ex);
  if (lane < OUTC) Out[(size_t)row * OUTC + lane] = logit - m - logf(s);
}

// ---------------- launch ----------------

extern "C" void kernel_launch(void* const* d_in, const int* in_sizes, int n_in,
                              void* d_out, int out_size, void* d_ws, size_t ws_size,
                              hipStream_t stream) {
  const float* x      = (const float*)d_in[0];
  const int*   edge   = (const int*)d_in[1];
  const float* lin1_w = (const float*)d_in[2];
  const float* lin1_b = (const float*)d_in[3];
  const float* gcn_w  = (const float*)d_in[4];
  const float* gcn_b  = (const float*)d_in[5];
  const float* lin2_w = (const float*)d_in[6];
  const float* lin2_b = (const float*)d_in[7];
  float* out = (float*)d_out;

  const int N = NN;
  const int E = in_sizes[1] / 2;  // 3,200,000
  const int* src = edge;
  const int* dst = edge + E;

  char* p = (char*)d_ws;
  auto alloc = [&](size_t bytes) { char* q = p; p += (bytes + 255) & ~(size_t)255; return q; };
  float*    hA      = (float*)alloc((size_t)N * 128 * 4);
  unsigned* hB16    = (unsigned*)alloc((size_t)N * 64 * 4);
  int*      row_off = (int*)alloc((size_t)(N + 1) * 4);
  float*    dinv    = (float*)alloc((size_t)N * 4);
  int*      csr     = (int*)alloc((size_t)E * 4);
  int*      bc      = (int*)alloc(256 * 4);
  int*      bbase   = (int*)alloc(256 * 4);
  int*      bcur    = (int*)alloc(256 * 4);
  // pairs aliases hB16: graph prep finishes before the first gemm writes hB16.
  unsigned* pairs   = hB16;

  // graph prep
  zero_small_kernel<<<1, 256, 0, stream>>>(bc, NBUCK);
  tilehist_kernel<<<(E + PT_TILE - 1) / PT_TILE, 256, 0, stream>>>(dst, bc, E);
  bucket_scan_kernel<<<1, 256, 0, stream>>>(bc, bbase, bcur, row_off, N, E);
  partition_kernel<<<(E + PT_TILE - 1) / PT_TILE, 256, 0, stream>>>(src, dst, bcur, pairs, E);
  bucket_fill_kernel<<<NBUCK, 256, 0, stream>>>(pairs, bbase, row_off, dinv, csr, N);

  int gemm_blocks = (N + 63) / 64;
  gemm_kernel<<<gemm_blocks, 256, 0, stream>>>(x, lin1_w, lin1_b, hA, N, 1);
  for (int k = 0; k < 3; k++) {
    gemm_scaled_bf16_kernel<<<gemm_blocks, 256, 0, stream>>>(
        hA, gcn_w + (size_t)k * 128 * 128, dinv, hB16, N);
    aggregate_bf16_kernel<<<(N + 3) / 4, 256, 0, stream>>>(
        hB16, row_off, csr, dinv, gcn_b + (size_t)k * 128, hA, N);
  }
  head_kernel<<<(N + 3) / 4, 256, 0, stream>>>(hA, lin2_w, lin2_b, out, N);
}

// Round 6
// 1021.494 us; speedup vs baseline: 2.0298x; 1.0817x over previous
//
#include <hip/hip_runtime.h>
#include <math.h>

#define NN 100000
#define HIDC 128
#define OUTC 40
#define NBUCK ((NN + 511) >> 9)   // 196 buckets of 512 dst nodes
#define PT_TILE 8192

typedef __attribute__((ext_vector_type(2))) float floatx2;

// ---------------- graph prep (bucket-based, no per-node global atomics) ----------------

__global__ void zero_small_kernel(int* __restrict__ p, int n) {
  int i = threadIdx.x;
  if (i < n) p[i] = 0;
}

// per-tile LDS histogram over 196 buckets -> global bucket counts
__global__ __launch_bounds__(256) void tilehist_kernel(
    const int* __restrict__ dst, int* __restrict__ bc, int E) {
  __shared__ int hist[256];
  int t = threadIdx.x;
  hist[t] = 0;
  __syncthreads();
  int e0 = blockIdx.x * PT_TILE;
  int ec = E - e0; if (ec > PT_TILE) ec = PT_TILE;
  for (int i = t; i < ec; i += 256)
    atomicAdd(&hist[dst[e0 + i] >> 9], 1);
  __syncthreads();
  if (t < NBUCK && hist[t] > 0) atomicAdd(&bc[t], hist[t]);
}

// single block: exclusive scan of bc[NBUCK] -> bbase, bcur; row_off[N] = E
__global__ __launch_bounds__(256) void bucket_scan_kernel(
    const int* __restrict__ bc, int* __restrict__ bbase, int* __restrict__ bcur,
    int* __restrict__ row_off, int N, int E) {
  __shared__ int sh[256];
  int t = threadIdx.x;
  int v = (t < NBUCK) ? bc[t] : 0;
  sh[t] = v;
  __syncthreads();
  for (int off = 1; off < 256; off <<= 1) {
    int u = (t >= off) ? sh[t - off] : 0;
    __syncthreads();
    sh[t] += u;
    __syncthreads();
  }
  if (t < NBUCK) { int ex = sh[t] - v; bbase[t] = ex; bcur[t] = ex; }
  if (t == 0) { bbase[NBUCK] = E; row_off[N] = E; }
}

// ---- phase 1: partition edges into 196 dst-buckets (packed uint32) ----
// pack = (dst & 511) << 17 | src   (src < 2^17; N=100000 < 131072)

__global__ __launch_bounds__(256) void partition_kernel(
    const int* __restrict__ src, const int* __restrict__ dst,
    int* __restrict__ bcur, unsigned* __restrict__ pairs, int E) {
  __shared__ int hist[256];
  __shared__ int base[256];
  __shared__ int lcur[256];
  int t = threadIdx.x;
  hist[t] = 0; lcur[t] = 0;
  __syncthreads();
  int e0 = blockIdx.x * PT_TILE;
  int ec = E - e0; if (ec > PT_TILE) ec = PT_TILE;
  for (int i = t; i < ec; i += 256)
    atomicAdd(&hist[dst[e0 + i] >> 9], 1);
  __syncthreads();
  if (hist[t] > 0) base[t] = atomicAdd(&bcur[t], hist[t]);
  __syncthreads();
  for (int i = t; i < ec; i += 256) {
    int d = dst[e0 + i], s = src[e0 + i];
    int b = d >> 9;
    int pos = atomicAdd(&lcur[b], 1);
    pairs[base[b] + pos] = ((unsigned)(d & 511) << 17) | (unsigned)s;
  }
}

// ---- phase 2: per-bucket LDS hist(512) + scan -> row_off/dinv, then csr scatter ----

__global__ __launch_bounds__(256) void bucket_fill_kernel(
    const unsigned* __restrict__ pairs, const int* __restrict__ bbase,
    int* __restrict__ row_off, float* __restrict__ dinv,
    int* __restrict__ csr, int N) {
  int b = blockIdx.x;
  int d0 = b << 9;
  int nd = N - d0; if (nd > 512) nd = 512;
  __shared__ int hist[512];
  __shared__ int cur[512];
  __shared__ int sums[256];
  int t = threadIdx.x;
  hist[t] = 0; hist[t + 256] = 0;
  __syncthreads();
  int rbeg = bbase[b], rend = bbase[b + 1];
  for (int i = rbeg + t; i < rend; i += 256)
    atomicAdd(&hist[pairs[i] >> 17], 1);
  __syncthreads();
  int h0 = hist[2 * t], h1 = hist[2 * t + 1];
  int s = h0 + h1;
  sums[t] = s;
  __syncthreads();
  for (int off = 1; off < 256; off <<= 1) {
    int u = (t >= off) ? sums[t - off] : 0;
    __syncthreads();
    sums[t] += u;
    __syncthreads();
  }
  int base0 = rbeg + sums[t] - s;
  int base1 = base0 + h0;
  int j0 = 2 * t, j1 = 2 * t + 1;
  if (j0 < nd) {
    row_off[d0 + j0] = base0;
    dinv[d0 + j0] = rsqrtf((float)(h0 + 1));
    cur[j0] = base0;
  }
  if (j1 < nd) {
    row_off[d0 + j1] = base1;
    dinv[d0 + j1] = rsqrtf((float)(h1 + 1));
    cur[j1] = base1;
  }
  __syncthreads();
  for (int i = rbeg + t; i < rend; i += 256) {
    unsigned pk = pairs[i];
    int q = atomicAdd(&cur[pk >> 17], 1);
    csr[q] = pk & 0x1FFFF;
  }
}

// ---------------- GEMM (M x 128) @ (128 x 128) fp32 out, bias+relu ----------------

__global__ __launch_bounds__(256) void gemm_kernel(
    const float* __restrict__ X, const float* __restrict__ W,
    const float* __restrict__ bias, float* __restrict__ Y, int M, int relu) {
  __shared__ __align__(16) float Ws[128 * 128];
  __shared__ __align__(16) float Xs[64 * 128];
  int tx = threadIdx.x;
  int cg = tx & 31;
  int rg = tx >> 5;

  for (int i = tx; i < 4096; i += 256)
    ((float4*)Ws)[i] = ((const float4*)W)[i];

  int row0 = blockIdx.x * 64;
  int rows_here = M - row0; if (rows_here > 64) rows_here = 64;
  const float4* Xg = (const float4*)(X + (size_t)row0 * 128);
  for (int i = tx; i < rows_here * 32; i += 256)
    ((float4*)Xs)[i] = Xg[i];
  __syncthreads();

  float acc[8][4];
#pragma unroll
  for (int r = 0; r < 8; r++)
#pragma unroll
    for (int c = 0; c < 4; c++) acc[r][c] = 0.f;

  for (int k = 0; k < 128; k += 4) {
    float4 w0 = *(const float4*)&Ws[(k + 0) * 128 + cg * 4];
    float4 w1 = *(const float4*)&Ws[(k + 1) * 128 + cg * 4];
    float4 w2 = *(const float4*)&Ws[(k + 2) * 128 + cg * 4];
    float4 w3 = *(const float4*)&Ws[(k + 3) * 128 + cg * 4];
#pragma unroll
    for (int r = 0; r < 8; r++) {
      float4 xv = *(const float4*)&Xs[(rg * 8 + r) * 128 + k];
      acc[r][0] = fmaf(xv.x, w0.x, fmaf(xv.y, w1.x, fmaf(xv.z, w2.x, fmaf(xv.w, w3.x, acc[r][0]))));
      acc[r][1] = fmaf(xv.x, w0.y, fmaf(xv.y, w1.y, fmaf(xv.z, w2.y, fmaf(xv.w, w3.y, acc[r][1]))));
      acc[r][2] = fmaf(xv.x, w0.z, fmaf(xv.y, w1.z, fmaf(xv.z, w2.z, fmaf(xv.w, w3.z, acc[r][2]))));
      acc[r][3] = fmaf(xv.x, w0.w, fmaf(xv.y, w1.w, fmaf(xv.z, w2.w, fmaf(xv.w, w3.w, acc[r][3]))));
    }
  }

  float4 bv = make_float4(0.f, 0.f, 0.f, 0.f);
  if (bias) bv = ((const float4*)bias)[cg];
#pragma unroll
  for (int r = 0; r < 8; r++) {
    int row = row0 + rg * 8 + r;
    if (row < M) {
      float4 o;
      o.x = acc[r][0] + bv.x; o.y = acc[r][1] + bv.y;
      o.z = acc[r][2] + bv.z; o.w = acc[r][3] + bv.w;
      if (relu) {
        o.x = fmaxf(o.x, 0.f); o.y = fmaxf(o.y, 0.f);
        o.z = fmaxf(o.z, 0.f); o.w = fmaxf(o.w, 0.f);
      }
      *(float4*)&Y[(size_t)row * 128 + cg * 4] = o;
    }
  }
}

// ---- GEMM variant for GCN layers: Y8[row] = fp8_e4m3( dinv[row] * (X@W)[row] ) ----
// output row = 32 uints (4 fp8 per uint); thread writes 1 uint.

__global__ __launch_bounds__(256) void gemm_scaled_fp8_kernel(
    const float* __restrict__ X, const float* __restrict__ W,
    const float* __restrict__ dinv, unsigned* __restrict__ Y8, int M) {
  __shared__ __align__(16) float Ws[128 * 128];
  __shared__ __align__(16) float Xs[64 * 128];
  int tx = threadIdx.x;
  int cg = tx & 31;
  int rg = tx >> 5;

  for (int i = tx; i < 4096; i += 256)
    ((float4*)Ws)[i] = ((const float4*)W)[i];

  int row0 = blockIdx.x * 64;
  int rows_here = M - row0; if (rows_here > 64) rows_here = 64;
  const float4* Xg = (const float4*)(X + (size_t)row0 * 128);
  for (int i = tx; i < rows_here * 32; i += 256)
    ((float4*)Xs)[i] = Xg[i];
  __syncthreads();

  float acc[8][4];
#pragma unroll
  for (int r = 0; r < 8; r++)
#pragma unroll
    for (int c = 0; c < 4; c++) acc[r][c] = 0.f;

  for (int k = 0; k < 128; k += 4) {
    float4 w0 = *(const float4*)&Ws[(k + 0) * 128 + cg * 4];
    float4 w1 = *(const float4*)&Ws[(k + 1) * 128 + cg * 4];
    float4 w2 = *(const float4*)&Ws[(k + 2) * 128 + cg * 4];
    float4 w3 = *(const float4*)&Ws[(k + 3) * 128 + cg * 4];
#pragma unroll
    for (int r = 0; r < 8; r++) {
      float4 xv = *(const float4*)&Xs[(rg * 8 + r) * 128 + k];
      acc[r][0] = fmaf(xv.x, w0.x, fmaf(xv.y, w1.x, fmaf(xv.z, w2.x, fmaf(xv.w, w3.x, acc[r][0]))));
      acc[r][1] = fmaf(xv.x, w0.y, fmaf(xv.y, w1.y, fmaf(xv.z, w2.y, fmaf(xv.w, w3.y, acc[r][1]))));
      acc[r][2] = fmaf(xv.x, w0.z, fmaf(xv.y, w1.z, fmaf(xv.z, w2.z, fmaf(xv.w, w3.z, acc[r][2]))));
      acc[r][3] = fmaf(xv.x, w0.w, fmaf(xv.y, w1.w, fmaf(xv.z, w2.w, fmaf(xv.w, w3.w, acc[r][3]))));
    }
  }

#pragma unroll
  for (int r = 0; r < 8; r++) {
    int row = row0 + rg * 8 + r;
    if (row < M) {
      float s = dinv[row];
      unsigned u = 0;
      u = __builtin_amdgcn_cvt_pk_fp8_f32(acc[r][0] * s, acc[r][1] * s, (int)u, false);
      u = __builtin_amdgcn_cvt_pk_fp8_f32(acc[r][2] * s, acc[r][3] * s, (int)u, true);
      Y8[(size_t)row * 32 + cg] = u;
    }
  }
}

// ---------------- aggregation: pull over dst-CSR, fp8 gathers, fp32 accum ----------------
// Row = 128 B = 32 uints. Half-wave per edge: lanes 0-31 even edges, 32-63 odd.
// out[d] = relu( dinv[d]*( sum_s fp8H[s] + fp8H[d] ) + b )

__global__ __launch_bounds__(256) void aggregate_fp8_kernel(
    const unsigned* __restrict__ Ht8, const int* __restrict__ row_off,
    const int* __restrict__ csr, const float* __restrict__ dinv,
    const float* __restrict__ bias, float* __restrict__ Out, int N) {
  int wave = (blockIdx.x * blockDim.x + threadIdx.x) >> 6;
  int lane = threadIdx.x & 63;
  if (wave >= N) return;
  int half = lane >> 5;
  int col = lane & 31;
  int d = wave;
  int beg = row_off[d], end = row_off[d + 1];
  float a0 = 0.f, a1 = 0.f, a2 = 0.f, a3 = 0.f;
  int i = beg + half;
  for (; i + 2 < end; i += 4) {
    int s0 = csr[i], s1 = csr[i + 2];
    unsigned u0 = Ht8[(size_t)s0 * 32 + col];
    unsigned u1 = Ht8[(size_t)s1 * 32 + col];
    floatx2 lo0 = __builtin_amdgcn_cvt_pk_f32_fp8((int)u0, false);
    floatx2 hi0 = __builtin_amdgcn_cvt_pk_f32_fp8((int)u0, true);
    floatx2 lo1 = __builtin_amdgcn_cvt_pk_f32_fp8((int)u1, false);
    floatx2 hi1 = __builtin_amdgcn_cvt_pk_f32_fp8((int)u1, true);
    a0 += lo0[0]; a1 += lo0[1]; a2 += hi0[0]; a3 += hi0[1];
    a0 += lo1[0]; a1 += lo1[1]; a2 += hi1[0]; a3 += hi1[1];
  }
  if (i < end) {
    unsigned u0 = Ht8[(size_t)csr[i] * 32 + col];
    floatx2 lo0 = __builtin_amdgcn_cvt_pk_f32_fp8((int)u0, false);
    floatx2 hi0 = __builtin_amdgcn_cvt_pk_f32_fp8((int)u0, true);
    a0 += lo0[0]; a1 += lo0[1]; a2 += hi0[0]; a3 += hi0[1];
  }
  if (half == 0) {  // self-loop added once
    unsigned us = Ht8[(size_t)d * 32 + col];
    floatx2 lo = __builtin_amdgcn_cvt_pk_f32_fp8((int)us, false);
    floatx2 hi = __builtin_amdgcn_cvt_pk_f32_fp8((int)us, true);
    a0 += lo[0]; a1 += lo[1]; a2 += hi[0]; a3 += hi[1];
  }
  // combine halves (lane ^ 32)
  a0 += __shfl_xor(a0, 32, 64);
  a1 += __shfl_xor(a1, 32, 64);
  a2 += __shfl_xor(a2, 32, 64);
  a3 += __shfl_xor(a3, 32, 64);
  if (half == 0) {
    float dd = dinv[d];
    float4 bv = ((const float4*)bias)[col];
    float4 o;
    o.x = fmaxf(fmaf(dd, a0, bv.x), 0.f);
    o.y = fmaxf(fmaf(dd, a1, bv.y), 0.f);
    o.z = fmaxf(fmaf(dd, a2, bv.z), 0.f);
    o.w = fmaxf(fmaf(dd, a3, bv.w), 0.f);
    ((float4*)Out)[(size_t)d * 32 + col] = o;
  }
}

// ---------------- head: logits = H @ W2 + b2, then log_softmax per row ----------------

__device__ __forceinline__ float wave_max(float v) {
#pragma unroll
  for (int off = 32; off > 0; off >>= 1) v = fmaxf(v, __shfl_xor(v, off, 64));
  return v;
}
__device__ __forceinline__ float wave_sum(float v) {
#pragma unroll
  for (int off = 32; off > 0; off >>= 1) v += __shfl_xor(v, off, 64);
  return v;
}

__global__ __launch_bounds__(256) void head_kernel(
    const float* __restrict__ H, const float* __restrict__ W2,
    const float* __restrict__ b2, float* __restrict__ Out, int N) {
  __shared__ __align__(16) float Ws[128 * OUTC];
  __shared__ float bs[OUTC];
  int t = threadIdx.x;
  for (int i = t; i < 128 * OUTC; i += 256) Ws[i] = W2[i];
  if (t < OUTC) bs[t] = b2[t];
  __syncthreads();
  int row = blockIdx.x * 4 + (t >> 6);
  if (row >= N) return;
  int lane = t & 63;
  int c = (lane < OUTC) ? lane : (OUTC - 1);
  const float4* h4 = (const float4*)(H + (size_t)row * 128);
  float logit = bs[c];
  for (int k4 = 0; k4 < 32; k4++) {
    float4 hv = h4[k4];
    int k = k4 * 4;
    logit = fmaf(hv.x, Ws[(k + 0) * OUTC + c],
            fmaf(hv.y, Ws[(k + 1) * OUTC + c],
            fmaf(hv.z, Ws[(k + 2) * OUTC + c],
            fmaf(hv.w, Ws[(k + 3) * OUTC + c], logit))));
  }
  float v = (lane < OUTC) ? logit : -3.4e38f;
  float m = wave_max(v);
  float ex = (lane < OUTC) ? expf(logit - m) : 0.f;
  float s = wave_sum(ex);
  if (lane < OUTC) Out[(size_t)row * OUTC + lane] = logit - m - logf(s);
}

// ---------------- launch ----------------

extern "C" void kernel_launch(void* const* d_in, const int* in_sizes, int n_in,
                              void* d_out, int out_size, void* d_ws, size_t ws_size,
                              hipStream_t stream) {
  const float* x      = (const float*)d_in[0];
  const int*   edge   = (const int*)d_in[1];
  const float* lin1_w = (const float*)d_in[2];
  const float* lin1_b = (const float*)d_in[3];
  const float* gcn_w  = (const float*)d_in[4];
  const float* gcn_b  = (const float*)d_in[5];
  const float* lin2_w = (const float*)d_in[6];
  const float* lin2_b = (const float*)d_in[7];
  float* out = (float*)d_out;

  const int N = NN;
  const int E = in_sizes[1] / 2;  // 3,200,000
  const int* src = edge;
  const int* dst = edge + E;

  char* p = (char*)d_ws;
  auto alloc = [&](size_t bytes) { char* q = p; p += (bytes + 255) & ~(size_t)255; return q; };
  float*    hA      = (float*)alloc((size_t)N * 128 * 4);
  unsigned* hB8     = (unsigned*)alloc((size_t)N * 64 * 4);  // sized for pairs alias (E*4 <= N*256)
  int*      row_off = (int*)alloc((size_t)(N + 1) * 4);
  float*    dinv    = (float*)alloc((size_t)N * 4);
  int*      csr     = (int*)alloc((size_t)E * 4);
  int*      bc      = (int*)alloc(256 * 4);
  int*      bbase   = (int*)alloc(256 * 4);
  int*      bcur    = (int*)alloc(256 * 4);
  // pairs aliases hB8: graph prep finishes before the first gemm writes hB8.
  unsigned* pairs   = hB8;

  // graph prep
  zero_small_kernel<<<1, 256, 0, stream>>>(bc, NBUCK);
  tilehist_kernel<<<(E + PT_TILE - 1) / PT_TILE, 256, 0, stream>>>(dst, bc, E);
  bucket_scan_kernel<<<1, 256, 0, stream>>>(bc, bbase, bcur, row_off, N, E);
  partition_kernel<<<(E + PT_TILE - 1) / PT_TILE, 256, 0, stream>>>(src, dst, bcur, pairs, E);
  bucket_fill_kernel<<<NBUCK, 256, 0, stream>>>(pairs, bbase, row_off, dinv, csr, N);

  int gemm_blocks = (N + 63) / 64;
  gemm_kernel<<<gemm_blocks, 256, 0, stream>>>(x, lin1_w, lin1_b, hA, N, 1);
  for (int k = 0; k < 3; k++) {
    gemm_scaled_fp8_kernel<<<gemm_blocks, 256, 0, stream>>>(
        hA, gcn_w + (size_t)k * 128 * 128, dinv, hB8, N);
    aggregate_fp8_kernel<<<(N + 3) / 4, 256, 0, stream>>>(
        hB8, row_off, csr, dinv, gcn_b + (size_t)k * 128, hA, N);
  }
  head_kernel<<<(N + 3) / 4, 256, 0, stream>>>(hA, lin2_w, lin2_b, out, N);
}

// Round 7
// 734.052 us; speedup vs baseline: 2.8246x; 1.3916x over previous
//
#include <hip/hip_runtime.h>
#include <math.h>

#define NN 100000
#define NP 100032              // padded to 64-row multiple (1563 * 64)
#define HIDC 128
#define OUTC 40
#define NBUCK ((NN + 511) >> 9)   // 196 buckets of 512 dst nodes
#define PT_TILE 8192

typedef __attribute__((ext_vector_type(2))) float floatx2;
typedef __attribute__((ext_vector_type(4))) float floatx4;
typedef __attribute__((ext_vector_type(8))) short short8;

// bf16 helpers (RN) -------------------------------------------------------
__device__ __forceinline__ unsigned pack_bf16x2(float a, float b) {
  unsigned ua = __float_as_uint(a), ub = __float_as_uint(b);
  ua = ua + 0x7fff + ((ua >> 16) & 1);
  ub = ub + 0x7fff + ((ub >> 16) & 1);
  return (ua >> 16) | (ub & 0xffff0000u);
}
__device__ __forceinline__ unsigned short bf16r(float x) {
  unsigned u = __float_as_uint(x);
  u = u + 0x7fff + ((u >> 16) & 1);
  return (unsigned short)(u >> 16);
}
__device__ __forceinline__ float bf_lo(unsigned u) { return __uint_as_float(u << 16); }
__device__ __forceinline__ float bf_hi(unsigned u) { return __uint_as_float(u & 0xffff0000u); }

// ---------------- graph prep (bucket-based) ----------------

__global__ void zero_small_kernel(int* __restrict__ p, int n) {
  int i = threadIdx.x;
  if (i < n) p[i] = 0;
}

__global__ __launch_bounds__(256) void tilehist_kernel(
    const int* __restrict__ dst, int* __restrict__ bc, int E) {
  __shared__ int hist[256];
  int t = threadIdx.x;
  hist[t] = 0;
  __syncthreads();
  int e0 = blockIdx.x * PT_TILE;
  int ec = E - e0; if (ec > PT_TILE) ec = PT_TILE;
  for (int i = t; i < ec; i += 256)
    atomicAdd(&hist[dst[e0 + i] >> 9], 1);
  __syncthreads();
  if (t < NBUCK && hist[t] > 0) atomicAdd(&bc[t], hist[t]);
}

__global__ __launch_bounds__(256) void bucket_scan_kernel(
    const int* __restrict__ bc, int* __restrict__ bbase, int* __restrict__ bcur,
    int* __restrict__ row_off, int N, int E) {
  __shared__ int sh[256];
  int t = threadIdx.x;
  int v = (t < NBUCK) ? bc[t] : 0;
  sh[t] = v;
  __syncthreads();
  for (int off = 1; off < 256; off <<= 1) {
    int u = (t >= off) ? sh[t - off] : 0;
    __syncthreads();
    sh[t] += u;
    __syncthreads();
  }
  if (t < NBUCK) { int ex = sh[t] - v; bbase[t] = ex; bcur[t] = ex; }
  if (t == 0) { bbase[NBUCK] = E; row_off[N] = E; }
}

__global__ __launch_bounds__(256) void partition_kernel(
    const int* __restrict__ src, const int* __restrict__ dst,
    int* __restrict__ bcur, unsigned* __restrict__ pairs, int E) {
  __shared__ int hist[256];
  __shared__ int base[256];
  __shared__ int lcur[256];
  int t = threadIdx.x;
  hist[t] = 0; lcur[t] = 0;
  __syncthreads();
  int e0 = blockIdx.x * PT_TILE;
  int ec = E - e0; if (ec > PT_TILE) ec = PT_TILE;
  for (int i = t; i < ec; i += 256)
    atomicAdd(&hist[dst[e0 + i] >> 9], 1);
  __syncthreads();
  if (hist[t] > 0) base[t] = atomicAdd(&bcur[t], hist[t]);
  __syncthreads();
  for (int i = t; i < ec; i += 256) {
    int d = dst[e0 + i], s = src[e0 + i];
    int b = d >> 9;
    int pos = atomicAdd(&lcur[b], 1);
    pairs[base[b] + pos] = ((unsigned)(d & 511) << 17) | (unsigned)s;
  }
}

__global__ __launch_bounds__(256) void bucket_fill_kernel(
    const unsigned* __restrict__ pairs, const int* __restrict__ bbase,
    int* __restrict__ row_off, float* __restrict__ dinv,
    int* __restrict__ csr, int N) {
  int b = blockIdx.x;
  int d0 = b << 9;
  int nd = N - d0; if (nd > 512) nd = 512;
  __shared__ int hist[512];
  __shared__ int cur[512];
  __shared__ int sums[256];
  int t = threadIdx.x;
  hist[t] = 0; hist[t + 256] = 0;
  __syncthreads();
  int rbeg = bbase[b], rend = bbase[b + 1];
  for (int i = rbeg + t; i < rend; i += 256)
    atomicAdd(&hist[pairs[i] >> 17], 1);
  __syncthreads();
  int h0 = hist[2 * t], h1 = hist[2 * t + 1];
  int s = h0 + h1;
  sums[t] = s;
  __syncthreads();
  for (int off = 1; off < 256; off <<= 1) {
    int u = (t >= off) ? sums[t - off] : 0;
    __syncthreads();
    sums[t] += u;
    __syncthreads();
  }
  int base0 = rbeg + sums[t] - s;
  int base1 = base0 + h0;
  int j0 = 2 * t, j1 = 2 * t + 1;
  if (j0 < nd) {
    row_off[d0 + j0] = base0;
    dinv[d0 + j0] = rsqrtf((float)(h0 + 1));
    cur[j0] = base0;
  }
  if (j1 < nd) {
    row_off[d0 + j1] = base1;
    dinv[d0 + j1] = rsqrtf((float)(h1 + 1));
    cur[j1] = base1;
  }
  __syncthreads();
  for (int i = rbeg + t; i < rend; i += 256) {
    unsigned pk = pairs[i];
    int q = atomicAdd(&cur[pk >> 17], 1);
    csr[q] = pk & 0x1FFFF;
  }
}

// ---------------- input/weight conversion ----------------

// x fp32 -> bf16 packed (2 per uint)
__global__ __launch_bounds__(256) void convert_x_kernel(
    const float* __restrict__ x, unsigned* __restrict__ x16, int n2) {
  int i = blockIdx.x * 256 + threadIdx.x;
  if (i < n2) {
    float2 v = ((const float2*)x)[i];
    x16[i] = pack_bf16x2(v.x, v.y);
  }
}

// W[k][n] fp32 -> Wt[n][k] bf16, 4 matrices (lin1, gcn0..2)
__global__ __launch_bounds__(256) void prep_weights_kernel(
    const float* __restrict__ lin1_w, const float* __restrict__ gcn_w,
    unsigned short* __restrict__ Wt) {
  int b = blockIdx.x;
  const float* src = (b == 0) ? lin1_w : (gcn_w + (size_t)(b - 1) * 16384);
  unsigned short* dst = Wt + (size_t)b * 16384;
  for (int i = threadIdx.x; i < 16384; i += 256) {
    int n = i >> 7, k = i & 127;
    dst[(size_t)n * 128 + k] = bf16r(src[(size_t)k * 128 + n]);
  }
}

// ---------------- MFMA GEMM: Y = A(Mx128 bf16) @ Wt^T(128x128 bf16) ----------------
// No LDS. Block = 256 threads = 4 waves; 64 rows x 128 cols per block.
// Wave w: cols 32w..32w+31 (2 col-tiles), all 4 row-tiles. 8 MFMAs x 4 k-chunks.
// A-operand: A[m=lane&15][k=quad*8+j] contiguous in global (row-major).
// B-operand: Wt[n=lane&15][k=quad*8+j] (pre-transposed W).
// mode 0: Y16 bf16 = relu(acc + bias[col]);  mode 1: Y8 fp8 = dinv[row]*acc.

__global__ __launch_bounds__(256) void gemm_mfma_kernel(
    const unsigned short* __restrict__ A, const unsigned short* __restrict__ Wt,
    const float* __restrict__ bias, const float* __restrict__ dinv,
    void* __restrict__ Y, int M, int mode) {
  int t = threadIdx.x;
  int w = t >> 6;
  int l = t & 63;
  int quad = l >> 4;
  int m16 = l & 15;
  int row0 = blockIdx.x * 64;
  int colbase = w * 32;

  floatx4 acc[4][2];
#pragma unroll
  for (int rt = 0; rt < 4; rt++)
#pragma unroll
    for (int ct = 0; ct < 2; ct++) acc[rt][ct] = (floatx4)0.f;

  const unsigned short* Aw = A + (size_t)row0 * 128;
#pragma unroll
  for (int kc = 0; kc < 4; kc++) {
    int kof = kc * 32 + quad * 8;
    short8 b0 = *(const short8*)(Wt + (size_t)(colbase + m16) * 128 + kof);
    short8 b1 = *(const short8*)(Wt + (size_t)(colbase + 16 + m16) * 128 + kof);
#pragma unroll
    for (int rt = 0; rt < 4; rt++) {
      short8 a = *(const short8*)(Aw + (size_t)(rt * 16 + m16) * 128 + kof);
      acc[rt][0] = __builtin_amdgcn_mfma_f32_16x16x32_bf16(a, b0, acc[rt][0], 0, 0, 0);
      acc[rt][1] = __builtin_amdgcn_mfma_f32_16x16x32_bf16(a, b1, acc[rt][1], 0, 0, 0);
    }
  }

  // C/D: col = lane&15, row = quad*4 + reg (within 16x16 tile)
  if (mode == 0) {
    unsigned short* Y16 = (unsigned short*)Y;
    float bv0 = bias[colbase + m16];
    float bv1 = bias[colbase + 16 + m16];
#pragma unroll
    for (int rt = 0; rt < 4; rt++) {
#pragma unroll
      for (int j = 0; j < 4; j++) {
        int row = row0 + rt * 16 + quad * 4 + j;
        if (row < M) {
          Y16[(size_t)row * 128 + colbase + m16] = bf16r(fmaxf(acc[rt][0][j] + bv0, 0.f));
          Y16[(size_t)row * 128 + colbase + 16 + m16] = bf16r(fmaxf(acc[rt][1][j] + bv1, 0.f));
        }
      }
    }
  } else {
    unsigned char* Y8 = (unsigned char*)Y;
#pragma unroll
    for (int rt = 0; rt < 4; rt++) {
#pragma unroll
      for (int j = 0; j < 4; j++) {
        int row = row0 + rt * 16 + quad * 4 + j;
        if (row < M) {
          float dd = dinv[row];
          float v0 = acc[rt][0][j] * dd;
          float v1 = acc[rt][1][j] * dd;
          Y8[(size_t)row * 128 + colbase + m16] =
              (unsigned char)(__builtin_amdgcn_cvt_pk_fp8_f32(v0, v0, 0, false) & 0xFF);
          Y8[(size_t)row * 128 + colbase + 16 + m16] =
              (unsigned char)(__builtin_amdgcn_cvt_pk_fp8_f32(v1, v1, 0, false) & 0xFF);
        }
      }
    }
  }
}

// ---------------- aggregation: fp8 gathers, fp32 accum, bf16 out ----------------

__global__ __launch_bounds__(256) void aggregate_fp8_kernel(
    const unsigned* __restrict__ Ht8, const int* __restrict__ row_off,
    const int* __restrict__ csr, const float* __restrict__ dinv,
    const float* __restrict__ bias, unsigned* __restrict__ Out, int N) {
  int wave = (blockIdx.x * blockDim.x + threadIdx.x) >> 6;
  int lane = threadIdx.x & 63;
  if (wave >= N) return;
  int half = lane >> 5;
  int col = lane & 31;
  int d = wave;
  int beg = row_off[d], end = row_off[d + 1];
  float a0 = 0.f, a1 = 0.f, a2 = 0.f, a3 = 0.f;
  int i = beg + half;
  for (; i + 2 < end; i += 4) {
    int s0 = csr[i], s1 = csr[i + 2];
    unsigned u0 = Ht8[(size_t)s0 * 32 + col];
    unsigned u1 = Ht8[(size_t)s1 * 32 + col];
    floatx2 lo0 = __builtin_amdgcn_cvt_pk_f32_fp8((int)u0, false);
    floatx2 hi0 = __builtin_amdgcn_cvt_pk_f32_fp8((int)u0, true);
    floatx2 lo1 = __builtin_amdgcn_cvt_pk_f32_fp8((int)u1, false);
    floatx2 hi1 = __builtin_amdgcn_cvt_pk_f32_fp8((int)u1, true);
    a0 += lo0[0]; a1 += lo0[1]; a2 += hi0[0]; a3 += hi0[1];
    a0 += lo1[0]; a1 += lo1[1]; a2 += hi1[0]; a3 += hi1[1];
  }
  if (i < end) {
    unsigned u0 = Ht8[(size_t)csr[i] * 32 + col];
    floatx2 lo0 = __builtin_amdgcn_cvt_pk_f32_fp8((int)u0, false);
    floatx2 hi0 = __builtin_amdgcn_cvt_pk_f32_fp8((int)u0, true);
    a0 += lo0[0]; a1 += lo0[1]; a2 += hi0[0]; a3 += hi0[1];
  }
  if (half == 0) {
    unsigned us = Ht8[(size_t)d * 32 + col];
    floatx2 lo = __builtin_amdgcn_cvt_pk_f32_fp8((int)us, false);
    floatx2 hi = __builtin_amdgcn_cvt_pk_f32_fp8((int)us, true);
    a0 += lo[0]; a1 += lo[1]; a2 += hi[0]; a3 += hi[1];
  }
  a0 += __shfl_xor(a0, 32, 64);
  a1 += __shfl_xor(a1, 32, 64);
  a2 += __shfl_xor(a2, 32, 64);
  a3 += __shfl_xor(a3, 32, 64);
  if (half == 0) {
    float dd = dinv[d];
    float4 bv = ((const float4*)bias)[col];
    unsigned u0 = pack_bf16x2(fmaxf(fmaf(dd, a0, bv.x), 0.f),
                              fmaxf(fmaf(dd, a1, bv.y), 0.f));
    unsigned u1 = pack_bf16x2(fmaxf(fmaf(dd, a2, bv.z), 0.f),
                              fmaxf(fmaf(dd, a3, bv.w), 0.f));
    uint2 o; o.x = u0; o.y = u1;
    ((uint2*)Out)[(size_t)d * 32 + col] = o;
  }
}

// ---------------- head: logits = H(bf16) @ W2 + b2, log_softmax ----------------

__device__ __forceinline__ float wave_max(float v) {
#pragma unroll
  for (int off = 32; off > 0; off >>= 1) v = fmaxf(v, __shfl_xor(v, off, 64));
  return v;
}
__device__ __forceinline__ float wave_sum(float v) {
#pragma unroll
  for (int off = 32; off > 0; off >>= 1) v += __shfl_xor(v, off, 64);
  return v;
}

__global__ __launch_bounds__(256) void head_kernel(
    const unsigned* __restrict__ H, const float* __restrict__ W2,
    const float* __restrict__ b2, float* __restrict__ Out, int N) {
  __shared__ __align__(16) float Ws[128 * OUTC];
  __shared__ float bs[OUTC];
  int t = threadIdx.x;
  for (int i = t; i < 128 * OUTC; i += 256) Ws[i] = W2[i];
  if (t < OUTC) bs[t] = b2[t];
  __syncthreads();
  int row = blockIdx.x * 4 + (t >> 6);
  if (row >= N) return;
  int lane = t & 63;
  int c = (lane < OUTC) ? lane : (OUTC - 1);
  const uint4* h4 = (const uint4*)(H + (size_t)row * 64);
  float logit = bs[c];
  for (int i = 0; i < 16; i++) {
    uint4 hv = h4[i];
    int k = i * 8;
    logit = fmaf(bf_lo(hv.x), Ws[(k + 0) * OUTC + c],
            fmaf(bf_hi(hv.x), Ws[(k + 1) * OUTC + c],
            fmaf(bf_lo(hv.y), Ws[(k + 2) * OUTC + c],
            fmaf(bf_hi(hv.y), Ws[(k + 3) * OUTC + c], logit))));
    logit = fmaf(bf_lo(hv.z), Ws[(k + 4) * OUTC + c],
            fmaf(bf_hi(hv.z), Ws[(k + 5) * OUTC + c],
            fmaf(bf_lo(hv.w), Ws[(k + 6) * OUTC + c],
            fmaf(bf_hi(hv.w), Ws[(k + 7) * OUTC + c], logit))));
  }
  float v = (lane < OUTC) ? logit : -3.4e38f;
  float m = wave_max(v);
  float ex = (lane < OUTC) ? expf(logit - m) : 0.f;
  float s = wave_sum(ex);
  if (lane < OUTC) Out[(size_t)row * OUTC + lane] = logit - m - logf(s);
}

// ---------------- launch ----------------

extern "C" void kernel_launch(void* const* d_in, const int* in_sizes, int n_in,
                              void* d_out, int out_size, void* d_ws, size_t ws_size,
                              hipStream_t stream) {
  const float* x      = (const float*)d_in[0];
  const int*   edge   = (const int*)d_in[1];
  const float* lin1_w = (const float*)d_in[2];
  const float* lin1_b = (const float*)d_in[3];
  const float* gcn_w  = (const float*)d_in[4];
  const float* gcn_b  = (const float*)d_in[5];
  const float* lin2_w = (const float*)d_in[6];
  const float* lin2_b = (const float*)d_in[7];
  float* out = (float*)d_out;

  const int N = NN;
  const int E = in_sizes[1] / 2;  // 3,200,000
  const int* src = edge;
  const int* dst = edge + E;

  char* p = (char*)d_ws;
  auto alloc = [&](size_t bytes) { char* q = p; p += (bytes + 255) & ~(size_t)255; return q; };
  unsigned*       hA16    = (unsigned*)alloc((size_t)NP * 128 * 2);   // bf16 features
  unsigned*       x16     = (unsigned*)alloc((size_t)NP * 128 * 2);   // bf16 input
  unsigned*       hB8     = (unsigned*)alloc((size_t)NP * 32 * 4);    // fp8 messages (12.8 MB)
  int*            row_off = (int*)alloc((size_t)(N + 1) * 4);
  float*          dinv    = (float*)alloc((size_t)NP * 4);
  int*            csr     = (int*)alloc((size_t)E * 4);
  unsigned short* Wt      = (unsigned short*)alloc((size_t)4 * 16384 * 2);
  int*            bc      = (int*)alloc(256 * 4);
  int*            bbase   = (int*)alloc(256 * 4);
  int*            bcur    = (int*)alloc(256 * 4);
  // pairs aliases hB8 (E*4 = 12.8 MB fits): prep finishes before first gcn gemm.
  unsigned* pairs = hB8;

  // graph prep
  zero_small_kernel<<<1, 256, 0, stream>>>(bc, NBUCK);
  tilehist_kernel<<<(E + PT_TILE - 1) / PT_TILE, 256, 0, stream>>>(dst, bc, E);
  bucket_scan_kernel<<<1, 256, 0, stream>>>(bc, bbase, bcur, row_off, N, E);
  partition_kernel<<<(E + PT_TILE - 1) / PT_TILE, 256, 0, stream>>>(src, dst, bcur, pairs, E);
  bucket_fill_kernel<<<NBUCK, 256, 0, stream>>>(pairs, bbase, row_off, dinv, csr, N);

  // dtype prep
  int n2 = N * 64;
  convert_x_kernel<<<(n2 + 255) / 256, 256, 0, stream>>>(x, x16, n2);
  prep_weights_kernel<<<4, 256, 0, stream>>>(lin1_w, gcn_w, Wt);

  int gb = NP / 64;  // 1563
  // lin1: hA16 = bf16(relu(x16 @ W1 + b1))
  gemm_mfma_kernel<<<gb, 256, 0, stream>>>((const unsigned short*)x16, Wt,
                                           lin1_b, nullptr, (void*)hA16, N, 0);
  for (int k = 0; k < 3; k++) {
    gemm_mfma_kernel<<<gb, 256, 0, stream>>>((const unsigned short*)hA16,
                                             Wt + (size_t)(k + 1) * 16384,
                                             nullptr, dinv, (void*)hB8, N, 1);
    aggregate_fp8_kernel<<<(N + 3) / 4, 256, 0, stream>>>(
        hB8, row_off, csr, dinv, gcn_b + (size_t)k * 128, hA16, N);
  }
  head_kernel<<<(N + 3) / 4, 256, 0, stream>>>(hA16, lin2_w, lin2_b, out, N);
}

// Round 8
// 603.441 us; speedup vs baseline: 3.4360x; 1.2164x over previous
//
#include <hip/hip_runtime.h>
#include <math.h>

#define NN 100000
#define NP 100032              // padded to 64-row multiple (1563 * 64)
#define HIDC 128
#define OUTC 40
#define NBUCK ((NN + 511) >> 9)   // 196 buckets of 512 dst nodes
#define PT_TILE 8192

typedef __attribute__((ext_vector_type(2))) float floatx2;
typedef __attribute__((ext_vector_type(4))) float floatx4;
typedef __attribute__((ext_vector_type(8))) short short8;

// bf16 helpers (RN) -------------------------------------------------------
__device__ __forceinline__ unsigned pack_bf16x2(float a, float b) {
  unsigned ua = __float_as_uint(a), ub = __float_as_uint(b);
  ua = ua + 0x7fff + ((ua >> 16) & 1);
  ub = ub + 0x7fff + ((ub >> 16) & 1);
  return (ua >> 16) | (ub & 0xffff0000u);
}
__device__ __forceinline__ unsigned short bf16r(float x) {
  unsigned u = __float_as_uint(x);
  u = u + 0x7fff + ((u >> 16) & 1);
  return (unsigned short)(u >> 16);
}
__device__ __forceinline__ float bf_lo(unsigned u) { return __uint_as_float(u << 16); }
__device__ __forceinline__ float bf_hi(unsigned u) { return __uint_as_float(u & 0xffff0000u); }

// ---------------- graph prep (bucket-based) ----------------

__global__ void zero_small_kernel(int* __restrict__ p, int n) {
  int i = threadIdx.x;
  if (i < n) p[i] = 0;
}

__global__ __launch_bounds__(256) void tilehist_kernel(
    const int* __restrict__ dst, int* __restrict__ bc, int E) {
  __shared__ int hist[256];
  int t = threadIdx.x;
  hist[t] = 0;
  __syncthreads();
  int e0 = blockIdx.x * PT_TILE;
  int ec = E - e0; if (ec > PT_TILE) ec = PT_TILE;
  for (int i = t; i < ec; i += 256)
    atomicAdd(&hist[dst[e0 + i] >> 9], 1);
  __syncthreads();
  if (t < NBUCK && hist[t] > 0) atomicAdd(&bc[t], hist[t]);
}

__global__ __launch_bounds__(256) void bucket_scan_kernel(
    const int* __restrict__ bc, int* __restrict__ bbase, int* __restrict__ bcur,
    int* __restrict__ row_off, int N, int E) {
  __shared__ int sh[256];
  int t = threadIdx.x;
  int v = (t < NBUCK) ? bc[t] : 0;
  sh[t] = v;
  __syncthreads();
  for (int off = 1; off < 256; off <<= 1) {
    int u = (t >= off) ? sh[t - off] : 0;
    __syncthreads();
    sh[t] += u;
    __syncthreads();
  }
  if (t < NBUCK) { int ex = sh[t] - v; bbase[t] = ex; bcur[t] = ex; }
  if (t == 0) { bbase[NBUCK] = E; row_off[N] = E; }
}

__global__ __launch_bounds__(256) void partition_kernel(
    const int* __restrict__ src, const int* __restrict__ dst,
    int* __restrict__ bcur, unsigned* __restrict__ pairs, int E) {
  __shared__ int hist[256];
  __shared__ int base[256];
  __shared__ int lcur[256];
  int t = threadIdx.x;
  hist[t] = 0; lcur[t] = 0;
  __syncthreads();
  int e0 = blockIdx.x * PT_TILE;
  int ec = E - e0; if (ec > PT_TILE) ec = PT_TILE;
  for (int i = t; i < ec; i += 256)
    atomicAdd(&hist[dst[e0 + i] >> 9], 1);
  __syncthreads();
  if (hist[t] > 0) base[t] = atomicAdd(&bcur[t], hist[t]);
  __syncthreads();
  for (int i = t; i < ec; i += 256) {
    int d = dst[e0 + i], s = src[e0 + i];
    int b = d >> 9;
    int pos = atomicAdd(&lcur[b], 1);
    pairs[base[b] + pos] = ((unsigned)(d & 511) << 17) | (unsigned)s;
  }
}

__global__ __launch_bounds__(256) void bucket_fill_kernel(
    const unsigned* __restrict__ pairs, const int* __restrict__ bbase,
    int* __restrict__ row_off, float* __restrict__ dinv,
    int* __restrict__ csr, int N) {
  int b = blockIdx.x;
  int d0 = b << 9;
  int nd = N - d0; if (nd > 512) nd = 512;
  __shared__ int hist[512];
  __shared__ int cur[512];
  __shared__ int sums[256];
  int t = threadIdx.x;
  hist[t] = 0; hist[t + 256] = 0;
  __syncthreads();
  int rbeg = bbase[b], rend = bbase[b + 1];
  for (int i = rbeg + t; i < rend; i += 256)
    atomicAdd(&hist[pairs[i] >> 17], 1);
  __syncthreads();
  int h0 = hist[2 * t], h1 = hist[2 * t + 1];
  int s = h0 + h1;
  sums[t] = s;
  __syncthreads();
  for (int off = 1; off < 256; off <<= 1) {
    int u = (t >= off) ? sums[t - off] : 0;
    __syncthreads();
    sums[t] += u;
    __syncthreads();
  }
  int base0 = rbeg + sums[t] - s;
  int base1 = base0 + h0;
  int j0 = 2 * t, j1 = 2 * t + 1;
  if (j0 < nd) {
    row_off[d0 + j0] = base0;
    dinv[d0 + j0] = rsqrtf((float)(h0 + 1));
    cur[j0] = base0;
  }
  if (j1 < nd) {
    row_off[d0 + j1] = base1;
    dinv[d0 + j1] = rsqrtf((float)(h1 + 1));
    cur[j1] = base1;
  }
  __syncthreads();
  for (int i = rbeg + t; i < rend; i += 256) {
    unsigned pk = pairs[i];
    int q = atomicAdd(&cur[pk >> 17], 1);
    csr[q] = pk & 0x1FFFF;
  }
}

// ---------------- input/weight conversion ----------------

__global__ __launch_bounds__(256) void convert_x_kernel(
    const float* __restrict__ x, unsigned* __restrict__ x16, int n2) {
  int i = blockIdx.x * 256 + threadIdx.x;
  if (i < n2) {
    float2 v = ((const float2*)x)[i];
    x16[i] = pack_bf16x2(v.x, v.y);
  }
}

// W[k][n] fp32 -> Wt[n][k] bf16, 4 matrices (lin1, gcn0..2)
__global__ __launch_bounds__(256) void prep_weights_kernel(
    const float* __restrict__ lin1_w, const float* __restrict__ gcn_w,
    unsigned short* __restrict__ Wt) {
  int b = blockIdx.x;
  const float* src = (b == 0) ? lin1_w : (gcn_w + (size_t)(b - 1) * 16384);
  unsigned short* dst = Wt + (size_t)b * 16384;
  for (int i = threadIdx.x; i < 16384; i += 256) {
    int n = i >> 7, k = i & 127;
    dst[(size_t)n * 128 + k] = bf16r(src[(size_t)k * 128 + n]);
  }
}

// lin2_w [128][40] fp32 -> W2t [48][128] bf16 (cols 40..47 zero)
__global__ __launch_bounds__(256) void prep_w2_kernel(
    const float* __restrict__ lin2_w, unsigned short* __restrict__ W2t) {
  for (int i = threadIdx.x; i < 48 * 128; i += 256) {
    int n = i >> 7, k = i & 127;
    W2t[i] = (n < OUTC) ? bf16r(lin2_w[(size_t)k * OUTC + n]) : (unsigned short)0;
  }
}

// ---------------- MFMA GEMM: Y = A(Mx128 bf16) @ Wt^T(128x128 bf16) ----------------
// mode 0: Y16 bf16 = relu(acc + bias[col]);  mode 1: Y8 fp8 = dinv[row]*acc.

__global__ __launch_bounds__(256) void gemm_mfma_kernel(
    const unsigned short* __restrict__ A, const unsigned short* __restrict__ Wt,
    const float* __restrict__ bias, const float* __restrict__ dinv,
    void* __restrict__ Y, int M, int mode) {
  int t = threadIdx.x;
  int w = t >> 6;
  int l = t & 63;
  int quad = l >> 4;
  int m16 = l & 15;
  int row0 = blockIdx.x * 64;
  int colbase = w * 32;

  floatx4 acc[4][2];
#pragma unroll
  for (int rt = 0; rt < 4; rt++)
#pragma unroll
    for (int ct = 0; ct < 2; ct++) acc[rt][ct] = (floatx4)0.f;

  const unsigned short* Aw = A + (size_t)row0 * 128;
#pragma unroll
  for (int kc = 0; kc < 4; kc++) {
    int kof = kc * 32 + quad * 8;
    short8 b0 = *(const short8*)(Wt + (size_t)(colbase + m16) * 128 + kof);
    short8 b1 = *(const short8*)(Wt + (size_t)(colbase + 16 + m16) * 128 + kof);
#pragma unroll
    for (int rt = 0; rt < 4; rt++) {
      short8 a = *(const short8*)(Aw + (size_t)(rt * 16 + m16) * 128 + kof);
      acc[rt][0] = __builtin_amdgcn_mfma_f32_16x16x32_bf16(a, b0, acc[rt][0], 0, 0, 0);
      acc[rt][1] = __builtin_amdgcn_mfma_f32_16x16x32_bf16(a, b1, acc[rt][1], 0, 0, 0);
    }
  }

  if (mode == 0) {
    unsigned short* Y16 = (unsigned short*)Y;
    float bv0 = bias[colbase + m16];
    float bv1 = bias[colbase + 16 + m16];
#pragma unroll
    for (int rt = 0; rt < 4; rt++) {
#pragma unroll
      for (int j = 0; j < 4; j++) {
        int row = row0 + rt * 16 + quad * 4 + j;
        if (row < M) {
          Y16[(size_t)row * 128 + colbase + m16] = bf16r(fmaxf(acc[rt][0][j] + bv0, 0.f));
          Y16[(size_t)row * 128 + colbase + 16 + m16] = bf16r(fmaxf(acc[rt][1][j] + bv1, 0.f));
        }
      }
    }
  } else {
    unsigned char* Y8 = (unsigned char*)Y;
#pragma unroll
    for (int rt = 0; rt < 4; rt++) {
#pragma unroll
      for (int j = 0; j < 4; j++) {
        int row = row0 + rt * 16 + quad * 4 + j;
        if (row < M) {
          float dd = dinv[row];
          float v0 = acc[rt][0][j] * dd;
          float v1 = acc[rt][1][j] * dd;
          Y8[(size_t)row * 128 + colbase + m16] =
              (unsigned char)(__builtin_amdgcn_cvt_pk_fp8_f32(v0, v0, 0, false) & 0xFF);
          Y8[(size_t)row * 128 + colbase + 16 + m16] =
              (unsigned char)(__builtin_amdgcn_cvt_pk_fp8_f32(v1, v1, 0, false) & 0xFF);
        }
      }
    }
  }
}

// ---------------- aggregation: quarter-wave fp8 gathers, fp32 accum, bf16 out ----------------
// Row = 128 B = 16 uint2. Quarter (16 lanes) per edge -> 4 edges per load inst,
// unroll x2 -> 1 KB in flight per wave. Cross-quarter combine via shfl_xor 16/32.

__global__ __launch_bounds__(256) void aggregate_fp8_kernel(
    const uint2* __restrict__ Ht8, const int* __restrict__ row_off,
    const int* __restrict__ csr, const float* __restrict__ dinv,
    const float* __restrict__ bias, unsigned* __restrict__ Out, int N) {
  int wave = (blockIdx.x * blockDim.x + threadIdx.x) >> 6;
  int lane = threadIdx.x & 63;
  if (wave >= N) return;
  int q = lane >> 4;     // quarter 0..3
  int c16 = lane & 15;   // covers fp8 cols 8*c16 .. 8*c16+7
  int d = wave;
  int beg = row_off[d], end = row_off[d + 1];
  float a0 = 0.f, a1 = 0.f, a2 = 0.f, a3 = 0.f;
  float a4 = 0.f, a5 = 0.f, a6 = 0.f, a7 = 0.f;
  int i = beg + q;
  for (; i + 4 < end; i += 8) {
    int s0 = csr[i], s1 = csr[i + 4];
    uint2 u0 = Ht8[(size_t)s0 * 16 + c16];
    uint2 u1 = Ht8[(size_t)s1 * 16 + c16];
    floatx2 p0 = __builtin_amdgcn_cvt_pk_f32_fp8((int)u0.x, false);
    floatx2 p1 = __builtin_amdgcn_cvt_pk_f32_fp8((int)u0.x, true);
    floatx2 p2 = __builtin_amdgcn_cvt_pk_f32_fp8((int)u0.y, false);
    floatx2 p3 = __builtin_amdgcn_cvt_pk_f32_fp8((int)u0.y, true);
    a0 += p0[0]; a1 += p0[1]; a2 += p1[0]; a3 += p1[1];
    a4 += p2[0]; a5 += p2[1]; a6 += p3[0]; a7 += p3[1];
    floatx2 r0 = __builtin_amdgcn_cvt_pk_f32_fp8((int)u1.x, false);
    floatx2 r1 = __builtin_amdgcn_cvt_pk_f32_fp8((int)u1.x, true);
    floatx2 r2 = __builtin_amdgcn_cvt_pk_f32_fp8((int)u1.y, false);
    floatx2 r3 = __builtin_amdgcn_cvt_pk_f32_fp8((int)u1.y, true);
    a0 += r0[0]; a1 += r0[1]; a2 += r1[0]; a3 += r1[1];
    a4 += r2[0]; a5 += r2[1]; a6 += r3[0]; a7 += r3[1];
  }
  for (; i < end; i += 4) {
    uint2 u0 = Ht8[(size_t)csr[i] * 16 + c16];
    floatx2 p0 = __builtin_amdgcn_cvt_pk_f32_fp8((int)u0.x, false);
    floatx2 p1 = __builtin_amdgcn_cvt_pk_f32_fp8((int)u0.x, true);
    floatx2 p2 = __builtin_amdgcn_cvt_pk_f32_fp8((int)u0.y, false);
    floatx2 p3 = __builtin_amdgcn_cvt_pk_f32_fp8((int)u0.y, true);
    a0 += p0[0]; a1 += p0[1]; a2 += p1[0]; a3 += p1[1];
    a4 += p2[0]; a5 += p2[1]; a6 += p3[0]; a7 += p3[1];
  }
  if (q == 0) {  // self-loop once
    uint2 us = Ht8[(size_t)d * 16 + c16];
    floatx2 p0 = __builtin_amdgcn_cvt_pk_f32_fp8((int)us.x, false);
    floatx2 p1 = __builtin_amdgcn_cvt_pk_f32_fp8((int)us.x, true);
    floatx2 p2 = __builtin_amdgcn_cvt_pk_f32_fp8((int)us.y, false);
    floatx2 p3 = __builtin_amdgcn_cvt_pk_f32_fp8((int)us.y, true);
    a0 += p0[0]; a1 += p0[1]; a2 += p1[0]; a3 += p1[1];
    a4 += p2[0]; a5 += p2[1]; a6 += p3[0]; a7 += p3[1];
  }
  a0 += __shfl_xor(a0, 16, 64); a0 += __shfl_xor(a0, 32, 64);
  a1 += __shfl_xor(a1, 16, 64); a1 += __shfl_xor(a1, 32, 64);
  a2 += __shfl_xor(a2, 16, 64); a2 += __shfl_xor(a2, 32, 64);
  a3 += __shfl_xor(a3, 16, 64); a3 += __shfl_xor(a3, 32, 64);
  a4 += __shfl_xor(a4, 16, 64); a4 += __shfl_xor(a4, 32, 64);
  a5 += __shfl_xor(a5, 16, 64); a5 += __shfl_xor(a5, 32, 64);
  a6 += __shfl_xor(a6, 16, 64); a6 += __shfl_xor(a6, 32, 64);
  a7 += __shfl_xor(a7, 16, 64); a7 += __shfl_xor(a7, 32, 64);
  if (q == 0) {
    float dd = dinv[d];
    float4 bv0 = ((const float4*)bias)[2 * c16];
    float4 bv1 = ((const float4*)bias)[2 * c16 + 1];
    float o0 = fmaxf(fmaf(dd, a0, bv0.x), 0.f);
    float o1 = fmaxf(fmaf(dd, a1, bv0.y), 0.f);
    float o2 = fmaxf(fmaf(dd, a2, bv0.z), 0.f);
    float o3 = fmaxf(fmaf(dd, a3, bv0.w), 0.f);
    float o4 = fmaxf(fmaf(dd, a4, bv1.x), 0.f);
    float o5 = fmaxf(fmaf(dd, a5, bv1.y), 0.f);
    float o6 = fmaxf(fmaf(dd, a6, bv1.z), 0.f);
    float o7 = fmaxf(fmaf(dd, a7, bv1.w), 0.f);
    uint4 o;
    o.x = pack_bf16x2(o0, o1);
    o.y = pack_bf16x2(o2, o3);
    o.z = pack_bf16x2(o4, o5);
    o.w = pack_bf16x2(o6, o7);
    ((uint4*)Out)[(size_t)d * 16 + c16] = o;
  }
}

// ---------------- head: MFMA logits + LDS log_softmax ----------------
// 64 rows/block, 4 waves; wave w = row-tile w; 3 col-tiles (48 cols, 40 valid).

__global__ __launch_bounds__(256) void head_mfma_kernel(
    const unsigned short* __restrict__ A, const unsigned short* __restrict__ W2t,
    const float* __restrict__ b2, float* __restrict__ Out, int N) {
  __shared__ float lg[64][48];
  __shared__ float bs[48];
  int t = threadIdx.x;
  int w = t >> 6, l = t & 63, quad = l >> 4, m16 = l & 15;
  if (t < 48) bs[t] = (t < OUTC) ? b2[t] : 0.f;
  int row0 = blockIdx.x * 64;

  floatx4 acc[3];
  acc[0] = (floatx4)0.f; acc[1] = (floatx4)0.f; acc[2] = (floatx4)0.f;
  const unsigned short* Aw = A + (size_t)(row0 + w * 16) * 128;
#pragma unroll
  for (int kc = 0; kc < 4; kc++) {
    int kof = kc * 32 + quad * 8;
    short8 a = *(const short8*)(Aw + (size_t)m16 * 128 + kof);
#pragma unroll
    for (int ct = 0; ct < 3; ct++) {
      short8 b = *(const short8*)(W2t + (size_t)(ct * 16 + m16) * 128 + kof);
      acc[ct] = __builtin_amdgcn_mfma_f32_16x16x32_bf16(a, b, acc[ct], 0, 0, 0);
    }
  }
#pragma unroll
  for (int ct = 0; ct < 3; ct++)
#pragma unroll
    for (int j = 0; j < 4; j++)
      lg[w * 16 + quad * 4 + j][ct * 16 + m16] = acc[ct][j];
  __syncthreads();

  int r = t >> 2, sub = t & 3;   // 4 lanes per row, 10 cols each
  int row = row0 + r;
  float vals[10];
  float mx = -3.4e38f;
#pragma unroll
  for (int j = 0; j < 10; j++) {
    float v = lg[r][sub * 10 + j] + bs[sub * 10 + j];
    vals[j] = v;
    mx = fmaxf(mx, v);
  }
  mx = fmaxf(mx, __shfl_xor(mx, 1, 64));
  mx = fmaxf(mx, __shfl_xor(mx, 2, 64));
  float se = 0.f;
#pragma unroll
  for (int j = 0; j < 10; j++) se += expf(vals[j] - mx);
  se += __shfl_xor(se, 1, 64);
  se += __shfl_xor(se, 2, 64);
  if (row < N) {
    float ls = logf(se);
#pragma unroll
    for (int j = 0; j < 10; j++)
      Out[(size_t)row * OUTC + sub * 10 + j] = vals[j] - mx - ls;
  }
}

// ---------------- launch ----------------

extern "C" void kernel_launch(void* const* d_in, const int* in_sizes, int n_in,
                              void* d_out, int out_size, void* d_ws, size_t ws_size,
                              hipStream_t stream) {
  const float* x      = (const float*)d_in[0];
  const int*   edge   = (const int*)d_in[1];
  const float* lin1_w = (const float*)d_in[2];
  const float* lin1_b = (const float*)d_in[3];
  const float* gcn_w  = (const float*)d_in[4];
  const float* gcn_b  = (const float*)d_in[5];
  const float* lin2_w = (const float*)d_in[6];
  const float* lin2_b = (const float*)d_in[7];
  float* out = (float*)d_out;

  const int N = NN;
  const int E = in_sizes[1] / 2;  // 3,200,000
  const int* src = edge;
  const int* dst = edge + E;

  char* p = (char*)d_ws;
  auto alloc = [&](size_t bytes) { char* q = p; p += (bytes + 255) & ~(size_t)255; return q; };
  unsigned*       hA16    = (unsigned*)alloc((size_t)NP * 128 * 2);   // bf16 features
  unsigned*       x16     = (unsigned*)alloc((size_t)NP * 128 * 2);   // bf16 input
  unsigned*       hB8     = (unsigned*)alloc((size_t)NP * 32 * 4);    // fp8 messages (12.8 MB)
  int*            row_off = (int*)alloc((size_t)(N + 1) * 4);
  float*          dinv    = (float*)alloc((size_t)NP * 4);
  int*            csr     = (int*)alloc((size_t)E * 4);
  unsigned short* Wt      = (unsigned short*)alloc((size_t)4 * 16384 * 2);
  unsigned short* W2t     = (unsigned short*)alloc((size_t)48 * 128 * 2);
  int*            bc      = (int*)alloc(256 * 4);
  int*            bbase   = (int*)alloc(256 * 4);
  int*            bcur    = (int*)alloc(256 * 4);
  // pairs aliases hB8 (E*4 = 12.8 MB fits): prep finishes before first gcn gemm.
  unsigned* pairs = hB8;

  // graph prep
  zero_small_kernel<<<1, 256, 0, stream>>>(bc, NBUCK);
  tilehist_kernel<<<(E + PT_TILE - 1) / PT_TILE, 256, 0, stream>>>(dst, bc, E);
  bucket_scan_kernel<<<1, 256, 0, stream>>>(bc, bbase, bcur, row_off, N, E);
  partition_kernel<<<(E + PT_TILE - 1) / PT_TILE, 256, 0, stream>>>(src, dst, bcur, pairs, E);
  bucket_fill_kernel<<<NBUCK, 256, 0, stream>>>(pairs, bbase, row_off, dinv, csr, N);

  // dtype prep
  int n2 = N * 64;
  convert_x_kernel<<<(n2 + 255) / 256, 256, 0, stream>>>(x, x16, n2);
  prep_weights_kernel<<<4, 256, 0, stream>>>(lin1_w, gcn_w, Wt);
  prep_w2_kernel<<<1, 256, 0, stream>>>(lin2_w, W2t);

  int gb = NP / 64;  // 1563
  gemm_mfma_kernel<<<gb, 256, 0, stream>>>((const unsigned short*)x16, Wt,
                                           lin1_b, nullptr, (void*)hA16, N, 0);
  for (int k = 0; k < 3; k++) {
    gemm_mfma_kernel<<<gb, 256, 0, stream>>>((const unsigned short*)hA16,
                                             Wt + (size_t)(k + 1) * 16384,
                                             nullptr, dinv, (void*)hB8, N, 1);
    aggregate_fp8_kernel<<<(N + 3) / 4, 256, 0, stream>>>(
        (const uint2*)hB8, row_off, csr, dinv, gcn_b + (size_t)k * 128, hA16, N);
  }
  head_mfma_kernel<<<gb, 256, 0, stream>>>((const unsigned short*)hA16, W2t,
                                           lin2_b, out, N);
}

// Round 9
// 579.618 us; speedup vs baseline: 3.5772x; 1.0411x over previous
//
#include <hip/hip_runtime.h>
#include <math.h>

#define NN 100000
#define NP 100032              // padded to 64-row multiple (1563 * 64)
#define HIDC 128
#define OUTC 40
#define NBUCK ((NN + 511) >> 9)   // 196 buckets of 512 dst nodes
#define PT_TILE 8192

typedef __attribute__((ext_vector_type(2))) float floatx2;
typedef __attribute__((ext_vector_type(4))) float floatx4;
typedef __attribute__((ext_vector_type(8))) short short8;

// bf16 helpers (RN) -------------------------------------------------------
__device__ __forceinline__ unsigned pack_bf16x2(float a, float b) {
  unsigned ua = __float_as_uint(a), ub = __float_as_uint(b);
  ua = ua + 0x7fff + ((ua >> 16) & 1);
  ub = ub + 0x7fff + ((ub >> 16) & 1);
  return (ua >> 16) | (ub & 0xffff0000u);
}
__device__ __forceinline__ unsigned short bf16r(float x) {
  unsigned u = __float_as_uint(x);
  u = u + 0x7fff + ((u >> 16) & 1);
  return (unsigned short)(u >> 16);
}

// ---------------- graph prep (bucket-based) ----------------

__global__ void zero_small_kernel(int* __restrict__ p, int n) {
  int i = threadIdx.x;
  if (i < n) p[i] = 0;
}

__global__ __launch_bounds__(256) void tilehist_kernel(
    const int* __restrict__ dst, int* __restrict__ bc, int E) {
  __shared__ int hist[256];
  int t = threadIdx.x;
  hist[t] = 0;
  __syncthreads();
  int e0 = blockIdx.x * PT_TILE;
  int ec = E - e0; if (ec > PT_TILE) ec = PT_TILE;
  for (int i = t; i < ec; i += 256)
    atomicAdd(&hist[dst[e0 + i] >> 9], 1);
  __syncthreads();
  if (t < NBUCK && hist[t] > 0) atomicAdd(&bc[t], hist[t]);
}

__global__ __launch_bounds__(256) void bucket_scan_kernel(
    const int* __restrict__ bc, int* __restrict__ bbase, int* __restrict__ bcur,
    int* __restrict__ row_off, int N, int E) {
  __shared__ int sh[256];
  int t = threadIdx.x;
  int v = (t < NBUCK) ? bc[t] : 0;
  sh[t] = v;
  __syncthreads();
  for (int off = 1; off < 256; off <<= 1) {
    int u = (t >= off) ? sh[t - off] : 0;
    __syncthreads();
    sh[t] += u;
    __syncthreads();
  }
  if (t < NBUCK) { int ex = sh[t] - v; bbase[t] = ex; bcur[t] = ex; }
  if (t == 0) { bbase[NBUCK] = E; row_off[N] = E; }
}

__global__ __launch_bounds__(256) void partition_kernel(
    const int* __restrict__ src, const int* __restrict__ dst,
    int* __restrict__ bcur, unsigned* __restrict__ pairs, int E) {
  __shared__ int hist[256];
  __shared__ int base[256];
  __shared__ int lcur[256];
  int t = threadIdx.x;
  hist[t] = 0; lcur[t] = 0;
  __syncthreads();
  int e0 = blockIdx.x * PT_TILE;
  int ec = E - e0; if (ec > PT_TILE) ec = PT_TILE;
  for (int i = t; i < ec; i += 256)
    atomicAdd(&hist[dst[e0 + i] >> 9], 1);
  __syncthreads();
  if (hist[t] > 0) base[t] = atomicAdd(&bcur[t], hist[t]);
  __syncthreads();
  for (int i = t; i < ec; i += 256) {
    int d = dst[e0 + i], s = src[e0 + i];
    int b = d >> 9;
    int pos = atomicAdd(&lcur[b], 1);
    pairs[base[b] + pos] = ((unsigned)(d & 511) << 17) | (unsigned)s;
  }
}

__global__ __launch_bounds__(256) void bucket_fill_kernel(
    const unsigned* __restrict__ pairs, const int* __restrict__ bbase,
    int* __restrict__ row_off, float* __restrict__ dinv,
    int* __restrict__ csr, int N) {
  int b = blockIdx.x;
  int d0 = b << 9;
  int nd = N - d0; if (nd > 512) nd = 512;
  __shared__ int hist[512];
  __shared__ int cur[512];
  __shared__ int sums[256];
  int t = threadIdx.x;
  hist[t] = 0; hist[t + 256] = 0;
  __syncthreads();
  int rbeg = bbase[b], rend = bbase[b + 1];
  for (int i = rbeg + t; i < rend; i += 256)
    atomicAdd(&hist[pairs[i] >> 17], 1);
  __syncthreads();
  int h0 = hist[2 * t], h1 = hist[2 * t + 1];
  int s = h0 + h1;
  sums[t] = s;
  __syncthreads();
  for (int off = 1; off < 256; off <<= 1) {
    int u = (t >= off) ? sums[t - off] : 0;
    __syncthreads();
    sums[t] += u;
    __syncthreads();
  }
  int base0 = rbeg + sums[t] - s;
  int base1 = base0 + h0;
  int j0 = 2 * t, j1 = 2 * t + 1;
  if (j0 < nd) {
    row_off[d0 + j0] = base0;
    dinv[d0 + j0] = rsqrtf((float)(h0 + 1));
    cur[j0] = base0;
  }
  if (j1 < nd) {
    row_off[d0 + j1] = base1;
    dinv[d0 + j1] = rsqrtf((float)(h1 + 1));
    cur[j1] = base1;
  }
  __syncthreads();
  for (int i = rbeg + t; i < rend; i += 256) {
    unsigned pk = pairs[i];
    int q = atomicAdd(&cur[pk >> 17], 1);
    csr[q] = pk & 0x1FFFF;
  }
}

// ---------------- input/weight conversion ----------------

__global__ __launch_bounds__(256) void convert_x_kernel(
    const float* __restrict__ x, unsigned* __restrict__ x16, int n2) {
  int i = blockIdx.x * 256 + threadIdx.x;
  if (i < n2) {
    float2 v = ((const float2*)x)[i];
    x16[i] = pack_bf16x2(v.x, v.y);
  }
}

// W[k][n] fp32 -> Wt[n][k] bf16, 4 matrices (lin1, gcn0..2)
__global__ __launch_bounds__(256) void prep_weights_kernel(
    const float* __restrict__ lin1_w, const float* __restrict__ gcn_w,
    unsigned short* __restrict__ Wt) {
  int b = blockIdx.x;
  const float* src = (b == 0) ? lin1_w : (gcn_w + (size_t)(b - 1) * 16384);
  unsigned short* dst = Wt + (size_t)b * 16384;
  for (int i = threadIdx.x; i < 16384; i += 256) {
    int n = i >> 7, k = i & 127;
    dst[(size_t)n * 128 + k] = bf16r(src[(size_t)k * 128 + n]);
  }
}

// lin2_w [128][40] fp32 -> W2t [48][128] bf16 (cols 40..47 zero)
__global__ __launch_bounds__(256) void prep_w2_kernel(
    const float* __restrict__ lin2_w, unsigned short* __restrict__ W2t) {
  for (int i = threadIdx.x; i < 48 * 128; i += 256) {
    int n = i >> 7, k = i & 127;
    W2t[i] = (n < OUTC) ? bf16r(lin2_w[(size_t)k * OUTC + n]) : (unsigned short)0;
  }
}

// ---------------- MFMA GEMM: Y = A(Mx128 bf16) @ Wt^T(128x128 bf16) ----------------
// mode 0: Y16 bf16 = relu(acc + bias[col]);  mode 1: Y8 fp8 = dinv[row]*acc.

__global__ __launch_bounds__(256) void gemm_mfma_kernel(
    const unsigned short* __restrict__ A, const unsigned short* __restrict__ Wt,
    const float* __restrict__ bias, const float* __restrict__ dinv,
    void* __restrict__ Y, int M, int mode) {
  int t = threadIdx.x;
  int w = t >> 6;
  int l = t & 63;
  int quad = l >> 4;
  int m16 = l & 15;
  int row0 = blockIdx.x * 64;
  int colbase = w * 32;

  floatx4 acc[4][2];
#pragma unroll
  for (int rt = 0; rt < 4; rt++)
#pragma unroll
    for (int ct = 0; ct < 2; ct++) acc[rt][ct] = (floatx4)0.f;

  const unsigned short* Aw = A + (size_t)row0 * 128;
#pragma unroll
  for (int kc = 0; kc < 4; kc++) {
    int kof = kc * 32 + quad * 8;
    short8 b0 = *(const short8*)(Wt + (size_t)(colbase + m16) * 128 + kof);
    short8 b1 = *(const short8*)(Wt + (size_t)(colbase + 16 + m16) * 128 + kof);
#pragma unroll
    for (int rt = 0; rt < 4; rt++) {
      short8 a = *(const short8*)(Aw + (size_t)(rt * 16 + m16) * 128 + kof);
      acc[rt][0] = __builtin_amdgcn_mfma_f32_16x16x32_bf16(a, b0, acc[rt][0], 0, 0, 0);
      acc[rt][1] = __builtin_amdgcn_mfma_f32_16x16x32_bf16(a, b1, acc[rt][1], 0, 0, 0);
    }
  }

  if (mode == 0) {
    unsigned short* Y16 = (unsigned short*)Y;
    float bv0 = bias[colbase + m16];
    float bv1 = bias[colbase + 16 + m16];
#pragma unroll
    for (int rt = 0; rt < 4; rt++) {
#pragma unroll
      for (int j = 0; j < 4; j++) {
        int row = row0 + rt * 16 + quad * 4 + j;
        if (row < M) {
          Y16[(size_t)row * 128 + colbase + m16] = bf16r(fmaxf(acc[rt][0][j] + bv0, 0.f));
          Y16[(size_t)row * 128 + colbase + 16 + m16] = bf16r(fmaxf(acc[rt][1][j] + bv1, 0.f));
        }
      }
    }
  } else {
    unsigned char* Y8 = (unsigned char*)Y;
#pragma unroll
    for (int rt = 0; rt < 4; rt++) {
#pragma unroll
      for (int j = 0; j < 4; j++) {
        int row = row0 + rt * 16 + quad * 4 + j;
        if (row < M) {
          float dd = dinv[row];
          float v0 = acc[rt][0][j] * dd;
          float v1 = acc[rt][1][j] * dd;
          Y8[(size_t)row * 128 + colbase + m16] =
              (unsigned char)(__builtin_amdgcn_cvt_pk_fp8_f32(v0, v0, 0, false) & 0xFF);
          Y8[(size_t)row * 128 + colbase + 16 + m16] =
              (unsigned char)(__builtin_amdgcn_cvt_pk_fp8_f32(v1, v1, 0, false) & 0xFF);
        }
      }
    }
  }
}

// ---------------- aggregation: eighth-wave fp8 gathers, packed fp32 accum ----------------
// Row = 128 B = 8 uint4. Eighth (8 lanes) per edge -> 8 edges per load inst,
// unroll x2 -> 16 rows (2 KB) in flight per wave. floatx2 accumulators so
// cvt_pk_f32_fp8 feeds v_pk_add_f32. Cross-group combine via shfl_xor 8/16/32.

__global__ __launch_bounds__(256) void aggregate_fp8_kernel(
    const uint4* __restrict__ Ht8, const int* __restrict__ row_off,
    const int* __restrict__ csr, const float* __restrict__ dinv,
    const float* __restrict__ bias, uint4* __restrict__ Out, int N) {
  int wave = (blockIdx.x * blockDim.x + threadIdx.x) >> 6;
  int lane = threadIdx.x & 63;
  if (wave >= N) return;
  int g = lane >> 3;    // edge slot 0..7
  int c8 = lane & 7;    // covers fp8 cols 16*c8 .. 16*c8+15
  int d = wave;
  int beg = row_off[d], end = row_off[d + 1];
  floatx2 acc[8];
#pragma unroll
  for (int j = 0; j < 8; j++) acc[j] = (floatx2)0.f;

  int i = beg + g;
  for (; i + 8 < end; i += 16) {
    int s0 = csr[i], s1 = csr[i + 8];
    uint4 u0 = Ht8[(size_t)s0 * 8 + c8];
    uint4 u1 = Ht8[(size_t)s1 * 8 + c8];
    acc[0] += __builtin_amdgcn_cvt_pk_f32_fp8((int)u0.x, false);
    acc[1] += __builtin_amdgcn_cvt_pk_f32_fp8((int)u0.x, true);
    acc[2] += __builtin_amdgcn_cvt_pk_f32_fp8((int)u0.y, false);
    acc[3] += __builtin_amdgcn_cvt_pk_f32_fp8((int)u0.y, true);
    acc[4] += __builtin_amdgcn_cvt_pk_f32_fp8((int)u0.z, false);
    acc[5] += __builtin_amdgcn_cvt_pk_f32_fp8((int)u0.z, true);
    acc[6] += __builtin_amdgcn_cvt_pk_f32_fp8((int)u0.w, false);
    acc[7] += __builtin_amdgcn_cvt_pk_f32_fp8((int)u0.w, true);
    acc[0] += __builtin_amdgcn_cvt_pk_f32_fp8((int)u1.x, false);
    acc[1] += __builtin_amdgcn_cvt_pk_f32_fp8((int)u1.x, true);
    acc[2] += __builtin_amdgcn_cvt_pk_f32_fp8((int)u1.y, false);
    acc[3] += __builtin_amdgcn_cvt_pk_f32_fp8((int)u1.y, true);
    acc[4] += __builtin_amdgcn_cvt_pk_f32_fp8((int)u1.z, false);
    acc[5] += __builtin_amdgcn_cvt_pk_f32_fp8((int)u1.z, true);
    acc[6] += __builtin_amdgcn_cvt_pk_f32_fp8((int)u1.w, false);
    acc[7] += __builtin_amdgcn_cvt_pk_f32_fp8((int)u1.w, true);
  }
  for (; i < end; i += 8) {
    uint4 u0 = Ht8[(size_t)csr[i] * 8 + c8];
    acc[0] += __builtin_amdgcn_cvt_pk_f32_fp8((int)u0.x, false);
    acc[1] += __builtin_amdgcn_cvt_pk_f32_fp8((int)u0.x, true);
    acc[2] += __builtin_amdgcn_cvt_pk_f32_fp8((int)u0.y, false);
    acc[3] += __builtin_amdgcn_cvt_pk_f32_fp8((int)u0.y, true);
    acc[4] += __builtin_amdgcn_cvt_pk_f32_fp8((int)u0.z, false);
    acc[5] += __builtin_amdgcn_cvt_pk_f32_fp8((int)u0.z, true);
    acc[6] += __builtin_amdgcn_cvt_pk_f32_fp8((int)u0.w, false);
    acc[7] += __builtin_amdgcn_cvt_pk_f32_fp8((int)u0.w, true);
  }
  if (g == 0) {  // self-loop once
    uint4 us = Ht8[(size_t)d * 8 + c8];
    acc[0] += __builtin_amdgcn_cvt_pk_f32_fp8((int)us.x, false);
    acc[1] += __builtin_amdgcn_cvt_pk_f32_fp8((int)us.x, true);
    acc[2] += __builtin_amdgcn_cvt_pk_f32_fp8((int)us.y, false);
    acc[3] += __builtin_amdgcn_cvt_pk_f32_fp8((int)us.y, true);
    acc[4] += __builtin_amdgcn_cvt_pk_f32_fp8((int)us.z, false);
    acc[5] += __builtin_amdgcn_cvt_pk_f32_fp8((int)us.z, true);
    acc[6] += __builtin_amdgcn_cvt_pk_f32_fp8((int)us.w, false);
    acc[7] += __builtin_amdgcn_cvt_pk_f32_fp8((int)us.w, true);
  }
#pragma unroll
  for (int j = 0; j < 8; j++) {
    float x = acc[j][0], y = acc[j][1];
    x += __shfl_xor(x, 8, 64); x += __shfl_xor(x, 16, 64); x += __shfl_xor(x, 32, 64);
    y += __shfl_xor(y, 8, 64); y += __shfl_xor(y, 16, 64); y += __shfl_xor(y, 32, 64);
    acc[j][0] = x; acc[j][1] = y;
  }
  if (g == 0) {
    float dd = dinv[d];
    const float4* b4 = (const float4*)bias;
    float4 bv0 = b4[4 * c8 + 0];
    float4 bv1 = b4[4 * c8 + 1];
    float4 bv2 = b4[4 * c8 + 2];
    float4 bv3 = b4[4 * c8 + 3];
    uint4 o0, o1;
    o0.x = pack_bf16x2(fmaxf(fmaf(dd, acc[0][0], bv0.x), 0.f),
                       fmaxf(fmaf(dd, acc[0][1], bv0.y), 0.f));
    o0.y = pack_bf16x2(fmaxf(fmaf(dd, acc[1][0], bv0.z), 0.f),
                       fmaxf(fmaf(dd, acc[1][1], bv0.w), 0.f));
    o0.z = pack_bf16x2(fmaxf(fmaf(dd, acc[2][0], bv1.x), 0.f),
                       fmaxf(fmaf(dd, acc[2][1], bv1.y), 0.f));
    o0.w = pack_bf16x2(fmaxf(fmaf(dd, acc[3][0], bv1.z), 0.f),
                       fmaxf(fmaf(dd, acc[3][1], bv1.w), 0.f));
    o1.x = pack_bf16x2(fmaxf(fmaf(dd, acc[4][0], bv2.x), 0.f),
                       fmaxf(fmaf(dd, acc[4][1], bv2.y), 0.f));
    o1.y = pack_bf16x2(fmaxf(fmaf(dd, acc[5][0], bv2.z), 0.f),
                       fmaxf(fmaf(dd, acc[5][1], bv2.w), 0.f));
    o1.z = pack_bf16x2(fmaxf(fmaf(dd, acc[6][0], bv3.x), 0.f),
                       fmaxf(fmaf(dd, acc[6][1], bv3.y), 0.f));
    o1.w = pack_bf16x2(fmaxf(fmaf(dd, acc[7][0], bv3.z), 0.f),
                       fmaxf(fmaf(dd, acc[7][1], bv3.w), 0.f));
    Out[(size_t)d * 16 + 2 * c8] = o0;
    Out[(size_t)d * 16 + 2 * c8 + 1] = o1;
  }
}

// ---------------- head: MFMA logits + LDS log_softmax ----------------

__global__ __launch_bounds__(256) void head_mfma_kernel(
    const unsigned short* __restrict__ A, const unsigned short* __restrict__ W2t,
    const float* __restrict__ b2, float* __restrict__ Out, int N) {
  __shared__ float lg[64][48];
  __shared__ float bs[48];
  int t = threadIdx.x;
  int w = t >> 6, l = t & 63, quad = l >> 4, m16 = l & 15;
  if (t < 48) bs[t] = (t < OUTC) ? b2[t] : 0.f;
  int row0 = blockIdx.x * 64;

  floatx4 acc[3];
  acc[0] = (floatx4)0.f; acc[1] = (floatx4)0.f; acc[2] = (floatx4)0.f;
  const unsigned short* Aw = A + (size_t)(row0 + w * 16) * 128;
#pragma unroll
  for (int kc = 0; kc < 4; kc++) {
    int kof = kc * 32 + quad * 8;
    short8 a = *(const short8*)(Aw + (size_t)m16 * 128 + kof);
#pragma unroll
    for (int ct = 0; ct < 3; ct++) {
      short8 b = *(const short8*)(W2t + (size_t)(ct * 16 + m16) * 128 + kof);
      acc[ct] = __builtin_amdgcn_mfma_f32_16x16x32_bf16(a, b, acc[ct], 0, 0, 0);
    }
  }
#pragma unroll
  for (int ct = 0; ct < 3; ct++)
#pragma unroll
    for (int j = 0; j < 4; j++)
      lg[w * 16 + quad * 4 + j][ct * 16 + m16] = acc[ct][j];
  __syncthreads();

  int r = t >> 2, sub = t & 3;   // 4 lanes per row, 10 cols each
  int row = row0 + r;
  float vals[10];
  float mx = -3.4e38f;
#pragma unroll
  for (int j = 0; j < 10; j++) {
    float v = lg[r][sub * 10 + j] + bs[sub * 10 + j];
    vals[j] = v;
    mx = fmaxf(mx, v);
  }
  mx = fmaxf(mx, __shfl_xor(mx, 1, 64));
  mx = fmaxf(mx, __shfl_xor(mx, 2, 64));
  float se = 0.f;
#pragma unroll
  for (int j = 0; j < 10; j++) se += expf(vals[j] - mx);
  se += __shfl_xor(se, 1, 64);
  se += __shfl_xor(se, 2, 64);
  if (row < N) {
    float ls = logf(se);
#pragma unroll
    for (int j = 0; j < 10; j++)
      Out[(size_t)row * OUTC + sub * 10 + j] = vals[j] - mx - ls;
  }
}

// ---------------- launch ----------------

extern "C" void kernel_launch(void* const* d_in, const int* in_sizes, int n_in,
                              void* d_out, int out_size, void* d_ws, size_t ws_size,
                              hipStream_t stream) {
  const float* x      = (const float*)d_in[0];
  const int*   edge   = (const int*)d_in[1];
  const float* lin1_w = (const float*)d_in[2];
  const float* lin1_b = (const float*)d_in[3];
  const float* gcn_w  = (const float*)d_in[4];
  const float* gcn_b  = (const float*)d_in[5];
  const float* lin2_w = (const float*)d_in[6];
  const float* lin2_b = (const float*)d_in[7];
  float* out = (float*)d_out;

  const int N = NN;
  const int E = in_sizes[1] / 2;  // 3,200,000
  const int* src = edge;
  const int* dst = edge + E;

  char* p = (char*)d_ws;
  auto alloc = [&](size_t bytes) { char* q = p; p += (bytes + 255) & ~(size_t)255; return q; };
  unsigned*       hA16    = (unsigned*)alloc((size_t)NP * 128 * 2);   // bf16 features
  unsigned*       x16     = (unsigned*)alloc((size_t)NP * 128 * 2);   // bf16 input
  unsigned*       hB8     = (unsigned*)alloc((size_t)NP * 32 * 4);    // fp8 messages (12.8 MB)
  int*            row_off = (int*)alloc((size_t)(N + 1) * 4);
  float*          dinv    = (float*)alloc((size_t)NP * 4);
  int*            csr     = (int*)alloc((size_t)E * 4);
  unsigned short* Wt      = (unsigned short*)alloc((size_t)4 * 16384 * 2);
  unsigned short* W2t     = (unsigned short*)alloc((size_t)48 * 128 * 2);
  int*            bc      = (int*)alloc(256 * 4);
  int*            bbase   = (int*)alloc(256 * 4);
  int*            bcur    = (int*)alloc(256 * 4);
  // pairs aliases hB8 (E*4 = 12.8 MB fits): prep finishes before first gcn gemm.
  unsigned* pairs = hB8;

  // graph prep
  zero_small_kernel<<<1, 256, 0, stream>>>(bc, NBUCK);
  tilehist_kernel<<<(E + PT_TILE - 1) / PT_TILE, 256, 0, stream>>>(dst, bc, E);
  bucket_scan_kernel<<<1, 256, 0, stream>>>(bc, bbase, bcur, row_off, N, E);
  partition_kernel<<<(E + PT_TILE - 1) / PT_TILE, 256, 0, stream>>>(src, dst, bcur, pairs, E);
  bucket_fill_kernel<<<NBUCK, 256, 0, stream>>>(pairs, bbase, row_off, dinv, csr, N);

  // dtype prep
  int n2 = N * 64;
  convert_x_kernel<<<(n2 + 255) / 256, 256, 0, stream>>>(x, x16, n2);
  prep_weights_kernel<<<4, 256, 0, stream>>>(lin1_w, gcn_w, Wt);
  prep_w2_kernel<<<1, 256, 0, stream>>>(lin2_w, W2t);

  int gb = NP / 64;  // 1563
  gemm_mfma_kernel<<<gb, 256, 0, stream>>>((const unsigned short*)x16, Wt,
                                           lin1_b, nullptr, (void*)hA16, N, 0);
  for (int k = 0; k < 3; k++) {
    gemm_mfma_kernel<<<gb, 256, 0, stream>>>((const unsigned short*)hA16,
                                             Wt + (size_t)(k + 1) * 16384,
                                             nullptr, dinv, (void*)hB8, N, 1);
    aggregate_fp8_kernel<<<(N + 3) / 4, 256, 0, stream>>>(
        (const uint4*)hB8, row_off, csr, dinv, gcn_b + (size_t)k * 128, (uint4*)hA16, N);
  }
  head_mfma_kernel<<<gb, 256, 0, stream>>>((const unsigned short*)hA16, W2t,
                                           lin2_b, out, N);
}

// Round 10
// 578.580 us; speedup vs baseline: 3.5836x; 1.0018x over previous
//
#include <hip/hip_runtime.h>
#include <math.h>

#define NN 100000
#define NP 100032              // padded to 64-row multiple (1563 * 64)
#define HIDC 128
#define OUTC 40
#define NBUCK ((NN + 511) >> 9)   // 196 buckets of 512 dst nodes
#define PT_TILE 8192

typedef __attribute__((ext_vector_type(2))) float floatx2;
typedef __attribute__((ext_vector_type(4))) float floatx4;
typedef __attribute__((ext_vector_type(8))) short short8;

// bf16 helpers (RN) -------------------------------------------------------
__device__ __forceinline__ unsigned pack_bf16x2(float a, float b) {
  unsigned ua = __float_as_uint(a), ub = __float_as_uint(b);
  ua = ua + 0x7fff + ((ua >> 16) & 1);
  ub = ub + 0x7fff + ((ub >> 16) & 1);
  return (ua >> 16) | (ub & 0xffff0000u);
}
__device__ __forceinline__ unsigned short bf16r(float x) {
  unsigned u = __float_as_uint(x);
  u = u + 0x7fff + ((u >> 16) & 1);
  return (unsigned short)(u >> 16);
}

// ---------------- graph prep (bucket-based) ----------------

__global__ void zero_small_kernel(int* __restrict__ p, int n) {
  int i = threadIdx.x;
  if (i < n) p[i] = 0;
}

__global__ __launch_bounds__(256) void tilehist_kernel(
    const int* __restrict__ dst, int* __restrict__ bc, int E) {
  __shared__ int hist[256];
  int t = threadIdx.x;
  hist[t] = 0;
  __syncthreads();
  int e0 = blockIdx.x * PT_TILE;
  int ec = E - e0; if (ec > PT_TILE) ec = PT_TILE;
  for (int i = t; i < ec; i += 256)
    atomicAdd(&hist[dst[e0 + i] >> 9], 1);
  __syncthreads();
  if (t < NBUCK && hist[t] > 0) atomicAdd(&bc[t], hist[t]);
}

__global__ __launch_bounds__(256) void bucket_scan_kernel(
    const int* __restrict__ bc, int* __restrict__ bbase, int* __restrict__ bcur,
    int* __restrict__ row_off, int N, int E) {
  __shared__ int sh[256];
  int t = threadIdx.x;
  int v = (t < NBUCK) ? bc[t] : 0;
  sh[t] = v;
  __syncthreads();
  for (int off = 1; off < 256; off <<= 1) {
    int u = (t >= off) ? sh[t - off] : 0;
    __syncthreads();
    sh[t] += u;
    __syncthreads();
  }
  if (t < NBUCK) { int ex = sh[t] - v; bbase[t] = ex; bcur[t] = ex; }
  if (t == 0) { bbase[NBUCK] = E; row_off[N] = E; }
}

__global__ __launch_bounds__(256) void partition_kernel(
    const int* __restrict__ src, const int* __restrict__ dst,
    int* __restrict__ bcur, unsigned* __restrict__ pairs, int E) {
  __shared__ int hist[256];
  __shared__ int base[256];
  __shared__ int lcur[256];
  int t = threadIdx.x;
  hist[t] = 0; lcur[t] = 0;
  __syncthreads();
  int e0 = blockIdx.x * PT_TILE;
  int ec = E - e0; if (ec > PT_TILE) ec = PT_TILE;
  for (int i = t; i < ec; i += 256)
    atomicAdd(&hist[dst[e0 + i] >> 9], 1);
  __syncthreads();
  if (hist[t] > 0) base[t] = atomicAdd(&bcur[t], hist[t]);
  __syncthreads();
  for (int i = t; i < ec; i += 256) {
    int d = dst[e0 + i], s = src[e0 + i];
    int b = d >> 9;
    int pos = atomicAdd(&lcur[b], 1);
    pairs[base[b] + pos] = ((unsigned)(d & 511) << 17) | (unsigned)s;
  }
}

// per-bucket: LDS hist(512)+scan -> row_off/dinv/cur; degree counting-sort -> order;
// then csr scatter. One block per bucket.
__global__ __launch_bounds__(256) void bucket_fill_kernel(
    const unsigned* __restrict__ pairs, const int* __restrict__ bbase,
    int* __restrict__ row_off, float* __restrict__ dinv,
    int* __restrict__ csr, int* __restrict__ order, int N) {
  int b = blockIdx.x;
  int d0 = b << 9;
  int nd = N - d0; if (nd > 512) nd = 512;
  __shared__ int hist[512];
  __shared__ int cur[512];
  __shared__ int sums[256];
  int t = threadIdx.x;
  hist[t] = 0; hist[t + 256] = 0;
  __syncthreads();
  int rbeg = bbase[b], rend = bbase[b + 1];
  for (int i = rbeg + t; i < rend; i += 256)
    atomicAdd(&hist[pairs[i] >> 17], 1);
  __syncthreads();
  int h0 = hist[2 * t], h1 = hist[2 * t + 1];
  int s = h0 + h1;
  sums[t] = s;
  __syncthreads();
  for (int off = 1; off < 256; off <<= 1) {
    int u = (t >= off) ? sums[t - off] : 0;
    __syncthreads();
    sums[t] += u;
    __syncthreads();
  }
  int base0 = rbeg + sums[t] - s;
  int base1 = base0 + h0;
  int j0 = 2 * t, j1 = 2 * t + 1;
  if (j0 < nd) {
    row_off[d0 + j0] = base0;
    dinv[d0 + j0] = rsqrtf((float)(h0 + 1));
    cur[j0] = base0;
  }
  if (j1 < nd) {
    row_off[d0 + j1] = base1;
    dinv[d0 + j1] = rsqrtf((float)(h1 + 1));
    cur[j1] = base1;
  }
  __syncthreads();

  // ---- degree counting-sort within bucket -> order[d0 .. d0+nd) ----
  // reuse hist[0..127] as degree hist, hist[128..255] as cursors.
  if (t < 128) hist[t] = 0;
  __syncthreads();
  int c0 = h0 < 127 ? h0 : 127;
  int c1 = h1 < 127 ? h1 : 127;
  if (j0 < nd) atomicAdd(&hist[c0], 1);
  if (j1 < nd) atomicAdd(&hist[c1], 1);
  __syncthreads();
  int dv = (t < 128) ? hist[t] : 0;
  sums[t] = dv;
  __syncthreads();
  for (int off = 1; off < 128; off <<= 1) {
    int u = (t >= off) ? sums[t - off] : 0;
    __syncthreads();
    sums[t] += u;
    __syncthreads();
  }
  if (t < 128) hist[128 + t] = sums[t] - dv;  // exclusive base
  __syncthreads();
  if (j0 < nd) { int pos = atomicAdd(&hist[128 + c0], 1); order[d0 + pos] = d0 + j0; }
  if (j1 < nd) { int pos = atomicAdd(&hist[128 + c1], 1); order[d0 + pos] = d0 + j1; }
  __syncthreads();

  // ---- csr scatter ----
  for (int i = rbeg + t; i < rend; i += 256) {
    unsigned pk = pairs[i];
    int q = atomicAdd(&cur[pk >> 17], 1);
    csr[q] = pk & 0x1FFFF;
  }
}

// ---------------- input/weight conversion ----------------

__global__ __launch_bounds__(256) void convert_x_kernel(
    const float* __restrict__ x, unsigned* __restrict__ x16, int n2) {
  int i = blockIdx.x * 256 + threadIdx.x;
  if (i < n2) {
    float2 v = ((const float2*)x)[i];
    x16[i] = pack_bf16x2(v.x, v.y);
  }
}

__global__ __launch_bounds__(256) void prep_weights_kernel(
    const float* __restrict__ lin1_w, const float* __restrict__ gcn_w,
    unsigned short* __restrict__ Wt) {
  int b = blockIdx.x;
  const float* src = (b == 0) ? lin1_w : (gcn_w + (size_t)(b - 1) * 16384);
  unsigned short* dst = Wt + (size_t)b * 16384;
  for (int i = threadIdx.x; i < 16384; i += 256) {
    int n = i >> 7, k = i & 127;
    dst[(size_t)n * 128 + k] = bf16r(src[(size_t)k * 128 + n]);
  }
}

__global__ __launch_bounds__(256) void prep_w2_kernel(
    const float* __restrict__ lin2_w, unsigned short* __restrict__ W2t) {
  for (int i = threadIdx.x; i < 48 * 128; i += 256) {
    int n = i >> 7, k = i & 127;
    W2t[i] = (n < OUTC) ? bf16r(lin2_w[(size_t)k * OUTC + n]) : (unsigned short)0;
  }
}

// ---------------- MFMA GEMM: Y = A(Mx128 bf16) @ Wt^T(128x128 bf16) ----------------
// mode 0: Y16 bf16 = relu(acc + bias[col]);  mode 1: Y8 fp8 = dinv[row]*acc.

__global__ __launch_bounds__(256) void gemm_mfma_kernel(
    const unsigned short* __restrict__ A, const unsigned short* __restrict__ Wt,
    const float* __restrict__ bias, const float* __restrict__ dinv,
    void* __restrict__ Y, int M, int mode) {
  int t = threadIdx.x;
  int w = t >> 6;
  int l = t & 63;
  int quad = l >> 4;
  int m16 = l & 15;
  int row0 = blockIdx.x * 64;
  int colbase = w * 32;

  floatx4 acc[4][2];
#pragma unroll
  for (int rt = 0; rt < 4; rt++)
#pragma unroll
    for (int ct = 0; ct < 2; ct++) acc[rt][ct] = (floatx4)0.f;

  const unsigned short* Aw = A + (size_t)row0 * 128;
#pragma unroll
  for (int kc = 0; kc < 4; kc++) {
    int kof = kc * 32 + quad * 8;
    short8 b0 = *(const short8*)(Wt + (size_t)(colbase + m16) * 128 + kof);
    short8 b1 = *(const short8*)(Wt + (size_t)(colbase + 16 + m16) * 128 + kof);
#pragma unroll
    for (int rt = 0; rt < 4; rt++) {
      short8 a = *(const short8*)(Aw + (size_t)(rt * 16 + m16) * 128 + kof);
      acc[rt][0] = __builtin_amdgcn_mfma_f32_16x16x32_bf16(a, b0, acc[rt][0], 0, 0, 0);
      acc[rt][1] = __builtin_amdgcn_mfma_f32_16x16x32_bf16(a, b1, acc[rt][1], 0, 0, 0);
    }
  }

  if (mode == 0) {
    unsigned short* Y16 = (unsigned short*)Y;
    float bv0 = bias[colbase + m16];
    float bv1 = bias[colbase + 16 + m16];
#pragma unroll
    for (int rt = 0; rt < 4; rt++) {
#pragma unroll
      for (int j = 0; j < 4; j++) {
        int row = row0 + rt * 16 + quad * 4 + j;
        if (row < M) {
          Y16[(size_t)row * 128 + colbase + m16] = bf16r(fmaxf(acc[rt][0][j] + bv0, 0.f));
          Y16[(size_t)row * 128 + colbase + 16 + m16] = bf16r(fmaxf(acc[rt][1][j] + bv1, 0.f));
        }
      }
    }
  } else {
    unsigned char* Y8 = (unsigned char*)Y;
#pragma unroll
    for (int rt = 0; rt < 4; rt++) {
#pragma unroll
      for (int j = 0; j < 4; j++) {
        int row = row0 + rt * 16 + quad * 4 + j;
        if (row < M) {
          float dd = dinv[row];
          float v0 = acc[rt][0][j] * dd;
          float v1 = acc[rt][1][j] * dd;
          Y8[(size_t)row * 128 + colbase + m16] =
              (unsigned char)(__builtin_amdgcn_cvt_pk_fp8_f32(v0, v0, 0, false) & 0xFF);
          Y8[(size_t)row * 128 + colbase + 16 + m16] =
              (unsigned char)(__builtin_amdgcn_cvt_pk_fp8_f32(v1, v1, 0, false) & 0xFF);
        }
      }
    }
  }
}

// ---------------- aggregation: 8 lanes own one node, degree-sorted order ----------------
// Wave = 8 nodes (group g = lane>>3 handles node order[wid*8+g]). Each group's
// 8 lanes hold the full 128 B row (lane c8 = cols 16*c8..16*c8+15). No cross-lane
// reduce; epilogue writes the 256 B bf16 row directly. Degree sorting makes the
// 8 groups' loop counts near-equal (divergence ~0).

__global__ __launch_bounds__(256) void aggregate_fp8_kernel(
    const uint4* __restrict__ Ht8, const int* __restrict__ row_off,
    const int* __restrict__ csr, const float* __restrict__ dinv,
    const float* __restrict__ bias, const int* __restrict__ order,
    uint4* __restrict__ Out, int N) {
  int wid = (blockIdx.x * blockDim.x + threadIdx.x) >> 6;
  int lane = threadIdx.x & 63;
  int g = lane >> 3;    // node slot 0..7
  int c8 = lane & 7;    // 16 B chunk of the row
  int idx = wid * 8 + g;
  if (idx >= N) return;
  int d = order[idx];
  int beg = row_off[d], end = row_off[d + 1];

  floatx2 acc[8];
  // self-loop seeds the accumulator
  {
    uint4 us = Ht8[(size_t)d * 8 + c8];
    acc[0] = __builtin_amdgcn_cvt_pk_f32_fp8((int)us.x, false);
    acc[1] = __builtin_amdgcn_cvt_pk_f32_fp8((int)us.x, true);
    acc[2] = __builtin_amdgcn_cvt_pk_f32_fp8((int)us.y, false);
    acc[3] = __builtin_amdgcn_cvt_pk_f32_fp8((int)us.y, true);
    acc[4] = __builtin_amdgcn_cvt_pk_f32_fp8((int)us.z, false);
    acc[5] = __builtin_amdgcn_cvt_pk_f32_fp8((int)us.z, true);
    acc[6] = __builtin_amdgcn_cvt_pk_f32_fp8((int)us.w, false);
    acc[7] = __builtin_amdgcn_cvt_pk_f32_fp8((int)us.w, true);
  }
  int i = beg;
  for (; i + 1 < end; i += 2) {
    int s0 = csr[i], s1 = csr[i + 1];
    uint4 u0 = Ht8[(size_t)s0 * 8 + c8];
    uint4 u1 = Ht8[(size_t)s1 * 8 + c8];
    acc[0] += __builtin_amdgcn_cvt_pk_f32_fp8((int)u0.x, false);
    acc[1] += __builtin_amdgcn_cvt_pk_f32_fp8((int)u0.x, true);
    acc[2] += __builtin_amdgcn_cvt_pk_f32_fp8((int)u0.y, false);
    acc[3] += __builtin_amdgcn_cvt_pk_f32_fp8((int)u0.y, true);
    acc[4] += __builtin_amdgcn_cvt_pk_f32_fp8((int)u0.z, false);
    acc[5] += __builtin_amdgcn_cvt_pk_f32_fp8((int)u0.z, true);
    acc[6] += __builtin_amdgcn_cvt_pk_f32_fp8((int)u0.w, false);
    acc[7] += __builtin_amdgcn_cvt_pk_f32_fp8((int)u0.w, true);
    acc[0] += __builtin_amdgcn_cvt_pk_f32_fp8((int)u1.x, false);
    acc[1] += __builtin_amdgcn_cvt_pk_f32_fp8((int)u1.x, true);
    acc[2] += __builtin_amdgcn_cvt_pk_f32_fp8((int)u1.y, false);
    acc[3] += __builtin_amdgcn_cvt_pk_f32_fp8((int)u1.y, true);
    acc[4] += __builtin_amdgcn_cvt_pk_f32_fp8((int)u1.z, false);
    acc[5] += __builtin_amdgcn_cvt_pk_f32_fp8((int)u1.z, true);
    acc[6] += __builtin_amdgcn_cvt_pk_f32_fp8((int)u1.w, false);
    acc[7] += __builtin_amdgcn_cvt_pk_f32_fp8((int)u1.w, true);
  }
  if (i < end) {
    uint4 u0 = Ht8[(size_t)csr[i] * 8 + c8];
    acc[0] += __builtin_amdgcn_cvt_pk_f32_fp8((int)u0.x, false);
    acc[1] += __builtin_amdgcn_cvt_pk_f32_fp8((int)u0.x, true);
    acc[2] += __builtin_amdgcn_cvt_pk_f32_fp8((int)u0.y, false);
    acc[3] += __builtin_amdgcn_cvt_pk_f32_fp8((int)u0.y, true);
    acc[4] += __builtin_amdgcn_cvt_pk_f32_fp8((int)u0.z, false);
    acc[5] += __builtin_amdgcn_cvt_pk_f32_fp8((int)u0.z, true);
    acc[6] += __builtin_amdgcn_cvt_pk_f32_fp8((int)u0.w, false);
    acc[7] += __builtin_amdgcn_cvt_pk_f32_fp8((int)u0.w, true);
  }

  float dd = dinv[d];
  const float4* b4 = (const float4*)bias;
  float4 bv0 = b4[4 * c8 + 0];
  float4 bv1 = b4[4 * c8 + 1];
  float4 bv2 = b4[4 * c8 + 2];
  float4 bv3 = b4[4 * c8 + 3];
  uint4 o0, o1;
  o0.x = pack_bf16x2(fmaxf(fmaf(dd, acc[0][0], bv0.x), 0.f),
                     fmaxf(fmaf(dd, acc[0][1], bv0.y), 0.f));
  o0.y = pack_bf16x2(fmaxf(fmaf(dd, acc[1][0], bv0.z), 0.f),
                     fmaxf(fmaf(dd, acc[1][1], bv0.w), 0.f));
  o0.z = pack_bf16x2(fmaxf(fmaf(dd, acc[2][0], bv1.x), 0.f),
                     fmaxf(fmaf(dd, acc[2][1], bv1.y), 0.f));
  o0.w = pack_bf16x2(fmaxf(fmaf(dd, acc[3][0], bv1.z), 0.f),
                     fmaxf(fmaf(dd, acc[3][1], bv1.w), 0.f));
  o1.x = pack_bf16x2(fmaxf(fmaf(dd, acc[4][0], bv2.x), 0.f),
                     fmaxf(fmaf(dd, acc[4][1], bv2.y), 0.f));
  o1.y = pack_bf16x2(fmaxf(fmaf(dd, acc[5][0], bv2.z), 0.f),
                     fmaxf(fmaf(dd, acc[5][1], bv2.w), 0.f));
  o1.z = pack_bf16x2(fmaxf(fmaf(dd, acc[6][0], bv3.x), 0.f),
                     fmaxf(fmaf(dd, acc[6][1], bv3.y), 0.f));
  o1.w = pack_bf16x2(fmaxf(fmaf(dd, acc[7][0], bv3.z), 0.f),
                     fmaxf(fmaf(dd, acc[7][1], bv3.w), 0.f));
  Out[(size_t)d * 16 + 2 * c8] = o0;
  Out[(size_t)d * 16 + 2 * c8 + 1] = o1;
}

// ---------------- head: MFMA logits + LDS log_softmax ----------------

__global__ __launch_bounds__(256) void head_mfma_kernel(
    const unsigned short* __restrict__ A, const unsigned short* __restrict__ W2t,
    const float* __restrict__ b2, float* __restrict__ Out, int N) {
  __shared__ float lg[64][48];
  __shared__ float bs[48];
  int t = threadIdx.x;
  int w = t >> 6, l = t & 63, quad = l >> 4, m16 = l & 15;
  if (t < 48) bs[t] = (t < OUTC) ? b2[t] : 0.f;
  int row0 = blockIdx.x * 64;

  floatx4 acc[3];
  acc[0] = (floatx4)0.f; acc[1] = (floatx4)0.f; acc[2] = (floatx4)0.f;
  const unsigned short* Aw = A + (size_t)(row0 + w * 16) * 128;
#pragma unroll
  for (int kc = 0; kc < 4; kc++) {
    int kof = kc * 32 + quad * 8;
    short8 a = *(const short8*)(Aw + (size_t)m16 * 128 + kof);
#pragma unroll
    for (int ct = 0; ct < 3; ct++) {
      short8 b = *(const short8*)(W2t + (size_t)(ct * 16 + m16) * 128 + kof);
      acc[ct] = __builtin_amdgcn_mfma_f32_16x16x32_bf16(a, b, acc[ct], 0, 0, 0);
    }
  }
#pragma unroll
  for (int ct = 0; ct < 3; ct++)
#pragma unroll
    for (int j = 0; j < 4; j++)
      lg[w * 16 + quad * 4 + j][ct * 16 + m16] = acc[ct][j];
  __syncthreads();

  int r = t >> 2, sub = t & 3;
  int row = row0 + r;
  float vals[10];
  float mx = -3.4e38f;
#pragma unroll
  for (int j = 0; j < 10; j++) {
    float v = lg[r][sub * 10 + j] + bs[sub * 10 + j];
    vals[j] = v;
    mx = fmaxf(mx, v);
  }
  mx = fmaxf(mx, __shfl_xor(mx, 1, 64));
  mx = fmaxf(mx, __shfl_xor(mx, 2, 64));
  float se = 0.f;
#pragma unroll
  for (int j = 0; j < 10; j++) se += expf(vals[j] - mx);
  se += __shfl_xor(se, 1, 64);
  se += __shfl_xor(se, 2, 64);
  if (row < N) {
    float ls = logf(se);
#pragma unroll
    for (int j = 0; j < 10; j++)
      Out[(size_t)row * OUTC + sub * 10 + j] = vals[j] - mx - ls;
  }
}

// ---------------- launch ----------------

extern "C" void kernel_launch(void* const* d_in, const int* in_sizes, int n_in,
                              void* d_out, int out_size, void* d_ws, size_t ws_size,
                              hipStream_t stream) {
  const float* x      = (const float*)d_in[0];
  const int*   edge   = (const int*)d_in[1];
  const float* lin1_w = (const float*)d_in[2];
  const float* lin1_b = (const float*)d_in[3];
  const float* gcn_w  = (const float*)d_in[4];
  const float* gcn_b  = (const float*)d_in[5];
  const float* lin2_w = (const float*)d_in[6];
  const float* lin2_b = (const float*)d_in[7];
  float* out = (float*)d_out;

  const int N = NN;
  const int E = in_sizes[1] / 2;  // 3,200,000
  const int* src = edge;
  const int* dst = edge + E;

  char* p = (char*)d_ws;
  auto alloc = [&](size_t bytes) { char* q = p; p += (bytes + 255) & ~(size_t)255; return q; };
  unsigned*       hA16    = (unsigned*)alloc((size_t)NP * 128 * 2);   // bf16 features
  unsigned*       x16     = (unsigned*)alloc((size_t)NP * 128 * 2);   // bf16 input
  unsigned*       hB8     = (unsigned*)alloc((size_t)NP * 32 * 4);    // fp8 messages (12.8 MB)
  int*            row_off = (int*)alloc((size_t)(N + 1) * 4);
  float*          dinv    = (float*)alloc((size_t)NP * 4);
  int*            csr     = (int*)alloc((size_t)E * 4);
  int*            order   = (int*)alloc((size_t)N * 4);
  unsigned short* Wt      = (unsigned short*)alloc((size_t)4 * 16384 * 2);
  unsigned short* W2t     = (unsigned short*)alloc((size_t)48 * 128 * 2);
  int*            bc      = (int*)alloc(256 * 4);
  int*            bbase   = (int*)alloc(256 * 4);
  int*            bcur    = (int*)alloc(256 * 4);
  // pairs aliases hB8 (E*4 = 12.8 MB fits): prep finishes before first gcn gemm.
  unsigned* pairs = hB8;

  // graph prep
  zero_small_kernel<<<1, 256, 0, stream>>>(bc, NBUCK);
  tilehist_kernel<<<(E + PT_TILE - 1) / PT_TILE, 256, 0, stream>>>(dst, bc, E);
  bucket_scan_kernel<<<1, 256, 0, stream>>>(bc, bbase, bcur, row_off, N, E);
  partition_kernel<<<(E + PT_TILE - 1) / PT_TILE, 256, 0, stream>>>(src, dst, bcur, pairs, E);
  bucket_fill_kernel<<<NBUCK, 256, 0, stream>>>(pairs, bbase, row_off, dinv, csr, order, N);

  // dtype prep
  int n2 = N * 64;
  convert_x_kernel<<<(n2 + 255) / 256, 256, 0, stream>>>(x, x16, n2);
  prep_weights_kernel<<<4, 256, 0, stream>>>(lin1_w, gcn_w, Wt);
  prep_w2_kernel<<<1, 256, 0, stream>>>(lin2_w, W2t);

  int gb = NP / 64;  // 1563
  gemm_mfma_kernel<<<gb, 256, 0, stream>>>((const unsigned short*)x16, Wt,
                                           lin1_b, nullptr, (void*)hA16, N, 0);
  int ablocks = (N / 8 + 3) / 4;  // 8 nodes per wave, 4 waves per block
  for (int k = 0; k < 3; k++) {
    gemm_mfma_kernel<<<gb, 256, 0, stream>>>((const unsigned short*)hA16,
                                             Wt + (size_t)(k + 1) * 16384,
                                             nullptr, dinv, (void*)hB8, N, 1);
    aggregate_fp8_kernel<<<ablocks, 256, 0, stream>>>(
        (const uint4*)hB8, row_off, csr, dinv, gcn_b + (size_t)k * 128, order,
        (uint4*)hA16, N);
  }
  head_mfma_kernel<<<gb, 256, 0, stream>>>((const unsigned short*)hA16, W2t,
                                           lin2_b, out, N);
}

// Round 11
// 568.777 us; speedup vs baseline: 3.6454x; 1.0172x over previous
//
#include <hip/hip_runtime.h>
#include <math.h>

#define NN 100000
#define NP 100032              // padded to 64-row multiple (1563 * 64)
#define HIDC 128
#define OUTC 40
#define NBUCK ((NN + 511) >> 9)   // 196 buckets of 512 dst nodes
#define PT_TILE 8192

typedef __attribute__((ext_vector_type(2))) float floatx2;
typedef __attribute__((ext_vector_type(4))) float floatx4;
typedef __attribute__((ext_vector_type(8))) short short8;

// bf16 helpers (RN) -------------------------------------------------------
__device__ __forceinline__ unsigned pack_bf16x2(float a, float b) {
  unsigned ua = __float_as_uint(a), ub = __float_as_uint(b);
  ua = ua + 0x7fff + ((ua >> 16) & 1);
  ub = ub + 0x7fff + ((ub >> 16) & 1);
  return (ua >> 16) | (ub & 0xffff0000u);
}
__device__ __forceinline__ unsigned short bf16r(float x) {
  unsigned u = __float_as_uint(x);
  u = u + 0x7fff + ((u >> 16) & 1);
  return (unsigned short)(u >> 16);
}

// ---------------- graph prep (bucket-based) ----------------

__global__ __launch_bounds__(256) void tilehist_kernel(
    const int* __restrict__ dst, int* __restrict__ bc, int E) {
  __shared__ int hist[256];
  int t = threadIdx.x;
  hist[t] = 0;
  __syncthreads();
  int e0 = blockIdx.x * PT_TILE;
  int ec = E - e0; if (ec > PT_TILE) ec = PT_TILE;
  for (int i = t; i < ec; i += 256)
    atomicAdd(&hist[dst[e0 + i] >> 9], 1);
  __syncthreads();
  if (t < NBUCK && hist[t] > 0) atomicAdd(&bc[t], hist[t]);
}

__global__ __launch_bounds__(256) void bucket_scan_kernel(
    const int* __restrict__ bc, int* __restrict__ bbase, int* __restrict__ bcur,
    int* __restrict__ row_off, int N, int E) {
  __shared__ int sh[256];
  int t = threadIdx.x;
  int v = (t < NBUCK) ? bc[t] : 0;
  sh[t] = v;
  __syncthreads();
  for (int off = 1; off < 256; off <<= 1) {
    int u = (t >= off) ? sh[t - off] : 0;
    __syncthreads();
    sh[t] += u;
    __syncthreads();
  }
  if (t < NBUCK) { int ex = sh[t] - v; bbase[t] = ex; bcur[t] = ex; }
  if (t == 0) { bbase[NBUCK] = E; row_off[N] = E; }
}

__global__ __launch_bounds__(256) void partition_kernel(
    const int* __restrict__ src, const int* __restrict__ dst,
    int* __restrict__ bcur, unsigned* __restrict__ pairs, int E) {
  __shared__ int hist[256];
  __shared__ int base[256];
  __shared__ int lcur[256];
  int t = threadIdx.x;
  hist[t] = 0; lcur[t] = 0;
  __syncthreads();
  int e0 = blockIdx.x * PT_TILE;
  int ec = E - e0; if (ec > PT_TILE) ec = PT_TILE;
  for (int i = t; i < ec; i += 256)
    atomicAdd(&hist[dst[e0 + i] >> 9], 1);
  __syncthreads();
  if (hist[t] > 0) base[t] = atomicAdd(&bcur[t], hist[t]);
  __syncthreads();
  for (int i = t; i < ec; i += 256) {
    int d = dst[e0 + i], s = src[e0 + i];
    int b = d >> 9;
    int pos = atomicAdd(&lcur[b], 1);
    pairs[base[b] + pos] = ((unsigned)(d & 511) << 17) | (unsigned)s;
  }
}

// per-bucket: LDS hist(512)+scan -> row_off/dinv/cur; degree counting-sort -> order;
// then csr scatter. One block per bucket.
__global__ __launch_bounds__(256) void bucket_fill_kernel(
    const unsigned* __restrict__ pairs, const int* __restrict__ bbase,
    int* __restrict__ row_off, float* __restrict__ dinv,
    int* __restrict__ csr, int* __restrict__ order, int N) {
  int b = blockIdx.x;
  int d0 = b << 9;
  int nd = N - d0; if (nd > 512) nd = 512;
  __shared__ int hist[512];
  __shared__ int cur[512];
  __shared__ int sums[256];
  int t = threadIdx.x;
  hist[t] = 0; hist[t + 256] = 0;
  __syncthreads();
  int rbeg = bbase[b], rend = bbase[b + 1];
  for (int i = rbeg + t; i < rend; i += 256)
    atomicAdd(&hist[pairs[i] >> 17], 1);
  __syncthreads();
  int h0 = hist[2 * t], h1 = hist[2 * t + 1];
  int s = h0 + h1;
  sums[t] = s;
  __syncthreads();
  for (int off = 1; off < 256; off <<= 1) {
    int u = (t >= off) ? sums[t - off] : 0;
    __syncthreads();
    sums[t] += u;
    __syncthreads();
  }
  int base0 = rbeg + sums[t] - s;
  int base1 = base0 + h0;
  int j0 = 2 * t, j1 = 2 * t + 1;
  if (j0 < nd) {
    row_off[d0 + j0] = base0;
    dinv[d0 + j0] = rsqrtf((float)(h0 + 1));
    cur[j0] = base0;
  }
  if (j1 < nd) {
    row_off[d0 + j1] = base1;
    dinv[d0 + j1] = rsqrtf((float)(h1 + 1));
    cur[j1] = base1;
  }
  __syncthreads();

  // ---- degree counting-sort within bucket -> order ----
  if (t < 128) hist[t] = 0;
  __syncthreads();
  int c0 = h0 < 127 ? h0 : 127;
  int c1 = h1 < 127 ? h1 : 127;
  if (j0 < nd) atomicAdd(&hist[c0], 1);
  if (j1 < nd) atomicAdd(&hist[c1], 1);
  __syncthreads();
  int dv = (t < 128) ? hist[t] : 0;
  sums[t] = dv;
  __syncthreads();
  for (int off = 1; off < 128; off <<= 1) {
    int u = (t >= off) ? sums[t - off] : 0;
    __syncthreads();
    sums[t] += u;
    __syncthreads();
  }
  if (t < 128) hist[128 + t] = sums[t] - dv;
  __syncthreads();
  if (j0 < nd) { int pos = atomicAdd(&hist[128 + c0], 1); order[d0 + pos] = d0 + j0; }
  if (j1 < nd) { int pos = atomicAdd(&hist[128 + c1], 1); order[d0 + pos] = d0 + j1; }
  __syncthreads();

  // ---- csr scatter ----
  for (int i = rbeg + t; i < rend; i += 256) {
    unsigned pk = pairs[i];
    int q = atomicAdd(&cur[pk >> 17], 1);
    csr[q] = pk & 0x1FFFF;
  }
}

// ---------------- combined misc prep: zero bc, weight transposes ----------------
// block 0: zero bc; blocks 1..4: Wt[b-1]; block 5: W2t.

__global__ __launch_bounds__(256) void prep_misc_kernel(
    const float* __restrict__ lin1_w, const float* __restrict__ gcn_w,
    const float* __restrict__ lin2_w, int* __restrict__ bc,
    unsigned short* __restrict__ Wt, unsigned short* __restrict__ W2t) {
  int b = blockIdx.x;
  int t = threadIdx.x;
  if (b == 0) {
    if (t < NBUCK) bc[t] = 0;
  } else if (b <= 4) {
    const float* src = (b == 1) ? lin1_w : (gcn_w + (size_t)(b - 2) * 16384);
    unsigned short* dst = Wt + (size_t)(b - 1) * 16384;
    for (int i = t; i < 16384; i += 256) {
      int n = i >> 7, k = i & 127;
      dst[(size_t)n * 128 + k] = bf16r(src[(size_t)k * 128 + n]);
    }
  } else {
    for (int i = t; i < 48 * 128; i += 256) {
      int n = i >> 7, k = i & 127;
      W2t[i] = (n < OUTC) ? bf16r(lin2_w[(size_t)k * OUTC + n]) : (unsigned short)0;
    }
  }
}

// ---------------- MFMA GEMM: Y = A(Mx128) @ Wt^T(128x128 bf16) ----------------
// mode 0: A bf16, Y16 bf16 = relu(acc + bias[col])
// mode 1: A bf16, Y8 fp8 = dinv[row]*acc
// mode 2: A fp32 (converted in-flight), Y16 bf16 = relu(acc + bias[col])

template <int MODE>
__global__ __launch_bounds__(256) void gemm_mfma_kernel(
    const void* __restrict__ Av, const unsigned short* __restrict__ Wt,
    const float* __restrict__ bias, const float* __restrict__ dinv,
    void* __restrict__ Y, int M) {
  int t = threadIdx.x;
  int w = t >> 6;
  int l = t & 63;
  int quad = l >> 4;
  int m16 = l & 15;
  int row0 = blockIdx.x * 64;
  int colbase = w * 32;

  floatx4 acc[4][2];
#pragma unroll
  for (int rt = 0; rt < 4; rt++)
#pragma unroll
    for (int ct = 0; ct < 2; ct++) acc[rt][ct] = (floatx4)0.f;

#pragma unroll
  for (int kc = 0; kc < 4; kc++) {
    int kof = kc * 32 + quad * 8;
    short8 b0 = *(const short8*)(Wt + (size_t)(colbase + m16) * 128 + kof);
    short8 b1 = *(const short8*)(Wt + (size_t)(colbase + 16 + m16) * 128 + kof);
#pragma unroll
    for (int rt = 0; rt < 4; rt++) {
      short8 a;
      if (MODE == 2) {
        const float* Af = (const float*)Av + (size_t)(row0 + rt * 16 + m16) * 128 + kof;
        float4 f0 = *(const float4*)Af;
        float4 f1 = *(const float4*)(Af + 4);
        unsigned u0 = pack_bf16x2(f0.x, f0.y);
        unsigned u1 = pack_bf16x2(f0.z, f0.w);
        unsigned u2 = pack_bf16x2(f1.x, f1.y);
        unsigned u3 = pack_bf16x2(f1.z, f1.w);
        a[0] = (short)(u0 & 0xFFFF); a[1] = (short)(u0 >> 16);
        a[2] = (short)(u1 & 0xFFFF); a[3] = (short)(u1 >> 16);
        a[4] = (short)(u2 & 0xFFFF); a[5] = (short)(u2 >> 16);
        a[6] = (short)(u3 & 0xFFFF); a[7] = (short)(u3 >> 16);
      } else {
        a = *(const short8*)((const unsigned short*)Av +
                             (size_t)(row0 + rt * 16 + m16) * 128 + kof);
      }
      acc[rt][0] = __builtin_amdgcn_mfma_f32_16x16x32_bf16(a, b0, acc[rt][0], 0, 0, 0);
      acc[rt][1] = __builtin_amdgcn_mfma_f32_16x16x32_bf16(a, b1, acc[rt][1], 0, 0, 0);
    }
  }

  if (MODE != 1) {
    unsigned short* Y16 = (unsigned short*)Y;
    float bv0 = bias[colbase + m16];
    float bv1 = bias[colbase + 16 + m16];
#pragma unroll
    for (int rt = 0; rt < 4; rt++) {
#pragma unroll
      for (int j = 0; j < 4; j++) {
        int row = row0 + rt * 16 + quad * 4 + j;
        if (row < M) {
          Y16[(size_t)row * 128 + colbase + m16] = bf16r(fmaxf(acc[rt][0][j] + bv0, 0.f));
          Y16[(size_t)row * 128 + colbase + 16 + m16] = bf16r(fmaxf(acc[rt][1][j] + bv1, 0.f));
        }
      }
    }
  } else {
    unsigned char* Y8 = (unsigned char*)Y;
#pragma unroll
    for (int rt = 0; rt < 4; rt++) {
#pragma unroll
      for (int j = 0; j < 4; j++) {
        int row = row0 + rt * 16 + quad * 4 + j;
        if (row < M) {
          float dd = dinv[row];
          float v0 = acc[rt][0][j] * dd;
          float v1 = acc[rt][1][j] * dd;
          Y8[(size_t)row * 128 + colbase + m16] =
              (unsigned char)(__builtin_amdgcn_cvt_pk_fp8_f32(v0, v0, 0, false) & 0xFF);
          Y8[(size_t)row * 128 + colbase + 16 + m16] =
              (unsigned char)(__builtin_amdgcn_cvt_pk_fp8_f32(v1, v1, 0, false) & 0xFF);
        }
      }
    }
  }
}

// ---------------- aggregation: 8 lanes own one node, degree-sorted, unroll x4 ----------------

#define ACC8(u)                                                       \
  acc[0] += __builtin_amdgcn_cvt_pk_f32_fp8((int)(u).x, false);       \
  acc[1] += __builtin_amdgcn_cvt_pk_f32_fp8((int)(u).x, true);        \
  acc[2] += __builtin_amdgcn_cvt_pk_f32_fp8((int)(u).y, false);       \
  acc[3] += __builtin_amdgcn_cvt_pk_f32_fp8((int)(u).y, true);        \
  acc[4] += __builtin_amdgcn_cvt_pk_f32_fp8((int)(u).z, false);       \
  acc[5] += __builtin_amdgcn_cvt_pk_f32_fp8((int)(u).z, true);        \
  acc[6] += __builtin_amdgcn_cvt_pk_f32_fp8((int)(u).w, false);       \
  acc[7] += __builtin_amdgcn_cvt_pk_f32_fp8((int)(u).w, true);

__global__ __launch_bounds__(256) void aggregate_fp8_kernel(
    const uint4* __restrict__ Ht8, const int* __restrict__ row_off,
    const int* __restrict__ csr, const float* __restrict__ dinv,
    const float* __restrict__ bias, const int* __restrict__ order,
    uint4* __restrict__ Out, int N) {
  int wid = (blockIdx.x * blockDim.x + threadIdx.x) >> 6;
  int lane = threadIdx.x & 63;
  int g = lane >> 3;
  int c8 = lane & 7;
  int idx = wid * 8 + g;
  if (idx >= N) return;
  int d = order[idx];
  int beg = row_off[d], end = row_off[d + 1];

  floatx2 acc[8];
  {
    uint4 us = Ht8[(size_t)d * 8 + c8];
    acc[0] = __builtin_amdgcn_cvt_pk_f32_fp8((int)us.x, false);
    acc[1] = __builtin_amdgcn_cvt_pk_f32_fp8((int)us.x, true);
    acc[2] = __builtin_amdgcn_cvt_pk_f32_fp8((int)us.y, false);
    acc[3] = __builtin_amdgcn_cvt_pk_f32_fp8((int)us.y, true);
    acc[4] = __builtin_amdgcn_cvt_pk_f32_fp8((int)us.z, false);
    acc[5] = __builtin_amdgcn_cvt_pk_f32_fp8((int)us.z, true);
    acc[6] = __builtin_amdgcn_cvt_pk_f32_fp8((int)us.w, false);
    acc[7] = __builtin_amdgcn_cvt_pk_f32_fp8((int)us.w, true);
  }
  int i = beg;
  for (; i + 3 < end; i += 4) {
    int s0 = csr[i], s1 = csr[i + 1], s2 = csr[i + 2], s3 = csr[i + 3];
    uint4 u0 = Ht8[(size_t)s0 * 8 + c8];
    uint4 u1 = Ht8[(size_t)s1 * 8 + c8];
    uint4 u2 = Ht8[(size_t)s2 * 8 + c8];
    uint4 u3 = Ht8[(size_t)s3 * 8 + c8];
    ACC8(u0) ACC8(u1) ACC8(u2) ACC8(u3)
  }
  for (; i < end; i++) {
    uint4 u0 = Ht8[(size_t)csr[i] * 8 + c8];
    ACC8(u0)
  }

  float dd = dinv[d];
  const float4* b4 = (const float4*)bias;
  float4 bv0 = b4[4 * c8 + 0];
  float4 bv1 = b4[4 * c8 + 1];
  float4 bv2 = b4[4 * c8 + 2];
  float4 bv3 = b4[4 * c8 + 3];
  uint4 o0, o1;
  o0.x = pack_bf16x2(fmaxf(fmaf(dd, acc[0][0], bv0.x), 0.f),
                     fmaxf(fmaf(dd, acc[0][1], bv0.y), 0.f));
  o0.y = pack_bf16x2(fmaxf(fmaf(dd, acc[1][0], bv0.z), 0.f),
                     fmaxf(fmaf(dd, acc[1][1], bv0.w), 0.f));
  o0.z = pack_bf16x2(fmaxf(fmaf(dd, acc[2][0], bv1.x), 0.f),
                     fmaxf(fmaf(dd, acc[2][1], bv1.y), 0.f));
  o0.w = pack_bf16x2(fmaxf(fmaf(dd, acc[3][0], bv1.z), 0.f),
                     fmaxf(fmaf(dd, acc[3][1], bv1.w), 0.f));
  o1.x = pack_bf16x2(fmaxf(fmaf(dd, acc[4][0], bv2.x), 0.f),
                     fmaxf(fmaf(dd, acc[4][1], bv2.y), 0.f));
  o1.y = pack_bf16x2(fmaxf(fmaf(dd, acc[5][0], bv2.z), 0.f),
                     fmaxf(fmaf(dd, acc[5][1], bv2.w), 0.f));
  o1.z = pack_bf16x2(fmaxf(fmaf(dd, acc[6][0], bv3.x), 0.f),
                     fmaxf(fmaf(dd, acc[6][1], bv3.y), 0.f));
  o1.w = pack_bf16x2(fmaxf(fmaf(dd, acc[7][0], bv3.z), 0.f),
                     fmaxf(fmaf(dd, acc[7][1], bv3.w), 0.f));
  Out[(size_t)d * 16 + 2 * c8] = o0;
  Out[(size_t)d * 16 + 2 * c8 + 1] = o1;
}

// ---------------- head: MFMA logits + LDS log_softmax ----------------

__global__ __launch_bounds__(256) void head_mfma_kernel(
    const unsigned short* __restrict__ A, const unsigned short* __restrict__ W2t,
    const float* __restrict__ b2, float* __restrict__ Out, int N) {
  __shared__ float lg[64][48];
  __shared__ float bs[48];
  int t = threadIdx.x;
  int w = t >> 6, l = t & 63, quad = l >> 4, m16 = l & 15;
  if (t < 48) bs[t] = (t < OUTC) ? b2[t] : 0.f;
  int row0 = blockIdx.x * 64;

  floatx4 acc[3];
  acc[0] = (floatx4)0.f; acc[1] = (floatx4)0.f; acc[2] = (floatx4)0.f;
  const unsigned short* Aw = A + (size_t)(row0 + w * 16) * 128;
#pragma unroll
  for (int kc = 0; kc < 4; kc++) {
    int kof = kc * 32 + quad * 8;
    short8 a = *(const short8*)(Aw + (size_t)m16 * 128 + kof);
#pragma unroll
    for (int ct = 0; ct < 3; ct++) {
      short8 b = *(const short8*)(W2t + (size_t)(ct * 16 + m16) * 128 + kof);
      acc[ct] = __builtin_amdgcn_mfma_f32_16x16x32_bf16(a, b, acc[ct], 0, 0, 0);
    }
  }
#pragma unroll
  for (int ct = 0; ct < 3; ct++)
#pragma unroll
    for (int j = 0; j < 4; j++)
      lg[w * 16 + quad * 4 + j][ct * 16 + m16] = acc[ct][j];
  __syncthreads();

  int r = t >> 2, sub = t & 3;
  int row = row0 + r;
  float vals[10];
  float mx = -3.4e38f;
#pragma unroll
  for (int j = 0; j < 10; j++) {
    float v = lg[r][sub * 10 + j] + bs[sub * 10 + j];
    vals[j] = v;
    mx = fmaxf(mx, v);
  }
  mx = fmaxf(mx, __shfl_xor(mx, 1, 64));
  mx = fmaxf(mx, __shfl_xor(mx, 2, 64));
  float se = 0.f;
#pragma unroll
  for (int j = 0; j < 10; j++) se += expf(vals[j] - mx);
  se += __shfl_xor(se, 1, 64);
  se += __shfl_xor(se, 2, 64);
  if (row < N) {
    float ls = logf(se);
#pragma unroll
    for (int j = 0; j < 10; j++)
      Out[(size_t)row * OUTC + sub * 10 + j] = vals[j] - mx - ls;
  }
}

// ---------------- launch ----------------

extern "C" void kernel_launch(void* const* d_in, const int* in_sizes, int n_in,
                              void* d_out, int out_size, void* d_ws, size_t ws_size,
                              hipStream_t stream) {
  const float* x      = (const float*)d_in[0];
  const int*   edge   = (const int*)d_in[1];
  const float* lin1_w = (const float*)d_in[2];
  const float* lin1_b = (const float*)d_in[3];
  const float* gcn_w  = (const float*)d_in[4];
  const float* gcn_b  = (const float*)d_in[5];
  const float* lin2_w = (const float*)d_in[6];
  const float* lin2_b = (const float*)d_in[7];
  float* out = (float*)d_out;

  const int N = NN;
  const int E = in_sizes[1] / 2;  // 3,200,000
  const int* src = edge;
  const int* dst = edge + E;

  char* p = (char*)d_ws;
  auto alloc = [&](size_t bytes) { char* q = p; p += (bytes + 255) & ~(size_t)255; return q; };
  unsigned*       hA16    = (unsigned*)alloc((size_t)NP * 128 * 2);   // bf16 features
  unsigned*       hB8     = (unsigned*)alloc((size_t)NP * 32 * 4);    // fp8 messages (12.8 MB)
  int*            row_off = (int*)alloc((size_t)(N + 1) * 4);
  float*          dinv    = (float*)alloc((size_t)NP * 4);
  int*            csr     = (int*)alloc((size_t)E * 4);
  int*            order   = (int*)alloc((size_t)N * 4);
  unsigned short* Wt      = (unsigned short*)alloc((size_t)4 * 16384 * 2);
  unsigned short* W2t     = (unsigned short*)alloc((size_t)48 * 128 * 2);
  int*            bc      = (int*)alloc(256 * 4);
  int*            bbase   = (int*)alloc(256 * 4);
  int*            bcur    = (int*)alloc(256 * 4);
  // pairs aliases hB8 (E*4 = 12.8 MB fits): prep finishes before first gcn gemm.
  unsigned* pairs = hB8;

  // prep: zero bc + weight transposes (one dispatch)
  prep_misc_kernel<<<6, 256, 0, stream>>>(lin1_w, gcn_w, lin2_w, bc, Wt, W2t);
  tilehist_kernel<<<(E + PT_TILE - 1) / PT_TILE, 256, 0, stream>>>(dst, bc, E);
  bucket_scan_kernel<<<1, 256, 0, stream>>>(bc, bbase, bcur, row_off, N, E);
  partition_kernel<<<(E + PT_TILE - 1) / PT_TILE, 256, 0, stream>>>(src, dst, bcur, pairs, E);
  bucket_fill_kernel<<<NBUCK, 256, 0, stream>>>(pairs, bbase, row_off, dinv, csr, order, N);

  int gb = NP / 64;  // 1563
  // lin1: fused fp32->bf16 conversion inside the GEMM (mode 2)
  gemm_mfma_kernel<2><<<gb, 256, 0, stream>>>((const void*)x, Wt,
                                              lin1_b, nullptr, (void*)hA16, N);
  int ablocks = (N / 8 + 3) / 4;
  for (int k = 0; k < 3; k++) {
    gemm_mfma_kernel<1><<<gb, 256, 0, stream>>>((const void*)hA16,
                                                Wt + (size_t)(k + 1) * 16384,
                                                nullptr, dinv, (void*)hB8, N);
    aggregate_fp8_kernel<<<ablocks, 256, 0, stream>>>(
        (const uint4*)hB8, row_off, csr, dinv, gcn_b + (size_t)k * 128, order,
        (uint4*)hA16, N);
  }
  head_mfma_kernel<<<gb, 256, 0, stream>>>((const unsigned short*)hA16, W2t,
                                           lin2_b, out, N);
}